// Round 5
// baseline (770.977 us; speedup 1.0000x reference)
//
#include <hip/hip_runtime.h>
#include <math.h>

#define NG 100000
#define ND 50000
#define EGG 1600000
#define EDG 800000
#define EALL (EGG + EDG)
#define NALL (NG + NG)
#define HID 128
#define NH 8

// bucket sort params
#define SHIFT 11
#define BDSTS (1 << SHIFT)
#define NBUK  ((NALL + BDSTS - 1) / BDSTS)   // 98
#define S1_CH 6144

// ---------------- workspace layout (4-byte element offsets) ----------------
#define OFF_OUT_GG 0UL          // 12,800,000  (colPacked overlays until gat_gather)
#define OFF_OUT_DG 12800000UL   // 12,800,000
#define OFF_XG     25600000UL   // 12,800,000
#define OFF_XD     38400000UL   //  6,400,000
#define OFF_ASG    44800000UL   //    800,000  a_src_gg [NG,8]
#define OFF_ADG    45600000UL   //    800,000  a_dst_gg [NG,8]
#define OFF_ADD    46400000UL   //    800,000  a_dst_dg [NG,8]
#define OFF_ASD    47200000UL   //    400,000  a_src_dg [ND,8]
#define OFF_KPART  47600000UL   //        256  (zero-init)
#define OFF_DEG    47600256UL   //    200,000  (zero-init)
#define ZERO_BASE  OFF_KPART
#define ZERO_CNT   200256
#define OFF_ATTN   47800256UL   //          2 (+pad)
#define OFF_RP     47800272UL   //    200,001 (+pad)
#define OFF_BCUR   48000280UL   //        256
#define OFF_WTIL   48050000UL   //  3,072  gene wtilde [24][128]
#define OFF_BTIL   48054000UL   //     24
#define OFF_WTILD  48055000UL   //  1,024  disease wtilde [8][128]
#define OFF_BTILD  48057000UL   //      8
#define OFF_BSUM   48200280UL   //        256
#define OFF_COL    48200536UL   //  2,400,000
// end: 50,600,536 elems = 202.4 MB

typedef float  f32x4  __attribute__((ext_vector_type(4)));
typedef short  bf16x8 __attribute__((ext_vector_type(8)));
#define MFMA(a, b, c) __builtin_amdgcn_mfma_f32_16x16x32_bf16(a, b, c, 0, 0, 0)

__device__ __forceinline__ unsigned short bf16_rne(float f) {
    unsigned u = __float_as_uint(f);
    u += 0x7FFFu + ((u >> 16) & 1u);
    return (unsigned short)(u >> 16);
}
__device__ __forceinline__ float bf16f(unsigned short h) {
    return __uint_as_float(((unsigned)h) << 16);
}
__device__ __forceinline__ float fast_tanh(float x) {
    x = fminf(fmaxf(x, -15.f), 15.f);
    float t = __expf(2.f * x);
    return (t - 1.f) / (t + 1.f);
}

// ---------------- init ----------------
__global__ void init_zero_k(float* __restrict__ p, int n) {
    int i = blockIdx.x * 256 + threadIdx.x;
    if (i < n) p[i] = 0.f;
}

// ---------------- wtilde: w~[v*8+h][k] = sum_c att_v[h*16+c] * W[h*16+c][k] ----------------
__global__ void make_wtil(const float* __restrict__ W, const float* __restrict__ bias,
                          const float* __restrict__ a0, const float* __restrict__ a1,
                          const float* __restrict__ a2, int natt,
                          float* __restrict__ wtil, float* __restrict__ btil) {
    int tot = natt * 8 * 128;
    for (int i = blockIdx.x * 256 + threadIdx.x; i < tot; i += gridDim.x * 256) {
        int k = i & 127, cc = i >> 7;
        int v = cc >> 3, h = cc & 7;
        const float* av = (v == 0) ? a0 : (v == 1) ? a1 : a2;
        float s = 0.f;
        #pragma unroll
        for (int c = 0; c < 16; c++) s += av[h * 16 + c] * W[(h * 16 + c) * 128 + k];
        wtil[i] = s;
    }
    if (blockIdx.x == 0 && threadIdx.x < natt * 8) {
        int v = threadIdx.x >> 3, h = threadIdx.x & 7;
        const float* av = (v == 0) ? a0 : (v == 1) ? a1 : a2;
        float s = 0.f;
        #pragma unroll
        for (int c = 0; c < 16; c++) s += av[h * 16 + c] * bias[h * 16 + c];
        btil[threadIdx.x] = s;
    }
}

// ---------------- split-bf16 MFMA projection + fused logit columns ----------------
// C = X @ W^T + b (fp32-accurate via hi/lo split); extra col-tiles = X @ wtil^T + btil
template<int NATT>
__launch_bounds__(256)
__global__ void proj_mfma(const float* __restrict__ x, const float* __restrict__ W,
                          const float* __restrict__ bias,
                          const float* __restrict__ wtil, const float* __restrict__ btil,
                          float* __restrict__ outp,
                          float* __restrict__ o0, float* __restrict__ o1,
                          float* __restrict__ o2, int N) {
    constexpr int NTE = (NATT * 8 + 15) / 16;
    constexpr int NT = 8 + NTE;
    __shared__ bf16x8 Bhi[NT * 4 * 64];
    __shared__ bf16x8 Blo[NT * 4 * 64];
    // stage W (and wtil) as bf16 hi/lo in exact fragment layout: slot = (ct*4+kc)*64+lane
    for (int w = threadIdx.x; w < NT * 4 * 64 * 4; w += 256) {
        int j2 = w & 3, slot = w >> 2;
        int lane = slot & 63, kc = (slot >> 6) & 3, ct = slot >> 8;
        int k = kc * 32 + (lane >> 4) * 8 + j2 * 2;
        int c = lane & 15;
        float f0 = 0.f, f1 = 0.f;
        if (ct < 8) {
            int row = ct * 16 + c;
            f0 = W[row * 128 + k]; f1 = W[row * 128 + k + 1];
        } else {
            int cc = (ct - 8) * 16 + c;
            if (cc < NATT * 8) { f0 = wtil[cc * 128 + k]; f1 = wtil[cc * 128 + k + 1]; }
        }
        unsigned short h0 = bf16_rne(f0), h1 = bf16_rne(f1);
        unsigned short g0 = bf16_rne(f0 - bf16f(h0)), g1 = bf16_rne(f1 - bf16f(h1));
        ((unsigned*)&Bhi[slot])[j2] = ((unsigned)h1 << 16) | h0;
        ((unsigned*)&Blo[slot])[j2] = ((unsigned)g1 << 16) | g0;
    }
    __syncthreads();
    int wv = threadIdx.x >> 6, l = threadIdx.x & 63;
    int q = l >> 4, c16 = l & 15;
    for (int rb = blockIdx.x * 128; rb < N; rb += gridDim.x * 128) {
        int rw = rb + wv * 32;
        bf16x8 ah[2][4], al[2][4];
        #pragma unroll
        for (int t = 0; t < 2; t++) {
            int row = rw + t * 16 + c16;
            bool ok = row < N;
            const float* xr = &x[(size_t)row * 128 + q * 8];
            #pragma unroll
            for (int kc = 0; kc < 4; kc++) {
                float fv[8];
                if (ok) {
                    *(f32x4*)&fv[0] = *(const f32x4*)(xr + kc * 32);
                    *(f32x4*)&fv[4] = *(const f32x4*)(xr + kc * 32 + 4);
                } else {
                    #pragma unroll
                    for (int j = 0; j < 8; j++) fv[j] = 0.f;
                }
                #pragma unroll
                for (int j = 0; j < 8; j++) {
                    unsigned short h = bf16_rne(fv[j]);
                    ah[t][kc][j] = (short)h;
                    al[t][kc][j] = (short)bf16_rne(fv[j] - bf16f(h));
                }
            }
        }
        for (int ct = 0; ct < NT; ct++) {
            f32x4 aA0 = {0,0,0,0}, aB0 = {0,0,0,0}, aA1 = {0,0,0,0}, aB1 = {0,0,0,0};
            #pragma unroll
            for (int kc = 0; kc < 4; kc++) {
                bf16x8 bh = Bhi[(ct * 4 + kc) * 64 + l];
                bf16x8 bl = Blo[(ct * 4 + kc) * 64 + l];
                if (kc & 1) {
                    aB0 = MFMA(ah[0][kc], bh, aB0); aB1 = MFMA(ah[1][kc], bh, aB1);
                    aB0 = MFMA(ah[0][kc], bl, aB0); aB1 = MFMA(ah[1][kc], bl, aB1);
                    aB0 = MFMA(al[0][kc], bh, aB0); aB1 = MFMA(al[1][kc], bh, aB1);
                } else {
                    aA0 = MFMA(ah[0][kc], bh, aA0); aA1 = MFMA(ah[1][kc], bh, aA1);
                    aA0 = MFMA(ah[0][kc], bl, aA0); aA1 = MFMA(ah[1][kc], bl, aA1);
                    aA0 = MFMA(al[0][kc], bh, aA0); aA1 = MFMA(al[1][kc], bh, aA1);
                }
            }
            f32x4 d0 = aA0 + aB0, d1 = aA1 + aB1;
            if (ct < 8) {
                float bv = bias[ct * 16 + c16];
                #pragma unroll
                for (int t = 0; t < 2; t++) {
                    f32x4 d = t ? d1 : d0;
                    int row = rw + t * 16 + q * 4;
                    #pragma unroll
                    for (int r = 0; r < 4; r++)
                        if (row + r < N)
                            outp[(size_t)(row + r) * 128 + ct * 16 + c16] = d[r] + bv;
                }
            } else {
                int cc = (ct - 8) * 16 + c16;
                if (cc < NATT * 8) {
                    int v = cc >> 3, h = cc & 7;
                    float bt = btil[cc];
                    float* op = (v == 0) ? o0 : (v == 1) ? o1 : o2;
                    #pragma unroll
                    for (int t = 0; t < 2; t++) {
                        f32x4 d = t ? d1 : d0;
                        int row = rw + t * 16 + q * 4;
                        #pragma unroll
                        for (int r = 0; r < 4; r++)
                            if (row + r < N) op[(row + r) * 8 + h] = d[r] + bt;
                    }
                }
            }
        }
    }
}

// ---------------- kmean via plain bf16 MFMA: csum[col] += tanh(relu(src)@W^T + b) ----------------
__launch_bounds__(256)
__global__ void kmean_mfma(const float* __restrict__ src, const float* __restrict__ W,
                           const float* __restrict__ bias, float* __restrict__ kp, int N) {
    __shared__ bf16x8 Bhi[8 * 4 * 64];
    for (int w = threadIdx.x; w < 8 * 4 * 64 * 4; w += 256) {
        int j2 = w & 3, slot = w >> 2;
        int lane = slot & 63, kc = (slot >> 6) & 3, ct = slot >> 8;
        int k = kc * 32 + (lane >> 4) * 8 + j2 * 2;
        int row = ct * 16 + (lane & 15);
        float f0 = W[row * 128 + k], f1 = W[row * 128 + k + 1];
        ((unsigned*)&Bhi[slot])[j2] = ((unsigned)bf16_rne(f1) << 16) | bf16_rne(f0);
    }
    __syncthreads();
    int wv = threadIdx.x >> 6, l = threadIdx.x & 63;
    int q = l >> 4, c16 = l & 15;
    float csum[8];
    #pragma unroll
    for (int i = 0; i < 8; i++) csum[i] = 0.f;
    for (int rb = blockIdx.x * 128; rb < N; rb += gridDim.x * 128) {
        int rw = rb + wv * 32;
        bf16x8 ah[2][4];
        #pragma unroll
        for (int t = 0; t < 2; t++) {
            int row = rw + t * 16 + c16;
            bool ok = row < N;
            const float* xr = &src[(size_t)row * 128 + q * 8];
            #pragma unroll
            for (int kc = 0; kc < 4; kc++) {
                float fv[8];
                if (ok) {
                    *(f32x4*)&fv[0] = *(const f32x4*)(xr + kc * 32);
                    *(f32x4*)&fv[4] = *(const f32x4*)(xr + kc * 32 + 4);
                } else {
                    #pragma unroll
                    for (int j = 0; j < 8; j++) fv[j] = 0.f;
                }
                #pragma unroll
                for (int j = 0; j < 8; j++)
                    ah[t][kc][j] = (short)bf16_rne(fmaxf(fv[j], 0.f));
            }
        }
        #pragma unroll
        for (int ct = 0; ct < 8; ct++) {
            f32x4 aA0 = {0,0,0,0}, aB0 = {0,0,0,0}, aA1 = {0,0,0,0}, aB1 = {0,0,0,0};
            #pragma unroll
            for (int kc = 0; kc < 4; kc++) {
                bf16x8 bh = Bhi[(ct * 4 + kc) * 64 + l];
                if (kc & 1) { aB0 = MFMA(ah[0][kc], bh, aB0); aB1 = MFMA(ah[1][kc], bh, aB1); }
                else        { aA0 = MFMA(ah[0][kc], bh, aA0); aA1 = MFMA(ah[1][kc], bh, aA1); }
            }
            f32x4 d0 = aA0 + aB0, d1 = aA1 + aB1;
            float bv = bias[ct * 16 + c16];
            #pragma unroll
            for (int t = 0; t < 2; t++) {
                f32x4 d = t ? d1 : d0;
                int row = rw + t * 16 + q * 4;
                #pragma unroll
                for (int r = 0; r < 4; r++)
                    if (row + r < N) csum[ct] += fast_tanh(d[r] + bv);
            }
        }
    }
    #pragma unroll
    for (int ct = 0; ct < 8; ct++) {
        float v = csum[ct];
        v += __shfl_xor(v, 16);
        v += __shfl_xor(v, 32);
        if (l < 16) atomicAdd(&kp[ct * 16 + l], v);
    }
}

// ---------------- CSR build ----------------
__global__ void count_all(const int* __restrict__ gg_dst, const int* __restrict__ dg_dst,
                          int* __restrict__ deg) {
    int e = blockIdx.x * 256 + threadIdx.x;
    if (e < EGG) atomicAdd(&deg[gg_dst[e]], 1);
    else if (e < EALL) atomicAdd(&deg[NG + dg_dst[e - EGG]], 1);
}

__global__ void scan1(const int* __restrict__ deg, int* __restrict__ rp,
                      int* __restrict__ bsum, int N) {
    __shared__ int tsum[256];
    int t = threadIdx.x;
    int base = blockIdx.x * 1024 + t * 4;
    int v0 = 0, v1 = 0, v2 = 0, v3 = 0;
    if (base + 0 < N) v0 = deg[base + 0];
    if (base + 1 < N) v1 = deg[base + 1];
    if (base + 2 < N) v2 = deg[base + 2];
    if (base + 3 < N) v3 = deg[base + 3];
    int tot = v0 + v1 + v2 + v3;
    tsum[t] = tot;
    __syncthreads();
    for (int off = 1; off < 256; off <<= 1) {
        int y = (t >= off) ? tsum[t - off] : 0;
        __syncthreads();
        tsum[t] += y;
        __syncthreads();
    }
    int excl = tsum[t] - tot;
    if (base + 0 < N) rp[base + 0] = excl;
    if (base + 1 < N) rp[base + 1] = excl + v0;
    if (base + 2 < N) rp[base + 2] = excl + v0 + v1;
    if (base + 3 < N) rp[base + 3] = excl + v0 + v1 + v2;
    if (t == 255) bsum[blockIdx.x] = tsum[255];
}

__global__ void scan2(int* __restrict__ bsum, int NB) {
    __shared__ int s[256];
    int t = threadIdx.x;
    int v = (t < NB) ? bsum[t] : 0;
    s[t] = v;
    __syncthreads();
    for (int off = 1; off < 256; off <<= 1) {
        int y = (t >= off) ? s[t - off] : 0;
        __syncthreads();
        s[t] += y;
        __syncthreads();
    }
    if (t < NB) bsum[t] = s[t] - v;
}

__global__ void scan3(int* __restrict__ rp, const int* __restrict__ bsum,
                      int* __restrict__ bcur, int N, int E) {
    int i = blockIdx.x * 256 + threadIdx.x;
    if (i < N) {
        int v = rp[i] + bsum[i >> 10];
        rp[i] = v;
        if ((i & (BDSTS - 1)) == 0) bcur[i >> SHIFT] = v;
    }
    if (i == 0) rp[N] = E;
}

// ---------------- S1: LDS-staged bucket scatter ----------------
__launch_bounds__(256)
__global__ void bucket_scatter(const int* __restrict__ gg_src, const int* __restrict__ gg_dst,
                               const int* __restrict__ dg_src, const int* __restrict__ dg_dst,
                               int* __restrict__ bcur, unsigned int* __restrict__ colPacked) {
    __shared__ int cnt[256], scanE[256], gbase[256], cursor[256];
    __shared__ unsigned int sorted[S1_CH];
    __shared__ unsigned char bof[S1_CH];
    int t = threadIdx.x;
    cnt[t] = 0;
    __syncthreads();
    int base = blockIdx.x * S1_CH;
    for (int k = 0; k < S1_CH; k += 256) {
        int e = base + k + t;
        if (e < EALL) {
            int dn = (e < EGG) ? gg_dst[e] : (NG + dg_dst[e - EGG]);
            atomicAdd(&cnt[dn >> SHIFT], 1);
        }
    }
    __syncthreads();
    int v = cnt[t];
    __shared__ int ss[256];
    ss[t] = v;
    __syncthreads();
    for (int off = 1; off < 256; off <<= 1) {
        int y = (t >= off) ? ss[t - off] : 0;
        __syncthreads();
        ss[t] += y;
        __syncthreads();
    }
    scanE[t] = ss[t] - v;
    cursor[t] = ss[t] - v;
    if (t < NBUK && v > 0) gbase[t] = atomicAdd(&bcur[t], v);
    __syncthreads();
    for (int k = 0; k < S1_CH; k += 256) {
        int e = base + k + t;
        if (e < EALL) {
            int s, dn;
            if (e < EGG) { s = gg_src[e]; dn = gg_dst[e]; }
            else         { s = dg_src[e - EGG]; dn = NG + dg_dst[e - EGG]; }
            int b = dn >> SHIFT;
            int slot = atomicAdd(&cursor[b], 1);
            sorted[slot] = ((unsigned int)s << SHIFT) | (unsigned int)(dn & (BDSTS - 1));
            bof[slot] = (unsigned char)b;
        }
    }
    __syncthreads();
    int total = ss[255];
    for (int f = t; f < total; f += 256) {
        int b = bof[f];
        colPacked[gbase[b] + (f - scanE[b])] = sorted[f];
    }
}

// ---------------- S2: bucket-local counting sort ----------------
__launch_bounds__(256)
__global__ void bucket_sort(const unsigned int* __restrict__ colPacked,
                            const int* __restrict__ rp, int* __restrict__ col) {
    __shared__ int lcur[BDSTS];
    int b = blockIdx.x;
    int d0 = b << SHIFT;
    int dEnd = min(d0 + BDSTS, NALL);
    int nd = dEnd - d0;
    for (int i = threadIdx.x; i < nd; i += 256) lcur[i] = rp[d0 + i];
    __syncthreads();
    int ebase = rp[d0];
    int eend  = rp[dEnd];
    for (int i = ebase + threadIdx.x; i < eend; i += 256) {
        unsigned int p = colPacked[i];
        int dlow = (int)(p & (BDSTS - 1));
        int s    = (int)(p >> SHIFT);
        int pos = atomicAdd(&lcur[dlow], 1);
        col[pos] = s;
    }
}

// ---------------- fused GAT gather: one wave per dst node ----------------
__launch_bounds__(256)
__global__ void gat_gather(const int* __restrict__ rp, const int* __restrict__ col,
                           const float* __restrict__ a_s, const float* __restrict__ a_d,
                           const float* __restrict__ xsrc, float* __restrict__ outb,
                           int ndst) {
    int wid = (blockIdx.x * 256 + threadIdx.x) >> 6;
    int l = threadIdx.x & 63;
    if (wid >= ndst) return;
    int d = wid;
    int base = rp[d];
    int deg = rp[d + 1] - base;

    int hl = l & 7;
    int g  = l >> 3;
    float adl = a_d[d * 8 + hl];
    float m = -1e30f, ssum = 0.f;
    for (int c0 = 0; c0 < deg; c0 += 64) {
        int myi = c0 + l;
        int colreg = (myi < deg) ? col[base + myi] : 0;
        int lim = min(deg - c0, 64);
        for (int t = g; t < lim; t += 8) {
            int s = __shfl(colreg, t);
            float a = a_s[s * 8 + hl] + adl;
            a = a > 0.f ? a : 0.2f * a;
            float nm = fmaxf(m, a);
            ssum = ssum * __expf(m - nm) + __expf(a - nm);
            m = nm;
        }
    }
    for (int off = 8; off < 64; off <<= 1) {
        float m2 = __shfl_xor(m, off);
        float s2 = __shfl_xor(ssum, off);
        float nm = fmaxf(m, m2);
        ssum = ssum * __expf(m - nm) + s2 * __expf(m2 - nm);
        m = nm;
    }
    float rsc = 1.f / (ssum + 1e-16f);

    int half = l >> 5;
    int cl = l & 31;
    int hc = cl >> 2;
    uint32_t colbyte = (uint32_t)cl << 4;
    float4 acc = {0.f, 0.f, 0.f, 0.f};
    for (int c0 = 0; c0 < deg; c0 += 64) {
        int myi = c0 + l;
        int colreg = (myi < deg) ? col[base + myi] : 0;
        int lim = min(deg - c0, 64);
        for (int j8 = 0; j8 < lim; j8 += 8) {
            float alpha;
            {
                int s = __shfl(colreg, j8 + g);
                float a = a_s[s * 8 + hl] + adl;
                a = a > 0.f ? a : 0.2f * a;
                alpha = __expf(a - m) * rsc;
            }
            int jlim = min(lim - j8, 8);
            int jj = 0;
            for (; jj + 2 <= jlim; jj += 2) {
                int jrel = jj + half;
                int s = __shfl(colreg, j8 + jrel);
                float al = __shfl(alpha, (jrel << 3) + hc);
                const float4 xv = *(const float4*)((const char*)xsrc +
                                    (((size_t)(uint32_t)s << 9) + colbyte));
                acc.x += al * xv.x; acc.y += al * xv.y;
                acc.z += al * xv.z; acc.w += al * xv.w;
            }
            if (jj < jlim) {
                int s = __shfl(colreg, j8 + jj);
                float al = __shfl(alpha, (jj << 3) + hc);
                if (half == 0) {
                    const float4 xv = *(const float4*)((const char*)xsrc +
                                        (((size_t)(uint32_t)s << 9) + colbyte));
                    acc.x += al * xv.x; acc.y += al * xv.y;
                    acc.z += al * xv.z; acc.w += al * xv.w;
                }
            }
        }
    }
    acc.x += __shfl_xor(acc.x, 32);
    acc.y += __shfl_xor(acc.y, 32);
    acc.z += __shfl_xor(acc.z, 32);
    acc.w += __shfl_xor(acc.w, 32);
    if (half == 0)
        *(float4*)&outb[(size_t)d * 128 + cl * 4] = acc;
}

// ---------------- semantic softmax (2 scores) ----------------
__global__ void score_attn(const float* __restrict__ kpart, const float* __restrict__ q,
                           float* __restrict__ attn) {
    __shared__ float r0[128], r1[128];
    int t = threadIdx.x;
    r0[t] = q[t] * kpart[t];
    r1[t] = q[t] * kpart[128 + t];
    __syncthreads();
    for (int s = 64; s > 0; s >>= 1) {
        if (t < s) { r0[t] += r0[t + s]; r1[t] += r1[t + s]; }
        __syncthreads();
    }
    if (t == 0) {
        float s0 = r0[0] / (float)NG, s1 = r1[0] / (float)NG;
        float mx = fmaxf(s0, s1);
        float e0 = expf(s0 - mx), e1 = expf(s1 - mx);
        attn[0] = e0 / (e0 + e1);
        attn[1] = e1 / (e0 + e1);
    }
}

// ---------------- fused combine + final linear ----------------
__launch_bounds__(256)
__global__ void final_lin(const float* __restrict__ gg, const float* __restrict__ dgb,
                          const float* __restrict__ attn, const float* __restrict__ lin_w,
                          const float* __restrict__ lin_b, float* __restrict__ outp) {
    int wid = (blockIdx.x * 256 + threadIdx.x) >> 6;
    int l = threadIdx.x & 63;
    if (wid >= NG) return;
    float a0 = attn[0], a1 = attn[1];
    float2 gv = *(const float2*)&gg[(size_t)wid * 128 + l * 2];
    float2 dv = *(const float2*)&dgb[(size_t)wid * 128 + l * 2];
    float fx = a0 * fmaxf(gv.x, 0.f) + a1 * fmaxf(dv.x, 0.f);
    float fy = a0 * fmaxf(gv.y, 0.f) + a1 * fmaxf(dv.y, 0.f);
    float2 w0 = *(const float2*)&lin_w[l * 2];
    float2 w1 = *(const float2*)&lin_w[128 + l * 2];
    float p0 = fx * w0.x + fy * w0.y;
    float p1 = fx * w1.x + fy * w1.y;
    for (int off = 32; off > 0; off >>= 1) {
        p0 += __shfl_down(p0, off);
        p1 += __shfl_down(p1, off);
    }
    if (l == 0) {
        float2 o;
        o.x = p0 + lin_b[0];
        o.y = p1 + lin_b[1];
        *(float2*)&outp[wid * 2] = o;
    }
}

extern "C" void kernel_launch(void* const* d_in, const int* in_sizes, int n_in,
                              void* d_out, int out_size, void* d_ws, size_t ws_size,
                              hipStream_t stream) {
    const float* x_gene    = (const float*)d_in[0];
    const float* x_disease = (const float*)d_in[1];
    const int*   edge_gg   = (const int*)d_in[2];
    const int*   edge_dg   = (const int*)d_in[3];
    const float* pg_w      = (const float*)d_in[4];
    const float* pg_b      = (const float*)d_in[5];
    const float* pd_w      = (const float*)d_in[6];
    const float* pd_b      = (const float*)d_in[7];
    const float* att_src_gg= (const float*)d_in[8];
    const float* att_dst_gg= (const float*)d_in[9];
    const float* att_src_dg= (const float*)d_in[10];
    const float* att_dst_dg= (const float*)d_in[11];
    const float* k_lin_w   = (const float*)d_in[12];
    const float* k_lin_b   = (const float*)d_in[13];
    const float* q         = (const float*)d_in[14];
    const float* lin_w     = (const float*)d_in[15];
    const float* lin_b     = (const float*)d_in[16];
    float* out = (float*)d_out;
    float* ws  = (float*)d_ws;

    float* out_gg = ws + OFF_OUT_GG;
    float* out_dg = ws + OFF_OUT_DG;
    unsigned int* colPacked = (unsigned int*)(ws + OFF_OUT_GG);  // overlay
    float* xg     = ws + OFF_XG;
    float* xd     = ws + OFF_XD;
    float* a_src_gg = ws + OFF_ASG;
    float* a_dst_gg = ws + OFF_ADG;
    float* a_dst_dg = ws + OFF_ADD;
    float* a_src_dg = ws + OFF_ASD;
    float* kpart  = ws + OFF_KPART;
    float* attn   = ws + OFF_ATTN;
    float* wtilG  = ws + OFF_WTIL;
    float* btilG  = ws + OFF_BTIL;
    float* wtilD  = ws + OFF_WTILD;
    float* btilD  = ws + OFF_BTILD;
    int* deg  = (int*)(ws + OFF_DEG);
    int* rp   = (int*)(ws + OFF_RP);
    int* bcur = (int*)(ws + OFF_BCUR);
    int* bsum = (int*)(ws + OFF_BSUM);
    int* col  = (int*)(ws + OFF_COL);

    const int* gg_src = edge_gg;
    const int* gg_dst = edge_gg + EGG;
    const int* dg_src = edge_dg;
    const int* dg_dst = edge_dg + EDG;

    // 1. zero kpart + degree arrays; wtilde precompute
    hipLaunchKernelGGL(init_zero_k, dim3((ZERO_CNT + 255) / 256), dim3(256), 0, stream,
                       ws + ZERO_BASE, ZERO_CNT);
    hipLaunchKernelGGL(make_wtil, dim3(8), dim3(256), 0, stream,
                       pg_w, pg_b, att_src_gg, att_dst_gg, att_dst_dg, 3, wtilG, btilG);
    hipLaunchKernelGGL(make_wtil, dim3(4), dim3(256), 0, stream,
                       pd_w, pd_b, att_src_dg, att_src_dg, att_src_dg, 1, wtilD, btilD);
    // 2. split-bf16 MFMA projections with fused logits
    hipLaunchKernelGGL((proj_mfma<3>), dim3((NG + 127) / 128), dim3(256), 0, stream,
                       x_gene, pg_w, pg_b, wtilG, btilG, xg,
                       a_src_gg, a_dst_gg, a_dst_dg, NG);
    hipLaunchKernelGGL((proj_mfma<1>), dim3((ND + 127) / 128), dim3(256), 0, stream,
                       x_disease, pd_w, pd_b, wtilD, btilD, xd,
                       a_src_dg, (float*)nullptr, (float*)nullptr, ND);
    // 3. CSR row pointers
    hipLaunchKernelGGL(count_all, dim3((EALL + 255) / 256), dim3(256), 0, stream,
                       gg_dst, dg_dst, deg);
    hipLaunchKernelGGL(scan1, dim3((NALL + 1023) / 1024), dim3(256), 0, stream, deg, rp, bsum, NALL);
    hipLaunchKernelGGL(scan2, dim3(1), dim3(256), 0, stream, bsum, (NALL + 1023) / 1024);
    hipLaunchKernelGGL(scan3, dim3((NALL + 255) / 256), dim3(256), 0, stream, rp, bsum, bcur, NALL, EALL);
    // 4. two-level bucket sort into CSR col
    hipLaunchKernelGGL(bucket_scatter, dim3((EALL + S1_CH - 1) / S1_CH), dim3(256), 0, stream,
                       gg_src, gg_dst, dg_src, dg_dst, bcur, colPacked);
    hipLaunchKernelGGL(bucket_sort, dim3(NBUK), dim3(256), 0, stream, colPacked, rp, col);
    // 5. fused gathers (out_gg overwrites colPacked overlay — dead by now)
    hipLaunchKernelGGL(gat_gather, dim3((NG + 3) / 4), dim3(256), 0, stream,
                       rp, col, a_src_gg, a_dst_gg, xg, out_gg, NG);
    hipLaunchKernelGGL(gat_gather, dim3((NG + 3) / 4), dim3(256), 0, stream,
                       rp + NG, col, a_src_dg, a_dst_dg, xd, out_dg, NG);
    // 6. semantic attention (bf16 MFMA kmean)
    hipLaunchKernelGGL(kmean_mfma, dim3((NG + 127) / 128), dim3(256), 0, stream,
                       out_gg, k_lin_w, k_lin_b, kpart, NG);
    hipLaunchKernelGGL(kmean_mfma, dim3((NG + 127) / 128), dim3(256), 0, stream,
                       out_dg, k_lin_w, k_lin_b, kpart + 128, NG);
    hipLaunchKernelGGL(score_attn, dim3(1), dim3(128), 0, stream, kpart, q, attn);
    // 7. fused combine + final linear
    hipLaunchKernelGGL(final_lin, dim3((NG + 3) / 4), dim3(256), 0, stream,
                       out_gg, out_dg, attn, lin_w, lin_b, out);
}

// Round 6
// 743.177 us; speedup vs baseline: 1.0374x; 1.0374x over previous
//
#include <hip/hip_runtime.h>
#include <math.h>

#define NG 100000
#define ND 50000
#define EGG 1600000
#define EDG 800000
#define EALL (EGG + EDG)
#define NALL (NG + NG)
#define HID 128
#define NH 8

// bucket sort params
#define SHIFT 11
#define BDSTS (1 << SHIFT)
#define NBUK  ((NALL + BDSTS - 1) / BDSTS)   // 98
#define S1_CH 6144

// ---------------- workspace layout (4-byte element offsets) ----------------
#define OFF_OUT_GG 0UL          // 12,800,000  (colPacked overlays until gat_gather)
#define OFF_OUT_DG 12800000UL   // 12,800,000
#define OFF_XG     25600000UL   // 12,800,000
#define OFF_XD     38400000UL   //  6,400,000
#define OFF_ASG    44800000UL   //    800,000  a_src_gg [NG,8]
#define OFF_ADG    45600000UL   //    800,000  a_dst_gg [NG,8]
#define OFF_ADD    46400000UL   //    800,000  a_dst_dg [NG,8]
#define OFF_ASD    47200000UL   //    400,000  a_src_dg [ND,8]
#define OFF_KPART  47600000UL   //        256  (zero-init)
#define OFF_DEG    47600256UL   //    200,000  (zero-init)
#define ZERO_BASE  OFF_KPART
#define ZERO_CNT   200256
#define OFF_ATTN   47800256UL   //          2 (+pad)
#define OFF_RP     47800272UL   //    200,001 (+pad)
#define OFF_BCUR   48000280UL   //        256
#define OFF_BSUM   48200280UL   //        256
#define OFF_COL    48200536UL   //  2,400,000
// end: 50,600,536 elems = 202.4 MB

typedef float  f32x4  __attribute__((ext_vector_type(4)));
typedef short  bf16x8 __attribute__((ext_vector_type(8)));
#define MFMA(a, b, c) __builtin_amdgcn_mfma_f32_16x16x32_bf16(a, b, c, 0, 0, 0)

__device__ __forceinline__ unsigned short bf16_rne(float f) {
    unsigned u = __float_as_uint(f);
    u += 0x7FFFu + ((u >> 16) & 1u);
    return (unsigned short)(u >> 16);
}
__device__ __forceinline__ float fast_tanh(float x) {
    x = fminf(fmaxf(x, -15.f), 15.f);
    float t = __expf(2.f * x);
    return (t - 1.f) / (t + 1.f);
}

// ---------------- init ----------------
__global__ void init_zero_k(float* __restrict__ p, int n) {
    int i = blockIdx.x * 256 + threadIdx.x;
    if (i < n) p[i] = 0.f;
}

// ---------------- projection GEMM + fused attention-logit epilogue (VALU, known-good R4) ----------------
__launch_bounds__(256)
__global__ void proj_gemm_fused(const float* __restrict__ x, const float* __restrict__ W,
                                const float* __restrict__ bias, float* __restrict__ out, int N,
                                int natt,
                                const float* __restrict__ att0, const float* __restrict__ att1,
                                const float* __restrict__ att2,
                                float* __restrict__ o0, float* __restrict__ o1,
                                float* __restrict__ o2) {
    __shared__ float Ws[128 * 128];       // Ws[i*128 + j] = W[j*128 + i]
    __shared__ float rows_s[32][128];
    for (int idx = threadIdx.x; idx < 128 * 128; idx += 256) {
        int i = idx >> 7, j = idx & 127;
        Ws[i * 128 + j] = W[j * 128 + i];
    }
    int g = threadIdx.x >> 5;   // group 0..7, 4 rows each
    int l = threadIdx.x & 31;
    int g4 = g * 4;
    float4 bvec = *(const float4*)&bias[l * 4];
    float4 at0 = {0,0,0,0}, at1 = {0,0,0,0}, at2 = {0,0,0,0};
    if (natt > 0) at0 = *(const float4*)&att0[l * 4];
    if (natt > 1) at1 = *(const float4*)&att1[l * 4];
    if (natt > 2) at2 = *(const float4*)&att2[l * 4];
    __syncthreads();
    for (int base = blockIdx.x * 32; base < N; base += gridDim.x * 32) {
        int r0 = base + g4;
        #pragma unroll
        for (int k = 0; k < 4; k++) {
            int n = r0 + k;
            if (n < N)
                *(float4*)&rows_s[g4 + k][l * 4] = *(const float4*)&x[(size_t)n * 128 + l * 4];
        }
        __syncthreads();
        float4 acc0 = bvec, acc1 = bvec, acc2 = bvec, acc3 = bvec;
        #pragma unroll 4
        for (int i = 0; i < 128; i++) {
            float4 w = *(const float4*)&Ws[i * 128 + l * 4];
            float x0 = rows_s[g4 + 0][i];
            float x1 = rows_s[g4 + 1][i];
            float x2 = rows_s[g4 + 2][i];
            float x3 = rows_s[g4 + 3][i];
            acc0.x += x0 * w.x; acc0.y += x0 * w.y; acc0.z += x0 * w.z; acc0.w += x0 * w.w;
            acc1.x += x1 * w.x; acc1.y += x1 * w.y; acc1.z += x1 * w.z; acc1.w += x1 * w.w;
            acc2.x += x2 * w.x; acc2.y += x2 * w.y; acc2.z += x2 * w.z; acc2.w += x2 * w.w;
            acc3.x += x3 * w.x; acc3.y += x3 * w.y; acc3.z += x3 * w.z; acc3.w += x3 * w.w;
        }
        #define ROW_EPI(ACC, KK) do { \
            int n = r0 + KK; \
            if (n < N) { \
                *(float4*)&out[(size_t)n * 128 + l * 4] = ACC; \
                if (natt > 0) { \
                    float p = ACC.x*at0.x + ACC.y*at0.y + ACC.z*at0.z + ACC.w*at0.w; \
                    p += __shfl_xor(p, 1); p += __shfl_xor(p, 2); \
                    if ((l & 3) == 0) o0[n * 8 + (l >> 2)] = p; } \
                if (natt > 1) { \
                    float p = ACC.x*at1.x + ACC.y*at1.y + ACC.z*at1.z + ACC.w*at1.w; \
                    p += __shfl_xor(p, 1); p += __shfl_xor(p, 2); \
                    if ((l & 3) == 0) o1[n * 8 + (l >> 2)] = p; } \
                if (natt > 2) { \
                    float p = ACC.x*at2.x + ACC.y*at2.y + ACC.z*at2.z + ACC.w*at2.w; \
                    p += __shfl_xor(p, 1); p += __shfl_xor(p, 2); \
                    if ((l & 3) == 0) o2[n * 8 + (l >> 2)] = p; } \
            } } while (0)
        ROW_EPI(acc0, 0); ROW_EPI(acc1, 1); ROW_EPI(acc2, 2); ROW_EPI(acc3, 3);
        #undef ROW_EPI
        __syncthreads();
    }
}

// ---------------- kmean via bf16 MFMA (v2: no local arrays on the load path) ----------------
// csum[col] += tanh(relu(src) @ W^T + b); col sums atomically added to kp[0:128]
__launch_bounds__(256)
__global__ void kmean_mfma(const float* __restrict__ src, const float* __restrict__ W,
                           const float* __restrict__ bias, float* __restrict__ kp, int N) {
    __shared__ bf16x8 Bs[8 * 4 * 64];   // 32 KB, fragment layout: slot=(ct*4+kc)*64+lane
    for (int w = threadIdx.x; w < 8 * 4 * 64 * 4; w += 256) {
        int j2 = w & 3, slot = w >> 2;
        int lane = slot & 63, kc = (slot >> 6) & 3, ct = slot >> 8;
        int k = kc * 32 + (lane >> 4) * 8 + j2 * 2;
        int row = ct * 16 + (lane & 15);
        float f0 = W[row * 128 + k], f1 = W[row * 128 + k + 1];
        ((unsigned*)&Bs[slot])[j2] = ((unsigned)bf16_rne(f1) << 16) | bf16_rne(f0);
    }
    __syncthreads();
    int wv = threadIdx.x >> 6, l = threadIdx.x & 63;
    int q = l >> 4, c16 = l & 15;
    float csum[8];
    #pragma unroll
    for (int i = 0; i < 8; i++) csum[i] = 0.f;
    for (int rb = blockIdx.x * 128; rb < N; rb += gridDim.x * 128) {
        int rw = rb + wv * 32;
        bf16x8 a0f[4], a1f[4];   // A fragments for row-tiles t=0,1
        #pragma unroll
        for (int t = 0; t < 2; t++) {
            int row = rw + t * 16 + c16;
            bool ok = row < N;
            const float* xr = &src[(size_t)row * 128 + q * 8];
            #pragma unroll
            for (int kc = 0; kc < 4; kc++) {
                f32x4 v0 = {0,0,0,0}, v1 = {0,0,0,0};
                if (ok) {
                    v0 = *(const f32x4*)(xr + kc * 32);
                    v1 = *(const f32x4*)(xr + kc * 32 + 4);
                }
                bf16x8 f;
                f[0] = (short)bf16_rne(fmaxf(v0.x, 0.f));
                f[1] = (short)bf16_rne(fmaxf(v0.y, 0.f));
                f[2] = (short)bf16_rne(fmaxf(v0.z, 0.f));
                f[3] = (short)bf16_rne(fmaxf(v0.w, 0.f));
                f[4] = (short)bf16_rne(fmaxf(v1.x, 0.f));
                f[5] = (short)bf16_rne(fmaxf(v1.y, 0.f));
                f[6] = (short)bf16_rne(fmaxf(v1.z, 0.f));
                f[7] = (short)bf16_rne(fmaxf(v1.w, 0.f));
                if (t == 0) a0f[kc] = f; else a1f[kc] = f;
            }
        }
        #pragma unroll
        for (int ct = 0; ct < 8; ct++) {
            f32x4 aA0 = {0,0,0,0}, aB0 = {0,0,0,0}, aA1 = {0,0,0,0}, aB1 = {0,0,0,0};
            #pragma unroll
            for (int kc = 0; kc < 4; kc++) {
                bf16x8 bh = Bs[(ct * 4 + kc) * 64 + l];
                if (kc & 1) { aB0 = MFMA(a0f[kc], bh, aB0); aB1 = MFMA(a1f[kc], bh, aB1); }
                else        { aA0 = MFMA(a0f[kc], bh, aA0); aA1 = MFMA(a1f[kc], bh, aA1); }
            }
            f32x4 d0 = aA0 + aB0, d1 = aA1 + aB1;
            float bv = bias[ct * 16 + c16];
            int row0 = rw + q * 4;
            #pragma unroll
            for (int r = 0; r < 4; r++)
                if (row0 + r < N) csum[ct] += fast_tanh(d0[r] + bv);
            int row1 = rw + 16 + q * 4;
            #pragma unroll
            for (int r = 0; r < 4; r++)
                if (row1 + r < N) csum[ct] += fast_tanh(d1[r] + bv);
        }
    }
    #pragma unroll
    for (int ct = 0; ct < 8; ct++) {
        float v = csum[ct];
        v += __shfl_xor(v, 16);
        v += __shfl_xor(v, 32);
        if (l < 16) atomicAdd(&kp[ct * 16 + l], v);
    }
}

// ---------------- CSR build ----------------
__global__ void count_all(const int* __restrict__ gg_dst, const int* __restrict__ dg_dst,
                          int* __restrict__ deg) {
    int e = blockIdx.x * 256 + threadIdx.x;
    if (e < EGG) atomicAdd(&deg[gg_dst[e]], 1);
    else if (e < EALL) atomicAdd(&deg[NG + dg_dst[e - EGG]], 1);
}

__global__ void scan1(const int* __restrict__ deg, int* __restrict__ rp,
                      int* __restrict__ bsum, int N) {
    __shared__ int tsum[256];
    int t = threadIdx.x;
    int base = blockIdx.x * 1024 + t * 4;
    int v0 = 0, v1 = 0, v2 = 0, v3 = 0;
    if (base + 0 < N) v0 = deg[base + 0];
    if (base + 1 < N) v1 = deg[base + 1];
    if (base + 2 < N) v2 = deg[base + 2];
    if (base + 3 < N) v3 = deg[base + 3];
    int tot = v0 + v1 + v2 + v3;
    tsum[t] = tot;
    __syncthreads();
    for (int off = 1; off < 256; off <<= 1) {
        int y = (t >= off) ? tsum[t - off] : 0;
        __syncthreads();
        tsum[t] += y;
        __syncthreads();
    }
    int excl = tsum[t] - tot;
    if (base + 0 < N) rp[base + 0] = excl;
    if (base + 1 < N) rp[base + 1] = excl + v0;
    if (base + 2 < N) rp[base + 2] = excl + v0 + v1;
    if (base + 3 < N) rp[base + 3] = excl + v0 + v1 + v2;
    if (t == 255) bsum[blockIdx.x] = tsum[255];
}

__global__ void scan2(int* __restrict__ bsum, int NB) {
    __shared__ int s[256];
    int t = threadIdx.x;
    int v = (t < NB) ? bsum[t] : 0;
    s[t] = v;
    __syncthreads();
    for (int off = 1; off < 256; off <<= 1) {
        int y = (t >= off) ? s[t - off] : 0;
        __syncthreads();
        s[t] += y;
        __syncthreads();
    }
    if (t < NB) bsum[t] = s[t] - v;
}

__global__ void scan3(int* __restrict__ rp, const int* __restrict__ bsum,
                      int* __restrict__ bcur, int N, int E) {
    int i = blockIdx.x * 256 + threadIdx.x;
    if (i < N) {
        int v = rp[i] + bsum[i >> 10];
        rp[i] = v;
        if ((i & (BDSTS - 1)) == 0) bcur[i >> SHIFT] = v;
    }
    if (i == 0) rp[N] = E;
}

// ---------------- S1: LDS-staged bucket scatter ----------------
__launch_bounds__(256)
__global__ void bucket_scatter(const int* __restrict__ gg_src, const int* __restrict__ gg_dst,
                               const int* __restrict__ dg_src, const int* __restrict__ dg_dst,
                               int* __restrict__ bcur, unsigned int* __restrict__ colPacked) {
    __shared__ int cnt[256], scanE[256], gbase[256], cursor[256];
    __shared__ unsigned int sorted[S1_CH];
    __shared__ unsigned char bof[S1_CH];
    int t = threadIdx.x;
    cnt[t] = 0;
    __syncthreads();
    int base = blockIdx.x * S1_CH;
    for (int k = 0; k < S1_CH; k += 256) {
        int e = base + k + t;
        if (e < EALL) {
            int dn = (e < EGG) ? gg_dst[e] : (NG + dg_dst[e - EGG]);
            atomicAdd(&cnt[dn >> SHIFT], 1);
        }
    }
    __syncthreads();
    int v = cnt[t];
    __shared__ int ss[256];
    ss[t] = v;
    __syncthreads();
    for (int off = 1; off < 256; off <<= 1) {
        int y = (t >= off) ? ss[t - off] : 0;
        __syncthreads();
        ss[t] += y;
        __syncthreads();
    }
    scanE[t] = ss[t] - v;
    cursor[t] = ss[t] - v;
    if (t < NBUK && v > 0) gbase[t] = atomicAdd(&bcur[t], v);
    __syncthreads();
    for (int k = 0; k < S1_CH; k += 256) {
        int e = base + k + t;
        if (e < EALL) {
            int s, dn;
            if (e < EGG) { s = gg_src[e]; dn = gg_dst[e]; }
            else         { s = dg_src[e - EGG]; dn = NG + dg_dst[e - EGG]; }
            int b = dn >> SHIFT;
            int slot = atomicAdd(&cursor[b], 1);
            sorted[slot] = ((unsigned int)s << SHIFT) | (unsigned int)(dn & (BDSTS - 1));
            bof[slot] = (unsigned char)b;
        }
    }
    __syncthreads();
    int total = ss[255];
    for (int f = t; f < total; f += 256) {
        int b = bof[f];
        colPacked[gbase[b] + (f - scanE[b])] = sorted[f];
    }
}

// ---------------- S2: bucket-local counting sort ----------------
__launch_bounds__(256)
__global__ void bucket_sort(const unsigned int* __restrict__ colPacked,
                            const int* __restrict__ rp, int* __restrict__ col) {
    __shared__ int lcur[BDSTS];
    int b = blockIdx.x;
    int d0 = b << SHIFT;
    int dEnd = min(d0 + BDSTS, NALL);
    int nd = dEnd - d0;
    for (int i = threadIdx.x; i < nd; i += 256) lcur[i] = rp[d0 + i];
    __syncthreads();
    int ebase = rp[d0];
    int eend  = rp[dEnd];
    for (int i = ebase + threadIdx.x; i < eend; i += 256) {
        unsigned int p = colPacked[i];
        int dlow = (int)(p & (BDSTS - 1));
        int s    = (int)(p >> SHIFT);
        int pos = atomicAdd(&lcur[dlow], 1);
        col[pos] = s;
    }
}

// ---------------- fused GAT gather v3: one wave per dst node, 4-deep load pipeline ----------------
__launch_bounds__(256)
__global__ void gat_gather(const int* __restrict__ rp, const int* __restrict__ col,
                           const float* __restrict__ a_s, const float* __restrict__ a_d,
                           const float* __restrict__ xsrc, float* __restrict__ outb,
                           int ndst) {
    int wid = (blockIdx.x * 256 + threadIdx.x) >> 6;
    int l = threadIdx.x & 63;
    if (wid >= ndst) return;
    int d = wid;
    int base = rp[d];
    int deg = rp[d + 1] - base;

    int hl = l & 7;
    int g  = l >> 3;
    float adl = a_d[d * 8 + hl];
    float m = -1e30f, ssum = 0.f;
    for (int c0 = 0; c0 < deg; c0 += 64) {
        int myi = c0 + l;
        int colreg = (myi < deg) ? col[base + myi] : 0;
        int lim = min(deg - c0, 64);
        for (int t = g; t < lim; t += 8) {
            int s = __shfl(colreg, t);
            float a = a_s[s * 8 + hl] + adl;
            a = a > 0.f ? a : 0.2f * a;
            float nm = fmaxf(m, a);
            ssum = ssum * __expf(m - nm) + __expf(a - nm);
            m = nm;
        }
    }
    for (int off = 8; off < 64; off <<= 1) {
        float m2 = __shfl_xor(m, off);
        float s2 = __shfl_xor(ssum, off);
        float nm = fmaxf(m, m2);
        ssum = ssum * __expf(m - nm) + s2 * __expf(m2 - nm);
        m = nm;
    }
    float rsc = 1.f / (ssum + 1e-16f);

    int half = l >> 5;
    int cl = l & 31;
    int hc = cl >> 2;
    uint32_t colbyte = (uint32_t)cl << 4;
    float4 acc = {0.f, 0.f, 0.f, 0.f};
    for (int c0 = 0; c0 < deg; c0 += 64) {
        int myi = c0 + l;
        int colreg = (myi < deg) ? col[base + myi] : 0;
        int lim = min(deg - c0, 64);
        for (int j8 = 0; j8 < lim; j8 += 8) {
            float alpha;
            {
                int s = __shfl(colreg, j8 + g);
                float a = a_s[s * 8 + hl] + adl;
                a = a > 0.f ? a : 0.2f * a;
                alpha = __expf(a - m) * rsc;
            }
            int jlim = min(lim - j8, 8);
            if (jlim == 8) {
                // 4 independent row loads in flight before any FMA
                int s0 = __shfl(colreg, j8 + 0 + half);
                int s1 = __shfl(colreg, j8 + 2 + half);
                int s2 = __shfl(colreg, j8 + 4 + half);
                int s3 = __shfl(colreg, j8 + 6 + half);
                const float4 x0 = *(const float4*)((const char*)xsrc + (((size_t)(uint32_t)s0 << 9) + colbyte));
                const float4 x1 = *(const float4*)((const char*)xsrc + (((size_t)(uint32_t)s1 << 9) + colbyte));
                const float4 x2 = *(const float4*)((const char*)xsrc + (((size_t)(uint32_t)s2 << 9) + colbyte));
                const float4 x3 = *(const float4*)((const char*)xsrc + (((size_t)(uint32_t)s3 << 9) + colbyte));
                float al0 = __shfl(alpha, ((0 + half) << 3) + hc);
                float al1 = __shfl(alpha, ((2 + half) << 3) + hc);
                float al2 = __shfl(alpha, ((4 + half) << 3) + hc);
                float al3 = __shfl(alpha, ((6 + half) << 3) + hc);
                acc.x += al0 * x0.x + al1 * x1.x + al2 * x2.x + al3 * x3.x;
                acc.y += al0 * x0.y + al1 * x1.y + al2 * x2.y + al3 * x3.y;
                acc.z += al0 * x0.z + al1 * x1.z + al2 * x2.z + al3 * x3.z;
                acc.w += al0 * x0.w + al1 * x1.w + al2 * x2.w + al3 * x3.w;
            } else {
                int jj = 0;
                for (; jj + 2 <= jlim; jj += 2) {
                    int jrel = jj + half;
                    int s = __shfl(colreg, j8 + jrel);
                    float al = __shfl(alpha, (jrel << 3) + hc);
                    const float4 xv = *(const float4*)((const char*)xsrc +
                                        (((size_t)(uint32_t)s << 9) + colbyte));
                    acc.x += al * xv.x; acc.y += al * xv.y;
                    acc.z += al * xv.z; acc.w += al * xv.w;
                }
                if (jj < jlim) {
                    int s = __shfl(colreg, j8 + jj);
                    float al = __shfl(alpha, (jj << 3) + hc);
                    if (half == 0) {
                        const float4 xv = *(const float4*)((const char*)xsrc +
                                            (((size_t)(uint32_t)s << 9) + colbyte));
                        acc.x += al * xv.x; acc.y += al * xv.y;
                        acc.z += al * xv.z; acc.w += al * xv.w;
                    }
                }
            }
        }
    }
    acc.x += __shfl_xor(acc.x, 32);
    acc.y += __shfl_xor(acc.y, 32);
    acc.z += __shfl_xor(acc.z, 32);
    acc.w += __shfl_xor(acc.w, 32);
    if (half == 0)
        *(float4*)&outb[(size_t)d * 128 + cl * 4] = acc;
}

// ---------------- semantic softmax (2 scores) ----------------
__global__ void score_attn(const float* __restrict__ kpart, const float* __restrict__ q,
                           float* __restrict__ attn) {
    __shared__ float r0[128], r1[128];
    int t = threadIdx.x;
    r0[t] = q[t] * kpart[t];
    r1[t] = q[t] * kpart[128 + t];
    __syncthreads();
    for (int s = 64; s > 0; s >>= 1) {
        if (t < s) { r0[t] += r0[t + s]; r1[t] += r1[t + s]; }
        __syncthreads();
    }
    if (t == 0) {
        float s0 = r0[0] / (float)NG, s1 = r1[0] / (float)NG;
        float mx = fmaxf(s0, s1);
        float e0 = expf(s0 - mx), e1 = expf(s1 - mx);
        attn[0] = e0 / (e0 + e1);
        attn[1] = e1 / (e0 + e1);
    }
}

// ---------------- fused combine + final linear ----------------
__launch_bounds__(256)
__global__ void final_lin(const float* __restrict__ gg, const float* __restrict__ dgb,
                          const float* __restrict__ attn, const float* __restrict__ lin_w,
                          const float* __restrict__ lin_b, float* __restrict__ outp) {
    int wid = (blockIdx.x * 256 + threadIdx.x) >> 6;
    int l = threadIdx.x & 63;
    if (wid >= NG) return;
    float a0 = attn[0], a1 = attn[1];
    float2 gv = *(const float2*)&gg[(size_t)wid * 128 + l * 2];
    float2 dv = *(const float2*)&dgb[(size_t)wid * 128 + l * 2];
    float fx = a0 * fmaxf(gv.x, 0.f) + a1 * fmaxf(dv.x, 0.f);
    float fy = a0 * fmaxf(gv.y, 0.f) + a1 * fmaxf(dv.y, 0.f);
    float2 w0 = *(const float2*)&lin_w[l * 2];
    float2 w1 = *(const float2*)&lin_w[128 + l * 2];
    float p0 = fx * w0.x + fy * w0.y;
    float p1 = fx * w1.x + fy * w1.y;
    for (int off = 32; off > 0; off >>= 1) {
        p0 += __shfl_down(p0, off);
        p1 += __shfl_down(p1, off);
    }
    if (l == 0) {
        float2 o;
        o.x = p0 + lin_b[0];
        o.y = p1 + lin_b[1];
        *(float2*)&outp[wid * 2] = o;
    }
}

extern "C" void kernel_launch(void* const* d_in, const int* in_sizes, int n_in,
                              void* d_out, int out_size, void* d_ws, size_t ws_size,
                              hipStream_t stream) {
    const float* x_gene    = (const float*)d_in[0];
    const float* x_disease = (const float*)d_in[1];
    const int*   edge_gg   = (const int*)d_in[2];
    const int*   edge_dg   = (const int*)d_in[3];
    const float* pg_w      = (const float*)d_in[4];
    const float* pg_b      = (const float*)d_in[5];
    const float* pd_w      = (const float*)d_in[6];
    const float* pd_b      = (const float*)d_in[7];
    const float* att_src_gg= (const float*)d_in[8];
    const float* att_dst_gg= (const float*)d_in[9];
    const float* att_src_dg= (const float*)d_in[10];
    const float* att_dst_dg= (const float*)d_in[11];
    const float* k_lin_w   = (const float*)d_in[12];
    const float* k_lin_b   = (const float*)d_in[13];
    const float* q         = (const float*)d_in[14];
    const float* lin_w     = (const float*)d_in[15];
    const float* lin_b     = (const float*)d_in[16];
    float* out = (float*)d_out;
    float* ws  = (float*)d_ws;

    float* out_gg = ws + OFF_OUT_GG;
    float* out_dg = ws + OFF_OUT_DG;
    unsigned int* colPacked = (unsigned int*)(ws + OFF_OUT_GG);  // overlay
    float* xg     = ws + OFF_XG;
    float* xd     = ws + OFF_XD;
    float* a_src_gg = ws + OFF_ASG;
    float* a_dst_gg = ws + OFF_ADG;
    float* a_dst_dg = ws + OFF_ADD;
    float* a_src_dg = ws + OFF_ASD;
    float* kpart  = ws + OFF_KPART;
    float* attn   = ws + OFF_ATTN;
    int* deg  = (int*)(ws + OFF_DEG);
    int* rp   = (int*)(ws + OFF_RP);
    int* bcur = (int*)(ws + OFF_BCUR);
    int* bsum = (int*)(ws + OFF_BSUM);
    int* col  = (int*)(ws + OFF_COL);

    const int* gg_src = edge_gg;
    const int* gg_dst = edge_gg + EGG;
    const int* dg_src = edge_dg;
    const int* dg_dst = edge_dg + EDG;

    // 1. zero kpart + degree arrays
    hipLaunchKernelGGL(init_zero_k, dim3((ZERO_CNT + 255) / 256), dim3(256), 0, stream,
                       ws + ZERO_BASE, ZERO_CNT);
    // 2. projections with fused att-logit epilogue (VALU, known-good)
    hipLaunchKernelGGL(proj_gemm_fused, dim3(512), dim3(256), 0, stream,
                       x_gene, pg_w, pg_b, xg, NG, 3,
                       att_src_gg, att_dst_gg, att_dst_dg, a_src_gg, a_dst_gg, a_dst_dg);
    hipLaunchKernelGGL(proj_gemm_fused, dim3(512), dim3(256), 0, stream,
                       x_disease, pd_w, pd_b, xd, ND, 1,
                       att_src_dg, (const float*)nullptr, (const float*)nullptr,
                       a_src_dg, (float*)nullptr, (float*)nullptr);
    // 3. CSR row pointers
    hipLaunchKernelGGL(count_all, dim3((EALL + 255) / 256), dim3(256), 0, stream,
                       gg_dst, dg_dst, deg);
    hipLaunchKernelGGL(scan1, dim3((NALL + 1023) / 1024), dim3(256), 0, stream, deg, rp, bsum, NALL);
    hipLaunchKernelGGL(scan2, dim3(1), dim3(256), 0, stream, bsum, (NALL + 1023) / 1024);
    hipLaunchKernelGGL(scan3, dim3((NALL + 255) / 256), dim3(256), 0, stream, rp, bsum, bcur, NALL, EALL);
    // 4. two-level bucket sort into CSR col
    hipLaunchKernelGGL(bucket_scatter, dim3((EALL + S1_CH - 1) / S1_CH), dim3(256), 0, stream,
                       gg_src, gg_dst, dg_src, dg_dst, bcur, colPacked);
    hipLaunchKernelGGL(bucket_sort, dim3(NBUK), dim3(256), 0, stream, colPacked, rp, col);
    // 5. fused gathers (out_gg overwrites colPacked overlay — dead by now)
    hipLaunchKernelGGL(gat_gather, dim3((NG + 3) / 4), dim3(256), 0, stream,
                       rp, col, a_src_gg, a_dst_gg, xg, out_gg, NG);
    hipLaunchKernelGGL(gat_gather, dim3((NG + 3) / 4), dim3(256), 0, stream,
                       rp + NG, col, a_src_dg, a_dst_dg, xd, out_dg, NG);
    // 6. semantic attention (bf16 MFMA kmean, v2)
    hipLaunchKernelGGL(kmean_mfma, dim3((NG + 127) / 128), dim3(256), 0, stream,
                       out_gg, k_lin_w, k_lin_b, kpart, NG);
    hipLaunchKernelGGL(kmean_mfma, dim3((NG + 127) / 128), dim3(256), 0, stream,
                       out_dg, k_lin_w, k_lin_b, kpart + 128, NG);
    hipLaunchKernelGGL(score_attn, dim3(1), dim3(128), 0, stream, kpart, q, attn);
    // 7. fused combine + final linear
    hipLaunchKernelGGL(final_lin, dim3((NG + 3) / 4), dim3(256), 0, stream,
                       out_gg, out_dg, attn, lin_w, lin_b, out);
}

// Round 7
// 610.698 us; speedup vs baseline: 1.2625x; 1.2169x over previous
//
#include <hip/hip_runtime.h>
#include <math.h>

#define NG 100000
#define ND 50000
#define EGG 1600000
#define EDG 800000
#define EALL (EGG + EDG)
#define NALL (NG + NG)
#define HID 128
#define NH 8

// bucket sort params
#define SHIFT 11
#define BDSTS (1 << SHIFT)
#define NBUK  ((NALL + BDSTS - 1) / BDSTS)   // 98
#define S1_CH 6144
#define KM_HALF ((NG + 127) / 128)           // 782 blocks per metapath

// ---------------- workspace layout (4-byte element offsets) ----------------
#define OFF_OUT_GG 0UL          // 12,800,000  (colPacked overlays until gat_gather)
#define OFF_OUT_DG 12800000UL   // 12,800,000
#define OFF_XG     25600000UL   // bf16 [NG][128] = 3,200,000 floats-worth
#define OFF_XD     38400000UL   // bf16 [ND][128] = 1,600,000 floats-worth
#define OFF_ASG    44800000UL   //    800,000  a_src_gg [NG,8]
#define OFF_ADG    45600000UL   //    800,000  a_dst_gg [NG,8]
#define OFF_ADD    46400000UL   //    800,000  a_dst_dg [NG,8]
#define OFF_ASD    47200000UL   //    400,000  a_src_dg [ND,8]
#define OFF_KPART  47600000UL   //        256  (zero-init)
#define OFF_DEG    47600256UL   //    200,000  (zero-init)
#define ZERO_BASE  OFF_KPART
#define ZERO_CNT   200256
#define OFF_ATTN   47800256UL   //          2 (+pad)
#define OFF_RP     47800272UL   //    200,001 (+pad)
#define OFF_BCUR   48000280UL   //        256
#define OFF_BSUM   48200280UL   //        256
#define OFF_COL    48200536UL   //  2,400,000
// end: 50,600,536 elems = 202.4 MB

typedef float  f32x4  __attribute__((ext_vector_type(4)));
typedef short  bf16x8 __attribute__((ext_vector_type(8)));
#define MFMA(a, b, c) __builtin_amdgcn_mfma_f32_16x16x32_bf16(a, b, c, 0, 0, 0)

__device__ __forceinline__ unsigned short bf16_rne(float f) {
    unsigned u = __float_as_uint(f);
    u += 0x7FFFu + ((u >> 16) & 1u);
    return (unsigned short)(u >> 16);
}
__device__ __forceinline__ float fast_tanh(float x) {
    x = fminf(fmaxf(x, -15.f), 15.f);
    float t = __expf(2.f * x);
    return (t - 1.f) / (t + 1.f);
}

// ---------------- init ----------------
__global__ void init_zero_k(float* __restrict__ p, int n) {
    int i = blockIdx.x * 256 + threadIdx.x;
    if (i < n) p[i] = 0.f;
}

// ---------------- projection GEMM + fused logits; x rows stored as bf16 only ----------------
__launch_bounds__(256)
__global__ void proj_gemm_fused(const float* __restrict__ x, const float* __restrict__ W,
                                const float* __restrict__ bias,
                                unsigned short* __restrict__ xbf,   // [N][128] bf16
                                int N, int natt,
                                const float* __restrict__ att0, const float* __restrict__ att1,
                                const float* __restrict__ att2,
                                float* __restrict__ o0, float* __restrict__ o1,
                                float* __restrict__ o2) {
    __shared__ float Ws[128 * 128];       // Ws[i*128 + j] = W[j*128 + i]
    __shared__ float rows_s[32][128];
    for (int idx = threadIdx.x; idx < 128 * 128; idx += 256) {
        int i = idx >> 7, j = idx & 127;
        Ws[i * 128 + j] = W[j * 128 + i];
    }
    int g = threadIdx.x >> 5;   // group 0..7, 4 rows each
    int l = threadIdx.x & 31;
    int g4 = g * 4;
    float4 bvec = *(const float4*)&bias[l * 4];
    float4 at0 = {0,0,0,0}, at1 = {0,0,0,0}, at2 = {0,0,0,0};
    if (natt > 0) at0 = *(const float4*)&att0[l * 4];
    if (natt > 1) at1 = *(const float4*)&att1[l * 4];
    if (natt > 2) at2 = *(const float4*)&att2[l * 4];
    __syncthreads();
    for (int base = blockIdx.x * 32; base < N; base += gridDim.x * 32) {
        int r0 = base + g4;
        #pragma unroll
        for (int k = 0; k < 4; k++) {
            int n = r0 + k;
            if (n < N)
                *(float4*)&rows_s[g4 + k][l * 4] = *(const float4*)&x[(size_t)n * 128 + l * 4];
        }
        __syncthreads();
        float4 acc0 = bvec, acc1 = bvec, acc2 = bvec, acc3 = bvec;
        #pragma unroll 4
        for (int i = 0; i < 128; i++) {
            float4 w = *(const float4*)&Ws[i * 128 + l * 4];
            float x0 = rows_s[g4 + 0][i];
            float x1 = rows_s[g4 + 1][i];
            float x2 = rows_s[g4 + 2][i];
            float x3 = rows_s[g4 + 3][i];
            acc0.x += x0 * w.x; acc0.y += x0 * w.y; acc0.z += x0 * w.z; acc0.w += x0 * w.w;
            acc1.x += x1 * w.x; acc1.y += x1 * w.y; acc1.z += x1 * w.z; acc1.w += x1 * w.w;
            acc2.x += x2 * w.x; acc2.y += x2 * w.y; acc2.z += x2 * w.z; acc2.w += x2 * w.w;
            acc3.x += x3 * w.x; acc3.y += x3 * w.y; acc3.z += x3 * w.z; acc3.w += x3 * w.w;
        }
        #define ROW_EPI(ACC, KK) do { \
            int n = r0 + KK; \
            if (n < N) { \
                uint2 pk; \
                pk.x = ((unsigned)bf16_rne(ACC.y) << 16) | bf16_rne(ACC.x); \
                pk.y = ((unsigned)bf16_rne(ACC.w) << 16) | bf16_rne(ACC.z); \
                *(uint2*)&xbf[(size_t)n * 128 + l * 4] = pk; \
                if (natt > 0) { \
                    float p = ACC.x*at0.x + ACC.y*at0.y + ACC.z*at0.z + ACC.w*at0.w; \
                    p += __shfl_xor(p, 1); p += __shfl_xor(p, 2); \
                    if ((l & 3) == 0) o0[n * 8 + (l >> 2)] = p; } \
                if (natt > 1) { \
                    float p = ACC.x*at1.x + ACC.y*at1.y + ACC.z*at1.z + ACC.w*at1.w; \
                    p += __shfl_xor(p, 1); p += __shfl_xor(p, 2); \
                    if ((l & 3) == 0) o1[n * 8 + (l >> 2)] = p; } \
                if (natt > 2) { \
                    float p = ACC.x*at2.x + ACC.y*at2.y + ACC.z*at2.z + ACC.w*at2.w; \
                    p += __shfl_xor(p, 1); p += __shfl_xor(p, 2); \
                    if ((l & 3) == 0) o2[n * 8 + (l >> 2)] = p; } \
            } } while (0)
        ROW_EPI(acc0, 0); ROW_EPI(acc1, 1); ROW_EPI(acc2, 2); ROW_EPI(acc3, 3);
        #undef ROW_EPI
        __syncthreads();
    }
}

// ---------------- kmean via bf16 MFMA (merged: gg blocks then dg blocks) ----------------
__launch_bounds__(256)
__global__ void kmean_mfma(const float* __restrict__ srcA, const float* __restrict__ srcB,
                           const float* __restrict__ W, const float* __restrict__ bias,
                           float* __restrict__ kp) {
    __shared__ bf16x8 Bs[8 * 4 * 64];   // 32 KB fragment layout
    for (int w = threadIdx.x; w < 8 * 4 * 64 * 4; w += 256) {
        int j2 = w & 3, slot = w >> 2;
        int lane = slot & 63, kc = (slot >> 6) & 3, ct = slot >> 8;
        int k = kc * 32 + (lane >> 4) * 8 + j2 * 2;
        int row = ct * 16 + (lane & 15);
        float f0 = W[row * 128 + k], f1 = W[row * 128 + k + 1];
        ((unsigned*)&Bs[slot])[j2] = ((unsigned)bf16_rne(f1) << 16) | bf16_rne(f0);
    }
    __syncthreads();
    int half = blockIdx.x >= KM_HALF;
    const float* src = half ? srcB : srcA;
    float* kpp = half ? (kp + 128) : kp;
    int rb = (half ? blockIdx.x - KM_HALF : blockIdx.x) * 128;
    int wv = threadIdx.x >> 6, l = threadIdx.x & 63;
    int q = l >> 4, c16 = l & 15;
    float csum[8];
    #pragma unroll
    for (int i = 0; i < 8; i++) csum[i] = 0.f;
    {
        int rw = rb + wv * 32;
        bf16x8 a0f[4], a1f[4];
        #pragma unroll
        for (int t = 0; t < 2; t++) {
            int row = rw + t * 16 + c16;
            bool ok = row < NG;
            const float* xr = &src[(size_t)row * 128 + q * 8];
            #pragma unroll
            for (int kc = 0; kc < 4; kc++) {
                f32x4 v0 = {0,0,0,0}, v1 = {0,0,0,0};
                if (ok) {
                    v0 = *(const f32x4*)(xr + kc * 32);
                    v1 = *(const f32x4*)(xr + kc * 32 + 4);
                }
                bf16x8 f;
                f[0] = (short)bf16_rne(fmaxf(v0.x, 0.f));
                f[1] = (short)bf16_rne(fmaxf(v0.y, 0.f));
                f[2] = (short)bf16_rne(fmaxf(v0.z, 0.f));
                f[3] = (short)bf16_rne(fmaxf(v0.w, 0.f));
                f[4] = (short)bf16_rne(fmaxf(v1.x, 0.f));
                f[5] = (short)bf16_rne(fmaxf(v1.y, 0.f));
                f[6] = (short)bf16_rne(fmaxf(v1.z, 0.f));
                f[7] = (short)bf16_rne(fmaxf(v1.w, 0.f));
                if (t == 0) a0f[kc] = f; else a1f[kc] = f;
            }
        }
        #pragma unroll
        for (int ct = 0; ct < 8; ct++) {
            f32x4 aA0 = {0,0,0,0}, aB0 = {0,0,0,0}, aA1 = {0,0,0,0}, aB1 = {0,0,0,0};
            #pragma unroll
            for (int kc = 0; kc < 4; kc++) {
                bf16x8 bh = Bs[(ct * 4 + kc) * 64 + l];
                if (kc & 1) { aB0 = MFMA(a0f[kc], bh, aB0); aB1 = MFMA(a1f[kc], bh, aB1); }
                else        { aA0 = MFMA(a0f[kc], bh, aA0); aA1 = MFMA(a1f[kc], bh, aA1); }
            }
            f32x4 d0 = aA0 + aB0, d1 = aA1 + aB1;
            float bv = bias[ct * 16 + c16];
            int row0 = rw + q * 4;
            #pragma unroll
            for (int r = 0; r < 4; r++)
                if (row0 + r < NG) csum[ct] += fast_tanh(d0[r] + bv);
            int row1 = rw + 16 + q * 4;
            #pragma unroll
            for (int r = 0; r < 4; r++)
                if (row1 + r < NG) csum[ct] += fast_tanh(d1[r] + bv);
        }
    }
    #pragma unroll
    for (int ct = 0; ct < 8; ct++) {
        float v = csum[ct];
        v += __shfl_xor(v, 16);
        v += __shfl_xor(v, 32);
        if (l < 16) atomicAdd(&kpp[ct * 16 + l], v);
    }
}

// ---------------- CSR build ----------------
__global__ void count_all(const int* __restrict__ gg_dst, const int* __restrict__ dg_dst,
                          int* __restrict__ deg) {
    int e = blockIdx.x * 256 + threadIdx.x;
    if (e < EGG) atomicAdd(&deg[gg_dst[e]], 1);
    else if (e < EALL) atomicAdd(&deg[NG + dg_dst[e - EGG]], 1);
}

__global__ void scan1(const int* __restrict__ deg, int* __restrict__ rp,
                      int* __restrict__ bsum, int N) {
    __shared__ int tsum[256];
    int t = threadIdx.x;
    int base = blockIdx.x * 1024 + t * 4;
    int v0 = 0, v1 = 0, v2 = 0, v3 = 0;
    if (base + 0 < N) v0 = deg[base + 0];
    if (base + 1 < N) v1 = deg[base + 1];
    if (base + 2 < N) v2 = deg[base + 2];
    if (base + 3 < N) v3 = deg[base + 3];
    int tot = v0 + v1 + v2 + v3;
    tsum[t] = tot;
    __syncthreads();
    for (int off = 1; off < 256; off <<= 1) {
        int y = (t >= off) ? tsum[t - off] : 0;
        __syncthreads();
        tsum[t] += y;
        __syncthreads();
    }
    int excl = tsum[t] - tot;
    if (base + 0 < N) rp[base + 0] = excl;
    if (base + 1 < N) rp[base + 1] = excl + v0;
    if (base + 2 < N) rp[base + 2] = excl + v0 + v1;
    if (base + 3 < N) rp[base + 3] = excl + v0 + v1 + v2;
    if (t == 255) bsum[blockIdx.x] = tsum[255];
}

__global__ void scan2(int* __restrict__ bsum, int NB) {
    __shared__ int s[256];
    int t = threadIdx.x;
    int v = (t < NB) ? bsum[t] : 0;
    s[t] = v;
    __syncthreads();
    for (int off = 1; off < 256; off <<= 1) {
        int y = (t >= off) ? s[t - off] : 0;
        __syncthreads();
        s[t] += y;
        __syncthreads();
    }
    if (t < NB) bsum[t] = s[t] - v;
}

__global__ void scan3(int* __restrict__ rp, const int* __restrict__ bsum,
                      int* __restrict__ bcur, int N, int E) {
    int i = blockIdx.x * 256 + threadIdx.x;
    if (i < N) {
        int v = rp[i] + bsum[i >> 10];
        rp[i] = v;
        if ((i & (BDSTS - 1)) == 0) bcur[i >> SHIFT] = v;
    }
    if (i == 0) rp[N] = E;
}

// ---------------- S1: LDS-staged bucket scatter ----------------
__launch_bounds__(256)
__global__ void bucket_scatter(const int* __restrict__ gg_src, const int* __restrict__ gg_dst,
                               const int* __restrict__ dg_src, const int* __restrict__ dg_dst,
                               int* __restrict__ bcur, unsigned int* __restrict__ colPacked) {
    __shared__ int cnt[256], scanE[256], gbase[256], cursor[256];
    __shared__ unsigned int sorted[S1_CH];
    __shared__ unsigned char bof[S1_CH];
    int t = threadIdx.x;
    cnt[t] = 0;
    __syncthreads();
    int base = blockIdx.x * S1_CH;
    for (int k = 0; k < S1_CH; k += 256) {
        int e = base + k + t;
        if (e < EALL) {
            int dn = (e < EGG) ? gg_dst[e] : (NG + dg_dst[e - EGG]);
            atomicAdd(&cnt[dn >> SHIFT], 1);
        }
    }
    __syncthreads();
    int v = cnt[t];
    __shared__ int ss[256];
    ss[t] = v;
    __syncthreads();
    for (int off = 1; off < 256; off <<= 1) {
        int y = (t >= off) ? ss[t - off] : 0;
        __syncthreads();
        ss[t] += y;
        __syncthreads();
    }
    scanE[t] = ss[t] - v;
    cursor[t] = ss[t] - v;
    if (t < NBUK && v > 0) gbase[t] = atomicAdd(&bcur[t], v);
    __syncthreads();
    for (int k = 0; k < S1_CH; k += 256) {
        int e = base + k + t;
        if (e < EALL) {
            int s, dn;
            if (e < EGG) { s = gg_src[e]; dn = gg_dst[e]; }
            else         { s = dg_src[e - EGG]; dn = NG + dg_dst[e - EGG]; }
            int b = dn >> SHIFT;
            int slot = atomicAdd(&cursor[b], 1);
            sorted[slot] = ((unsigned int)s << SHIFT) | (unsigned int)(dn & (BDSTS - 1));
            bof[slot] = (unsigned char)b;
        }
    }
    __syncthreads();
    int total = ss[255];
    for (int f = t; f < total; f += 256) {
        int b = bof[f];
        colPacked[gbase[b] + (f - scanE[b])] = sorted[f];
    }
}

// ---------------- S2: bucket-local counting sort ----------------
__launch_bounds__(256)
__global__ void bucket_sort(const unsigned int* __restrict__ colPacked,
                            const int* __restrict__ rp, int* __restrict__ col) {
    __shared__ int lcur[BDSTS];
    int b = blockIdx.x;
    int d0 = b << SHIFT;
    int dEnd = min(d0 + BDSTS, NALL);
    int nd = dEnd - d0;
    for (int i = threadIdx.x; i < nd; i += 256) lcur[i] = rp[d0 + i];
    __syncthreads();
    int ebase = rp[d0];
    int eend  = rp[dEnd];
    for (int i = ebase + threadIdx.x; i < eend; i += 256) {
        unsigned int p = colPacked[i];
        int dlow = (int)(p & (BDSTS - 1));
        int s    = (int)(p >> SHIFT);
        int pos = atomicAdd(&lcur[dlow], 1);
        col[pos] = s;
    }
}

// ---------------- fused GAT gather v4: bf16 rows, gg+dg merged, one wave/dst ----------------
__launch_bounds__(256)
__global__ void gat_gather_all(const int* __restrict__ rp, const int* __restrict__ col,
                               const float* __restrict__ as_gg, const float* __restrict__ ad_gg,
                               const unsigned short* __restrict__ xg_bf,
                               const float* __restrict__ as_dg, const float* __restrict__ ad_dg,
                               const unsigned short* __restrict__ xd_bf,
                               float* __restrict__ out_gg, float* __restrict__ out_dg) {
    int wid = (blockIdx.x * 256 + threadIdx.x) >> 6;
    int l = threadIdx.x & 63;
    if (wid >= NALL) return;
    int isdg = wid >= NG;
    int d = isdg ? wid - NG : wid;
    const float* a_s = isdg ? as_dg : as_gg;
    const float* a_d = isdg ? ad_dg : ad_gg;
    const unsigned short* xbf = isdg ? xd_bf : xg_bf;
    float* outb = (isdg ? out_dg : out_gg) + (size_t)d * 128;

    int base = rp[wid];
    int deg = rp[wid + 1] - base;

    int hl = l & 7;
    int g  = l >> 3;
    float adl = a_d[d * 8 + hl];
    float m = -1e30f, ssum = 0.f;
    for (int c0 = 0; c0 < deg; c0 += 64) {
        int myi = c0 + l;
        int colreg = (myi < deg) ? col[base + myi] : 0;
        int lim = min(deg - c0, 64);
        for (int t = g; t < lim; t += 8) {
            int s = __shfl(colreg, t);
            float a = a_s[s * 8 + hl] + adl;
            a = a > 0.f ? a : 0.2f * a;
            float nm = fmaxf(m, a);
            ssum = ssum * __expf(m - nm) + __expf(a - nm);
            m = nm;
        }
    }
    for (int off = 8; off < 64; off <<= 1) {
        float m2 = __shfl_xor(m, off);
        float s2 = __shfl_xor(ssum, off);
        float nm = fmaxf(m, m2);
        ssum = ssum * __expf(m - nm) + s2 * __expf(m2 - nm);
        m = nm;
    }
    float rsc = 1.f / (ssum + 1e-16f);   // lane l holds (m, rsc) for head l&7

    // phase 2: quarter q = edge slot (4 edges/iter), cq = col block (8 bf16 cols)
    int q = l >> 4;
    int cq = l & 15;
    int hq = cq >> 1;                    // head of my col block
    uint32_t colbyte = (uint32_t)cq << 4;  // 16 B per col block
    float a0 = 0.f, a1 = 0.f, a2 = 0.f, a3 = 0.f, a4 = 0.f, a5 = 0.f, a6 = 0.f, a7 = 0.f;
    for (int c0 = 0; c0 < deg; c0 += 64) {
        int myi = c0 + l;
        int colreg = (myi < deg) ? col[base + myi] : 0;
        int lim = min(deg - c0, 64);
        for (int j8 = 0; j8 < lim; j8 += 8) {
            float alpha;
            {
                int s = __shfl(colreg, j8 + g);
                float a = a_s[s * 8 + hl] + adl;
                a = a > 0.f ? a : 0.2f * a;
                alpha = __expf(a - m) * rsc;
            }
            int jlim = min(lim - j8, 8);
            #pragma unroll
            for (int sub = 0; sub < 8; sub += 4) {
                int jrel = sub + q;
                int s = __shfl(colreg, j8 + jrel);
                float al = __shfl(alpha, (jrel << 3) + hq);
                al = (jrel < jlim) ? al : 0.f;
                const uint4 rv = *(const uint4*)((const char*)xbf +
                                    (((size_t)(uint32_t)s << 8) + colbyte));
                a0 += al * __uint_as_float(rv.x << 16);
                a1 += al * __uint_as_float(rv.x & 0xffff0000u);
                a2 += al * __uint_as_float(rv.y << 16);
                a3 += al * __uint_as_float(rv.y & 0xffff0000u);
                a4 += al * __uint_as_float(rv.z << 16);
                a5 += al * __uint_as_float(rv.z & 0xffff0000u);
                a6 += al * __uint_as_float(rv.w << 16);
                a7 += al * __uint_as_float(rv.w & 0xffff0000u);
            }
        }
    }
    a0 += __shfl_xor(a0, 16); a0 += __shfl_xor(a0, 32);
    a1 += __shfl_xor(a1, 16); a1 += __shfl_xor(a1, 32);
    a2 += __shfl_xor(a2, 16); a2 += __shfl_xor(a2, 32);
    a3 += __shfl_xor(a3, 16); a3 += __shfl_xor(a3, 32);
    a4 += __shfl_xor(a4, 16); a4 += __shfl_xor(a4, 32);
    a5 += __shfl_xor(a5, 16); a5 += __shfl_xor(a5, 32);
    a6 += __shfl_xor(a6, 16); a6 += __shfl_xor(a6, 32);
    a7 += __shfl_xor(a7, 16); a7 += __shfl_xor(a7, 32);
    if (q == 0) {
        float4 o0 = {a0, a1, a2, a3};
        float4 o1 = {a4, a5, a6, a7};
        *(float4*)&outb[cq * 8] = o0;
        *(float4*)&outb[cq * 8 + 4] = o1;
    }
}

// ---------------- semantic softmax (2 scores) ----------------
__global__ void score_attn(const float* __restrict__ kpart, const float* __restrict__ q,
                           float* __restrict__ attn) {
    __shared__ float r0[128], r1[128];
    int t = threadIdx.x;
    r0[t] = q[t] * kpart[t];
    r1[t] = q[t] * kpart[128 + t];
    __syncthreads();
    for (int s = 64; s > 0; s >>= 1) {
        if (t < s) { r0[t] += r0[t + s]; r1[t] += r1[t + s]; }
        __syncthreads();
    }
    if (t == 0) {
        float s0 = r0[0] / (float)NG, s1 = r1[0] / (float)NG;
        float mx = fmaxf(s0, s1);
        float e0 = expf(s0 - mx), e1 = expf(s1 - mx);
        attn[0] = e0 / (e0 + e1);
        attn[1] = e1 / (e0 + e1);
    }
}

// ---------------- fused combine + final linear ----------------
__launch_bounds__(256)
__global__ void final_lin(const float* __restrict__ gg, const float* __restrict__ dgb,
                          const float* __restrict__ attn, const float* __restrict__ lin_w,
                          const float* __restrict__ lin_b, float* __restrict__ outp) {
    int wid = (blockIdx.x * 256 + threadIdx.x) >> 6;
    int l = threadIdx.x & 63;
    if (wid >= NG) return;
    float a0 = attn[0], a1 = attn[1];
    float2 gv = *(const float2*)&gg[(size_t)wid * 128 + l * 2];
    float2 dv = *(const float2*)&dgb[(size_t)wid * 128 + l * 2];
    float fx = a0 * fmaxf(gv.x, 0.f) + a1 * fmaxf(dv.x, 0.f);
    float fy = a0 * fmaxf(gv.y, 0.f) + a1 * fmaxf(dv.y, 0.f);
    float2 w0 = *(const float2*)&lin_w[l * 2];
    float2 w1 = *(const float2*)&lin_w[128 + l * 2];
    float p0 = fx * w0.x + fy * w0.y;
    float p1 = fx * w1.x + fy * w1.y;
    for (int off = 32; off > 0; off >>= 1) {
        p0 += __shfl_down(p0, off);
        p1 += __shfl_down(p1, off);
    }
    if (l == 0) {
        float2 o;
        o.x = p0 + lin_b[0];
        o.y = p1 + lin_b[1];
        *(float2*)&outp[wid * 2] = o;
    }
}

extern "C" void kernel_launch(void* const* d_in, const int* in_sizes, int n_in,
                              void* d_out, int out_size, void* d_ws, size_t ws_size,
                              hipStream_t stream) {
    const float* x_gene    = (const float*)d_in[0];
    const float* x_disease = (const float*)d_in[1];
    const int*   edge_gg   = (const int*)d_in[2];
    const int*   edge_dg   = (const int*)d_in[3];
    const float* pg_w      = (const float*)d_in[4];
    const float* pg_b      = (const float*)d_in[5];
    const float* pd_w      = (const float*)d_in[6];
    const float* pd_b      = (const float*)d_in[7];
    const float* att_src_gg= (const float*)d_in[8];
    const float* att_dst_gg= (const float*)d_in[9];
    const float* att_src_dg= (const float*)d_in[10];
    const float* att_dst_dg= (const float*)d_in[11];
    const float* k_lin_w   = (const float*)d_in[12];
    const float* k_lin_b   = (const float*)d_in[13];
    const float* q         = (const float*)d_in[14];
    const float* lin_w     = (const float*)d_in[15];
    const float* lin_b     = (const float*)d_in[16];
    float* out = (float*)d_out;
    float* ws  = (float*)d_ws;

    float* out_gg = ws + OFF_OUT_GG;
    float* out_dg = ws + OFF_OUT_DG;
    unsigned int* colPacked = (unsigned int*)(ws + OFF_OUT_GG);  // overlay
    unsigned short* xg_bf = (unsigned short*)(ws + OFF_XG);
    unsigned short* xd_bf = (unsigned short*)(ws + OFF_XD);
    float* a_src_gg = ws + OFF_ASG;
    float* a_dst_gg = ws + OFF_ADG;
    float* a_dst_dg = ws + OFF_ADD;
    float* a_src_dg = ws + OFF_ASD;
    float* kpart  = ws + OFF_KPART;
    float* attn   = ws + OFF_ATTN;
    int* deg  = (int*)(ws + OFF_DEG);
    int* rp   = (int*)(ws + OFF_RP);
    int* bcur = (int*)(ws + OFF_BCUR);
    int* bsum = (int*)(ws + OFF_BSUM);
    int* col  = (int*)(ws + OFF_COL);

    const int* gg_src = edge_gg;
    const int* gg_dst = edge_gg + EGG;
    const int* dg_src = edge_dg;
    const int* dg_dst = edge_dg + EDG;

    // 1. zero kpart + degree arrays
    hipLaunchKernelGGL(init_zero_k, dim3((ZERO_CNT + 255) / 256), dim3(256), 0, stream,
                       ws + ZERO_BASE, ZERO_CNT);
    // 2. projections (bf16 x rows + fused logits)
    hipLaunchKernelGGL(proj_gemm_fused, dim3(512), dim3(256), 0, stream,
                       x_gene, pg_w, pg_b, xg_bf, NG, 3,
                       att_src_gg, att_dst_gg, att_dst_dg, a_src_gg, a_dst_gg, a_dst_dg);
    hipLaunchKernelGGL(proj_gemm_fused, dim3(512), dim3(256), 0, stream,
                       x_disease, pd_w, pd_b, xd_bf, ND, 1,
                       att_src_dg, (const float*)nullptr, (const float*)nullptr,
                       a_src_dg, (float*)nullptr, (float*)nullptr);
    // 3. CSR row pointers
    hipLaunchKernelGGL(count_all, dim3((EALL + 255) / 256), dim3(256), 0, stream,
                       gg_dst, dg_dst, deg);
    hipLaunchKernelGGL(scan1, dim3((NALL + 1023) / 1024), dim3(256), 0, stream, deg, rp, bsum, NALL);
    hipLaunchKernelGGL(scan2, dim3(1), dim3(256), 0, stream, bsum, (NALL + 1023) / 1024);
    hipLaunchKernelGGL(scan3, dim3((NALL + 255) / 256), dim3(256), 0, stream, rp, bsum, bcur, NALL, EALL);
    // 4. two-level bucket sort into CSR col
    hipLaunchKernelGGL(bucket_scatter, dim3((EALL + S1_CH - 1) / S1_CH), dim3(256), 0, stream,
                       gg_src, gg_dst, dg_src, dg_dst, bcur, colPacked);
    hipLaunchKernelGGL(bucket_sort, dim3(NBUK), dim3(256), 0, stream, colPacked, rp, col);
    // 5. merged fused gather (out_gg overwrites colPacked overlay — dead by now)
    hipLaunchKernelGGL(gat_gather_all, dim3((NALL + 3) / 4), dim3(256), 0, stream,
                       rp, col, a_src_gg, a_dst_gg, xg_bf, a_src_dg, a_dst_dg, xd_bf,
                       out_gg, out_dg);
    // 6. semantic attention (merged kmean)
    hipLaunchKernelGGL(kmean_mfma, dim3(KM_HALF * 2), dim3(256), 0, stream,
                       out_gg, out_dg, k_lin_w, k_lin_b, kpart);
    hipLaunchKernelGGL(score_attn, dim3(1), dim3(128), 0, stream, kpart, q, attn);
    // 7. fused combine + final linear
    hipLaunchKernelGGL(final_lin, dim3((NG + 3) / 4), dim3(256), 0, stream,
                       out_gg, out_dg, attn, lin_w, lin_b, out);
}

// Round 8
// 520.017 us; speedup vs baseline: 1.4826x; 1.1744x over previous
//
#include <hip/hip_runtime.h>
#include <math.h>

#define NG 100000
#define ND 50000
#define EGG 1600000
#define EDG 800000
#define EALL (EGG + EDG)
#define NALL (NG + NG)
#define HID 128
#define NH 8

// bucket sort params
#define SHIFT 11
#define BDSTS (1 << SHIFT)
#define NBUK  ((NALL + BDSTS - 1) / BDSTS)   // 98
#define S1_CH 6144
#define KM_HALF ((NG + 127) / 128)           // 782 blocks per metapath

// ---------------- workspace layout (4-byte element offsets) ----------------
#define OFF_OUT_GG 0UL          // 12,800,000  (colPacked overlays until gat_gather)
#define OFF_OUT_DG 12800000UL   // 12,800,000
#define OFF_XG     25600000UL   // bf16 [NG][128] = 3,200,000 floats-worth
#define OFF_XD     38400000UL   // bf16 [ND][128] = 1,600,000 floats-worth
#define OFF_ASG    44800000UL   //    800,000  a_src_gg [NG,8]
#define OFF_ADG    45600000UL   //    800,000  a_dst_gg [NG,8]
#define OFF_ADD    46400000UL   //    800,000  a_dst_dg [NG,8]
#define OFF_ASD    47200000UL   //    400,000  a_src_dg [ND,8]
#define OFF_KPART  47600000UL   //        256  (zero-init)
#define OFF_DEG    47600256UL   //    200,000  (zero-init)
#define ZERO_BASE  OFF_KPART
#define ZERO_CNT   200256
#define OFF_ATTN   47800256UL   //          2 (+pad)
#define OFF_RP     47800272UL   //    200,001 (+pad)
#define OFF_BCUR   48000280UL   //        256
#define OFF_BSUM   48200280UL   //        256
#define OFF_COL    48200536UL   //  2,400,000
// end: 50,600,536 elems = 202.4 MB

typedef float  f32x4  __attribute__((ext_vector_type(4)));
typedef short  bf16x8 __attribute__((ext_vector_type(8)));
#define MFMA(a, b, c) __builtin_amdgcn_mfma_f32_16x16x32_bf16(a, b, c, 0, 0, 0)

__device__ __forceinline__ unsigned short bf16_rne(float f) {
    unsigned u = __float_as_uint(f);
    u += 0x7FFFu + ((u >> 16) & 1u);
    return (unsigned short)(u >> 16);
}
__device__ __forceinline__ float fast_tanh(float x) {
    x = fminf(fmaxf(x, -15.f), 15.f);
    float t = __expf(2.f * x);
    return (t - 1.f) / (t + 1.f);
}
__device__ __forceinline__ bf16x8 cvt_relu(f32x4 v0, f32x4 v1) {
    bf16x8 f;
    f[0] = (short)bf16_rne(fmaxf(v0.x, 0.f));
    f[1] = (short)bf16_rne(fmaxf(v0.y, 0.f));
    f[2] = (short)bf16_rne(fmaxf(v0.z, 0.f));
    f[3] = (short)bf16_rne(fmaxf(v0.w, 0.f));
    f[4] = (short)bf16_rne(fmaxf(v1.x, 0.f));
    f[5] = (short)bf16_rne(fmaxf(v1.y, 0.f));
    f[6] = (short)bf16_rne(fmaxf(v1.z, 0.f));
    f[7] = (short)bf16_rne(fmaxf(v1.w, 0.f));
    return f;
}

// ---------------- init ----------------
__global__ void init_zero_k(float* __restrict__ p, int n) {
    int i = blockIdx.x * 256 + threadIdx.x;
    if (i < n) p[i] = 0.f;
}

// ---------------- projection GEMM + fused logits; x rows stored as bf16 only ----------------
__launch_bounds__(256)
__global__ void proj_gemm_fused(const float* __restrict__ x, const float* __restrict__ W,
                                const float* __restrict__ bias,
                                unsigned short* __restrict__ xbf,   // [N][128] bf16
                                int N, int natt,
                                const float* __restrict__ att0, const float* __restrict__ att1,
                                const float* __restrict__ att2,
                                float* __restrict__ o0, float* __restrict__ o1,
                                float* __restrict__ o2) {
    __shared__ float Ws[128 * 128];       // Ws[i*128 + j] = W[j*128 + i]
    __shared__ float rows_s[32][128];
    for (int idx = threadIdx.x; idx < 128 * 128; idx += 256) {
        int i = idx >> 7, j = idx & 127;
        Ws[i * 128 + j] = W[j * 128 + i];
    }
    int g = threadIdx.x >> 5;   // group 0..7, 4 rows each
    int l = threadIdx.x & 31;
    int g4 = g * 4;
    float4 bvec = *(const float4*)&bias[l * 4];
    float4 at0 = {0,0,0,0}, at1 = {0,0,0,0}, at2 = {0,0,0,0};
    if (natt > 0) at0 = *(const float4*)&att0[l * 4];
    if (natt > 1) at1 = *(const float4*)&att1[l * 4];
    if (natt > 2) at2 = *(const float4*)&att2[l * 4];
    __syncthreads();
    for (int base = blockIdx.x * 32; base < N; base += gridDim.x * 32) {
        int r0 = base + g4;
        #pragma unroll
        for (int k = 0; k < 4; k++) {
            int n = r0 + k;
            if (n < N)
                *(float4*)&rows_s[g4 + k][l * 4] = *(const float4*)&x[(size_t)n * 128 + l * 4];
        }
        __syncthreads();
        float4 acc0 = bvec, acc1 = bvec, acc2 = bvec, acc3 = bvec;
        #pragma unroll 4
        for (int i = 0; i < 128; i++) {
            float4 w = *(const float4*)&Ws[i * 128 + l * 4];
            float x0 = rows_s[g4 + 0][i];
            float x1 = rows_s[g4 + 1][i];
            float x2 = rows_s[g4 + 2][i];
            float x3 = rows_s[g4 + 3][i];
            acc0.x += x0 * w.x; acc0.y += x0 * w.y; acc0.z += x0 * w.z; acc0.w += x0 * w.w;
            acc1.x += x1 * w.x; acc1.y += x1 * w.y; acc1.z += x1 * w.z; acc1.w += x1 * w.w;
            acc2.x += x2 * w.x; acc2.y += x2 * w.y; acc2.z += x2 * w.z; acc2.w += x2 * w.w;
            acc3.x += x3 * w.x; acc3.y += x3 * w.y; acc3.z += x3 * w.z; acc3.w += x3 * w.w;
        }
        #define ROW_EPI(ACC, KK) do { \
            int n = r0 + KK; \
            if (n < N) { \
                uint2 pk; \
                pk.x = ((unsigned)bf16_rne(ACC.y) << 16) | bf16_rne(ACC.x); \
                pk.y = ((unsigned)bf16_rne(ACC.w) << 16) | bf16_rne(ACC.z); \
                *(uint2*)&xbf[(size_t)n * 128 + l * 4] = pk; \
                if (natt > 0) { \
                    float p = ACC.x*at0.x + ACC.y*at0.y + ACC.z*at0.z + ACC.w*at0.w; \
                    p += __shfl_xor(p, 1); p += __shfl_xor(p, 2); \
                    if ((l & 3) == 0) o0[n * 8 + (l >> 2)] = p; } \
                if (natt > 1) { \
                    float p = ACC.x*at1.x + ACC.y*at1.y + ACC.z*at1.z + ACC.w*at1.w; \
                    p += __shfl_xor(p, 1); p += __shfl_xor(p, 2); \
                    if ((l & 3) == 0) o1[n * 8 + (l >> 2)] = p; } \
                if (natt > 2) { \
                    float p = ACC.x*at2.x + ACC.y*at2.y + ACC.z*at2.z + ACC.w*at2.w; \
                    p += __shfl_xor(p, 1); p += __shfl_xor(p, 2); \
                    if ((l & 3) == 0) o2[n * 8 + (l >> 2)] = p; } \
            } } while (0)
        ROW_EPI(acc0, 0); ROW_EPI(acc1, 1); ROW_EPI(acc2, 2); ROW_EPI(acc3, 3);
        #undef ROW_EPI
        __syncthreads();
    }
}

// ---------------- kmean via bf16 MFMA v3: straight-line named fragments, no scratch ----------------
// csum[col] += tanh(relu(src) @ W^T + b); merged halves (gg blocks then dg blocks)
__launch_bounds__(256)
__global__ void kmean_mfma(const float* __restrict__ srcA, const float* __restrict__ srcB,
                           const float* __restrict__ W, const float* __restrict__ bias,
                           float* __restrict__ kp) {
    __shared__ bf16x8 Bs[8 * 4 * 64];   // 32 KB fragment layout: slot=(ct*4+kc)*64+lane
    // coalesced staging: each thread reads contiguous f32x4 of W, writes swizzled LDS slot
    for (int idx = threadIdx.x; idx < 128 * 32; idx += 256) {
        int row = idx >> 5, kq = idx & 31;
        f32x4 v = *(const f32x4*)&W[row * 128 + kq * 4];
        int ct = row >> 4, c = row & 15;
        int k0 = kq * 4;
        int kc = k0 >> 5, q16 = (k0 & 31) >> 3, j2 = (k0 & 7) >> 1;
        unsigned* dst = (unsigned*)&Bs[(ct * 4 + kc) * 64 + q16 * 16 + c];
        dst[j2]     = ((unsigned)bf16_rne(v.y) << 16) | bf16_rne(v.x);
        dst[j2 + 1] = ((unsigned)bf16_rne(v.w) << 16) | bf16_rne(v.z);
    }
    __syncthreads();
    int half = blockIdx.x >= KM_HALF;
    const float* src = half ? srcB : srcA;
    float* kpp = half ? (kp + 128) : kp;
    int rb = (half ? blockIdx.x - KM_HALF : blockIdx.x) * 128;
    int wv = threadIdx.x >> 6, l = threadIdx.x & 63;
    int q = l >> 4, c16 = l & 15;
    int rw = rb + wv * 32;
    // unguarded loads: worst over-read stays inside ws (next region); accumulation is row-guarded
    const float* xr0 = &src[(size_t)(rw + c16) * 128 + q * 8];
    const float* xr1 = xr0 + 16 * 128;
    bf16x8 f00 = cvt_relu(*(const f32x4*)(xr0 +  0), *(const f32x4*)(xr0 +  4));
    bf16x8 f01 = cvt_relu(*(const f32x4*)(xr0 + 32), *(const f32x4*)(xr0 + 36));
    bf16x8 f02 = cvt_relu(*(const f32x4*)(xr0 + 64), *(const f32x4*)(xr0 + 68));
    bf16x8 f03 = cvt_relu(*(const f32x4*)(xr0 + 96), *(const f32x4*)(xr0 + 100));
    bf16x8 f10 = cvt_relu(*(const f32x4*)(xr1 +  0), *(const f32x4*)(xr1 +  4));
    bf16x8 f11 = cvt_relu(*(const f32x4*)(xr1 + 32), *(const f32x4*)(xr1 + 36));
    bf16x8 f12 = cvt_relu(*(const f32x4*)(xr1 + 64), *(const f32x4*)(xr1 + 68));
    bf16x8 f13 = cvt_relu(*(const f32x4*)(xr1 + 96), *(const f32x4*)(xr1 + 100));
    float bv0 = bias[c16],      bv1 = bias[16 + c16], bv2 = bias[32 + c16], bv3 = bias[48 + c16];
    float bv4 = bias[64 + c16], bv5 = bias[80 + c16], bv6 = bias[96 + c16], bv7 = bias[112 + c16];
    int row0 = rw + q * 4;
    int row1 = row0 + 16;
    float cs0 = 0.f, cs1 = 0.f, cs2 = 0.f, cs3 = 0.f, cs4 = 0.f, cs5 = 0.f, cs6 = 0.f, cs7 = 0.f;
    #define CT_STEP(CT, CS, BV) { \
        bf16x8 b0 = Bs[((CT) * 4 + 0) * 64 + l]; \
        bf16x8 b1 = Bs[((CT) * 4 + 1) * 64 + l]; \
        bf16x8 b2 = Bs[((CT) * 4 + 2) * 64 + l]; \
        bf16x8 b3 = Bs[((CT) * 4 + 3) * 64 + l]; \
        f32x4 aA = {0,0,0,0}, aB = {0,0,0,0}, aC = {0,0,0,0}, aD = {0,0,0,0}; \
        aA = MFMA(f00, b0, aA); aB = MFMA(f01, b1, aB); \
        aA = MFMA(f02, b2, aA); aB = MFMA(f03, b3, aB); \
        aC = MFMA(f10, b0, aC); aD = MFMA(f11, b1, aD); \
        aC = MFMA(f12, b2, aC); aD = MFMA(f13, b3, aD); \
        f32x4 d0 = aA + aB, d1 = aC + aD; \
        float s = 0.f; \
        if (row0 + 0 < NG) s += fast_tanh(d0[0] + (BV)); \
        if (row0 + 1 < NG) s += fast_tanh(d0[1] + (BV)); \
        if (row0 + 2 < NG) s += fast_tanh(d0[2] + (BV)); \
        if (row0 + 3 < NG) s += fast_tanh(d0[3] + (BV)); \
        if (row1 + 0 < NG) s += fast_tanh(d1[0] + (BV)); \
        if (row1 + 1 < NG) s += fast_tanh(d1[1] + (BV)); \
        if (row1 + 2 < NG) s += fast_tanh(d1[2] + (BV)); \
        if (row1 + 3 < NG) s += fast_tanh(d1[3] + (BV)); \
        CS += s; }
    CT_STEP(0, cs0, bv0) CT_STEP(1, cs1, bv1) CT_STEP(2, cs2, bv2) CT_STEP(3, cs3, bv3)
    CT_STEP(4, cs4, bv4) CT_STEP(5, cs5, bv5) CT_STEP(6, cs6, bv6) CT_STEP(7, cs7, bv7)
    #undef CT_STEP
    // block reduce: per-wave cross-lane, then LDS (alias Bs after barrier), then 128 atomics
    __syncthreads();                 // all Bs reads done before aliasing
    float* red = (float*)Bs;         // [4 waves][128]
    #define REDUCE_CT(CT, CS) { \
        float v = (CS); \
        v += __shfl_xor(v, 16); v += __shfl_xor(v, 32); \
        if (l < 16) red[wv * 128 + (CT) * 16 + l] = v; }
    REDUCE_CT(0, cs0) REDUCE_CT(1, cs1) REDUCE_CT(2, cs2) REDUCE_CT(3, cs3)
    REDUCE_CT(4, cs4) REDUCE_CT(5, cs5) REDUCE_CT(6, cs6) REDUCE_CT(7, cs7)
    #undef REDUCE_CT
    __syncthreads();
    if (threadIdx.x < 128) {
        float s = red[threadIdx.x] + red[128 + threadIdx.x]
                + red[256 + threadIdx.x] + red[384 + threadIdx.x];
        atomicAdd(&kpp[threadIdx.x], s);
    }
}

// ---------------- CSR build ----------------
__global__ void count_all(const int* __restrict__ gg_dst, const int* __restrict__ dg_dst,
                          int* __restrict__ deg) {
    int e = blockIdx.x * 256 + threadIdx.x;
    if (e < EGG) atomicAdd(&deg[gg_dst[e]], 1);
    else if (e < EALL) atomicAdd(&deg[NG + dg_dst[e - EGG]], 1);
}

__global__ void scan1(const int* __restrict__ deg, int* __restrict__ rp,
                      int* __restrict__ bsum, int N) {
    __shared__ int tsum[256];
    int t = threadIdx.x;
    int base = blockIdx.x * 1024 + t * 4;
    int v0 = 0, v1 = 0, v2 = 0, v3 = 0;
    if (base + 0 < N) v0 = deg[base + 0];
    if (base + 1 < N) v1 = deg[base + 1];
    if (base + 2 < N) v2 = deg[base + 2];
    if (base + 3 < N) v3 = deg[base + 3];
    int tot = v0 + v1 + v2 + v3;
    tsum[t] = tot;
    __syncthreads();
    for (int off = 1; off < 256; off <<= 1) {
        int y = (t >= off) ? tsum[t - off] : 0;
        __syncthreads();
        tsum[t] += y;
        __syncthreads();
    }
    int excl = tsum[t] - tot;
    if (base + 0 < N) rp[base + 0] = excl;
    if (base + 1 < N) rp[base + 1] = excl + v0;
    if (base + 2 < N) rp[base + 2] = excl + v0 + v1;
    if (base + 3 < N) rp[base + 3] = excl + v0 + v1 + v2;
    if (t == 255) bsum[blockIdx.x] = tsum[255];
}

__global__ void scan2(int* __restrict__ bsum, int NB) {
    __shared__ int s[256];
    int t = threadIdx.x;
    int v = (t < NB) ? bsum[t] : 0;
    s[t] = v;
    __syncthreads();
    for (int off = 1; off < 256; off <<= 1) {
        int y = (t >= off) ? s[t - off] : 0;
        __syncthreads();
        s[t] += y;
        __syncthreads();
    }
    if (t < NB) bsum[t] = s[t] - v;
}

__global__ void scan3(int* __restrict__ rp, const int* __restrict__ bsum,
                      int* __restrict__ bcur, int N, int E) {
    int i = blockIdx.x * 256 + threadIdx.x;
    if (i < N) {
        int v = rp[i] + bsum[i >> 10];
        rp[i] = v;
        if ((i & (BDSTS - 1)) == 0) bcur[i >> SHIFT] = v;
    }
    if (i == 0) rp[N] = E;
}

// ---------------- S1: LDS-staged bucket scatter ----------------
__launch_bounds__(256)
__global__ void bucket_scatter(const int* __restrict__ gg_src, const int* __restrict__ gg_dst,
                               const int* __restrict__ dg_src, const int* __restrict__ dg_dst,
                               int* __restrict__ bcur, unsigned int* __restrict__ colPacked) {
    __shared__ int cnt[256], scanE[256], gbase[256], cursor[256];
    __shared__ unsigned int sorted[S1_CH];
    __shared__ unsigned char bof[S1_CH];
    int t = threadIdx.x;
    cnt[t] = 0;
    __syncthreads();
    int base = blockIdx.x * S1_CH;
    for (int k = 0; k < S1_CH; k += 256) {
        int e = base + k + t;
        if (e < EALL) {
            int dn = (e < EGG) ? gg_dst[e] : (NG + dg_dst[e - EGG]);
            atomicAdd(&cnt[dn >> SHIFT], 1);
        }
    }
    __syncthreads();
    int v = cnt[t];
    __shared__ int ss[256];
    ss[t] = v;
    __syncthreads();
    for (int off = 1; off < 256; off <<= 1) {
        int y = (t >= off) ? ss[t - off] : 0;
        __syncthreads();
        ss[t] += y;
        __syncthreads();
    }
    scanE[t] = ss[t] - v;
    cursor[t] = ss[t] - v;
    if (t < NBUK && v > 0) gbase[t] = atomicAdd(&bcur[t], v);
    __syncthreads();
    for (int k = 0; k < S1_CH; k += 256) {
        int e = base + k + t;
        if (e < EALL) {
            int s, dn;
            if (e < EGG) { s = gg_src[e]; dn = gg_dst[e]; }
            else         { s = dg_src[e - EGG]; dn = NG + dg_dst[e - EGG]; }
            int b = dn >> SHIFT;
            int slot = atomicAdd(&cursor[b], 1);
            sorted[slot] = ((unsigned int)s << SHIFT) | (unsigned int)(dn & (BDSTS - 1));
            bof[slot] = (unsigned char)b;
        }
    }
    __syncthreads();
    int total = ss[255];
    for (int f = t; f < total; f += 256) {
        int b = bof[f];
        colPacked[gbase[b] + (f - scanE[b])] = sorted[f];
    }
}

// ---------------- S2: bucket-local counting sort ----------------
__launch_bounds__(256)
__global__ void bucket_sort(const unsigned int* __restrict__ colPacked,
                            const int* __restrict__ rp, int* __restrict__ col) {
    __shared__ int lcur[BDSTS];
    int b = blockIdx.x;
    int d0 = b << SHIFT;
    int dEnd = min(d0 + BDSTS, NALL);
    int nd = dEnd - d0;
    for (int i = threadIdx.x; i < nd; i += 256) lcur[i] = rp[d0 + i];
    __syncthreads();
    int ebase = rp[d0];
    int eend  = rp[dEnd];
    for (int i = ebase + threadIdx.x; i < eend; i += 256) {
        unsigned int p = colPacked[i];
        int dlow = (int)(p & (BDSTS - 1));
        int s    = (int)(p >> SHIFT);
        int pos = atomicAdd(&lcur[dlow], 1);
        col[pos] = s;
    }
}

// ---------------- fused GAT gather v4: bf16 rows, gg+dg merged, one wave/dst ----------------
__launch_bounds__(256)
__global__ void gat_gather_all(const int* __restrict__ rp, const int* __restrict__ col,
                               const float* __restrict__ as_gg, const float* __restrict__ ad_gg,
                               const unsigned short* __restrict__ xg_bf,
                               const float* __restrict__ as_dg, const float* __restrict__ ad_dg,
                               const unsigned short* __restrict__ xd_bf,
                               float* __restrict__ out_gg, float* __restrict__ out_dg) {
    int wid = (blockIdx.x * 256 + threadIdx.x) >> 6;
    int l = threadIdx.x & 63;
    if (wid >= NALL) return;
    int isdg = wid >= NG;
    int d = isdg ? wid - NG : wid;
    const float* a_s = isdg ? as_dg : as_gg;
    const float* a_d = isdg ? ad_dg : ad_gg;
    const unsigned short* xbf = isdg ? xd_bf : xg_bf;
    float* outb = (isdg ? out_dg : out_gg) + (size_t)d * 128;

    int base = rp[wid];
    int deg = rp[wid + 1] - base;

    int hl = l & 7;
    int g  = l >> 3;
    float adl = a_d[d * 8 + hl];
    float m = -1e30f, ssum = 0.f;
    for (int c0 = 0; c0 < deg; c0 += 64) {
        int myi = c0 + l;
        int colreg = (myi < deg) ? col[base + myi] : 0;
        int lim = min(deg - c0, 64);
        for (int t = g; t < lim; t += 8) {
            int s = __shfl(colreg, t);
            float a = a_s[s * 8 + hl] + adl;
            a = a > 0.f ? a : 0.2f * a;
            float nm = fmaxf(m, a);
            ssum = ssum * __expf(m - nm) + __expf(a - nm);
            m = nm;
        }
    }
    for (int off = 8; off < 64; off <<= 1) {
        float m2 = __shfl_xor(m, off);
        float s2 = __shfl_xor(ssum, off);
        float nm = fmaxf(m, m2);
        ssum = ssum * __expf(m - nm) + s2 * __expf(m2 - nm);
        m = nm;
    }
    float rsc = 1.f / (ssum + 1e-16f);   // lane l holds (m, rsc) for head l&7

    // phase 2: quarter q = edge slot (4 edges/iter), cq = col block (8 bf16 cols)
    int q = l >> 4;
    int cq = l & 15;
    int hq = cq >> 1;                    // head of my col block
    uint32_t colbyte = (uint32_t)cq << 4;  // 16 B per col block
    float a0 = 0.f, a1 = 0.f, a2 = 0.f, a3 = 0.f, a4 = 0.f, a5 = 0.f, a6 = 0.f, a7 = 0.f;
    for (int c0 = 0; c0 < deg; c0 += 64) {
        int myi = c0 + l;
        int colreg = (myi < deg) ? col[base + myi] : 0;
        int lim = min(deg - c0, 64);
        for (int j8 = 0; j8 < lim; j8 += 8) {
            float alpha;
            {
                int s = __shfl(colreg, j8 + g);
                float a = a_s[s * 8 + hl] + adl;
                a = a > 0.f ? a : 0.2f * a;
                alpha = __expf(a - m) * rsc;
            }
            int jlim = min(lim - j8, 8);
            #pragma unroll
            for (int sub = 0; sub < 8; sub += 4) {
                int jrel = sub + q;
                int s = __shfl(colreg, j8 + jrel);
                float al = __shfl(alpha, (jrel << 3) + hq);
                al = (jrel < jlim) ? al : 0.f;
                const uint4 rv = *(const uint4*)((const char*)xbf +
                                    (((size_t)(uint32_t)s << 8) + colbyte));
                a0 += al * __uint_as_float(rv.x << 16);
                a1 += al * __uint_as_float(rv.x & 0xffff0000u);
                a2 += al * __uint_as_float(rv.y << 16);
                a3 += al * __uint_as_float(rv.y & 0xffff0000u);
                a4 += al * __uint_as_float(rv.z << 16);
                a5 += al * __uint_as_float(rv.z & 0xffff0000u);
                a6 += al * __uint_as_float(rv.w << 16);
                a7 += al * __uint_as_float(rv.w & 0xffff0000u);
            }
        }
    }
    a0 += __shfl_xor(a0, 16); a0 += __shfl_xor(a0, 32);
    a1 += __shfl_xor(a1, 16); a1 += __shfl_xor(a1, 32);
    a2 += __shfl_xor(a2, 16); a2 += __shfl_xor(a2, 32);
    a3 += __shfl_xor(a3, 16); a3 += __shfl_xor(a3, 32);
    a4 += __shfl_xor(a4, 16); a4 += __shfl_xor(a4, 32);
    a5 += __shfl_xor(a5, 16); a5 += __shfl_xor(a5, 32);
    a6 += __shfl_xor(a6, 16); a6 += __shfl_xor(a6, 32);
    a7 += __shfl_xor(a7, 16); a7 += __shfl_xor(a7, 32);
    if (q == 0) {
        float4 o0 = {a0, a1, a2, a3};
        float4 o1 = {a4, a5, a6, a7};
        *(float4*)&outb[cq * 8] = o0;
        *(float4*)&outb[cq * 8 + 4] = o1;
    }
}

// ---------------- semantic softmax (2 scores) ----------------
__global__ void score_attn(const float* __restrict__ kpart, const float* __restrict__ q,
                           float* __restrict__ attn) {
    __shared__ float r0[128], r1[128];
    int t = threadIdx.x;
    r0[t] = q[t] * kpart[t];
    r1[t] = q[t] * kpart[128 + t];
    __syncthreads();
    for (int s = 64; s > 0; s >>= 1) {
        if (t < s) { r0[t] += r0[t + s]; r1[t] += r1[t + s]; }
        __syncthreads();
    }
    if (t == 0) {
        float s0 = r0[0] / (float)NG, s1 = r1[0] / (float)NG;
        float mx = fmaxf(s0, s1);
        float e0 = expf(s0 - mx), e1 = expf(s1 - mx);
        attn[0] = e0 / (e0 + e1);
        attn[1] = e1 / (e0 + e1);
    }
}

// ---------------- fused combine + final linear ----------------
__launch_bounds__(256)
__global__ void final_lin(const float* __restrict__ gg, const float* __restrict__ dgb,
                          const float* __restrict__ attn, const float* __restrict__ lin_w,
                          const float* __restrict__ lin_b, float* __restrict__ outp) {
    int wid = (blockIdx.x * 256 + threadIdx.x) >> 6;
    int l = threadIdx.x & 63;
    if (wid >= NG) return;
    float a0 = attn[0], a1 = attn[1];
    float2 gv = *(const float2*)&gg[(size_t)wid * 128 + l * 2];
    float2 dv = *(const float2*)&dgb[(size_t)wid * 128 + l * 2];
    float fx = a0 * fmaxf(gv.x, 0.f) + a1 * fmaxf(dv.x, 0.f);
    float fy = a0 * fmaxf(gv.y, 0.f) + a1 * fmaxf(dv.y, 0.f);
    float2 w0 = *(const float2*)&lin_w[l * 2];
    float2 w1 = *(const float2*)&lin_w[128 + l * 2];
    float p0 = fx * w0.x + fy * w0.y;
    float p1 = fx * w1.x + fy * w1.y;
    for (int off = 32; off > 0; off >>= 1) {
        p0 += __shfl_down(p0, off);
        p1 += __shfl_down(p1, off);
    }
    if (l == 0) {
        float2 o;
        o.x = p0 + lin_b[0];
        o.y = p1 + lin_b[1];
        *(float2*)&outp[wid * 2] = o;
    }
}

extern "C" void kernel_launch(void* const* d_in, const int* in_sizes, int n_in,
                              void* d_out, int out_size, void* d_ws, size_t ws_size,
                              hipStream_t stream) {
    const float* x_gene    = (const float*)d_in[0];
    const float* x_disease = (const float*)d_in[1];
    const int*   edge_gg   = (const int*)d_in[2];
    const int*   edge_dg   = (const int*)d_in[3];
    const float* pg_w      = (const float*)d_in[4];
    const float* pg_b      = (const float*)d_in[5];
    const float* pd_w      = (const float*)d_in[6];
    const float* pd_b      = (const float*)d_in[7];
    const float* att_src_gg= (const float*)d_in[8];
    const float* att_dst_gg= (const float*)d_in[9];
    const float* att_src_dg= (const float*)d_in[10];
    const float* att_dst_dg= (const float*)d_in[11];
    const float* k_lin_w   = (const float*)d_in[12];
    const float* k_lin_b   = (const float*)d_in[13];
    const float* q         = (const float*)d_in[14];
    const float* lin_w     = (const float*)d_in[15];
    const float* lin_b     = (const float*)d_in[16];
    float* out = (float*)d_out;
    float* ws  = (float*)d_ws;

    float* out_gg = ws + OFF_OUT_GG;
    float* out_dg = ws + OFF_OUT_DG;
    unsigned int* colPacked = (unsigned int*)(ws + OFF_OUT_GG);  // overlay
    unsigned short* xg_bf = (unsigned short*)(ws + OFF_XG);
    unsigned short* xd_bf = (unsigned short*)(ws + OFF_XD);
    float* a_src_gg = ws + OFF_ASG;
    float* a_dst_gg = ws + OFF_ADG;
    float* a_dst_dg = ws + OFF_ADD;
    float* a_src_dg = ws + OFF_ASD;
    float* kpart  = ws + OFF_KPART;
    float* attn   = ws + OFF_ATTN;
    int* deg  = (int*)(ws + OFF_DEG);
    int* rp   = (int*)(ws + OFF_RP);
    int* bcur = (int*)(ws + OFF_BCUR);
    int* bsum = (int*)(ws + OFF_BSUM);
    int* col  = (int*)(ws + OFF_COL);

    const int* gg_src = edge_gg;
    const int* gg_dst = edge_gg + EGG;
    const int* dg_src = edge_dg;
    const int* dg_dst = edge_dg + EDG;

    // 1. zero kpart + degree arrays
    hipLaunchKernelGGL(init_zero_k, dim3((ZERO_CNT + 255) / 256), dim3(256), 0, stream,
                       ws + ZERO_BASE, ZERO_CNT);
    // 2. projections (bf16 x rows + fused logits)
    hipLaunchKernelGGL(proj_gemm_fused, dim3(512), dim3(256), 0, stream,
                       x_gene, pg_w, pg_b, xg_bf, NG, 3,
                       att_src_gg, att_dst_gg, att_dst_dg, a_src_gg, a_dst_gg, a_dst_dg);
    hipLaunchKernelGGL(proj_gemm_fused, dim3(512), dim3(256), 0, stream,
                       x_disease, pd_w, pd_b, xd_bf, ND, 1,
                       att_src_dg, (const float*)nullptr, (const float*)nullptr,
                       a_src_dg, (float*)nullptr, (float*)nullptr);
    // 3. CSR row pointers
    hipLaunchKernelGGL(count_all, dim3((EALL + 255) / 256), dim3(256), 0, stream,
                       gg_dst, dg_dst, deg);
    hipLaunchKernelGGL(scan1, dim3((NALL + 1023) / 1024), dim3(256), 0, stream, deg, rp, bsum, NALL);
    hipLaunchKernelGGL(scan2, dim3(1), dim3(256), 0, stream, bsum, (NALL + 1023) / 1024);
    hipLaunchKernelGGL(scan3, dim3((NALL + 255) / 256), dim3(256), 0, stream, rp, bsum, bcur, NALL, EALL);
    // 4. two-level bucket sort into CSR col
    hipLaunchKernelGGL(bucket_scatter, dim3((EALL + S1_CH - 1) / S1_CH), dim3(256), 0, stream,
                       gg_src, gg_dst, dg_src, dg_dst, bcur, colPacked);
    hipLaunchKernelGGL(bucket_sort, dim3(NBUK), dim3(256), 0, stream, colPacked, rp, col);
    // 5. merged fused gather (out_gg overwrites colPacked overlay — dead by now)
    hipLaunchKernelGGL(gat_gather_all, dim3((NALL + 3) / 4), dim3(256), 0, stream,
                       rp, col, a_src_gg, a_dst_gg, xg_bf, a_src_dg, a_dst_dg, xd_bf,
                       out_gg, out_dg);
    // 6. semantic attention (merged kmean, straight-line MFMA)
    hipLaunchKernelGGL(kmean_mfma, dim3(KM_HALF * 2), dim3(256), 0, stream,
                       out_gg, out_dg, k_lin_w, k_lin_b, kpart);
    hipLaunchKernelGGL(score_attn, dim3(1), dim3(128), 0, stream, kpart, q, attn);
    // 7. fused combine + final linear
    hipLaunchKernelGGL(final_lin, dim3((NG + 3) / 4), dim3(256), 0, stream,
                       out_gg, out_dg, attn, lin_w, lin_b, out);
}

// Round 9
// 476.935 us; speedup vs baseline: 1.6165x; 1.0903x over previous
//
#include <hip/hip_runtime.h>
#include <hip/hip_fp16.h>
#include <math.h>

#define NG 100000
#define ND 50000
#define EGG 1600000
#define EDG 800000
#define EALL (EGG + EDG)
#define NALL (NG + NG)
#define HID 128
#define NH 8

// bucket sort params
#define SHIFT 11
#define BDSTS (1 << SHIFT)
#define NBUK  ((NALL + BDSTS - 1) / BDSTS)   // 98
#define S1_CH 6144
#define KM_HALF ((NG + 127) / 128)           // 782 blocks per metapath

// ---------------- workspace layout (4-byte element offsets) ----------------
#define OFF_OUT_GG 0UL          // 12,800,000  (colPacked overlays until gat_gather)
#define OFF_OUT_DG 12800000UL   // 12,800,000
#define OFF_XG     25600000UL   // f16 [NG][128]
#define OFF_XD     38400000UL   // f16 [ND][128]
#define OFF_ASG    44800000UL   //    800,000  a_src_gg [NG,8]
#define OFF_ADG    45600000UL   //    800,000  a_dst_gg [NG,8]
#define OFF_ADD    46400000UL   //    800,000  a_dst_dg [NG,8]
#define OFF_ASD    47200000UL   //    400,000  a_src_dg [ND,8]
#define OFF_KPART  47600000UL   //        256  (zero-init)
#define OFF_DEG    47600256UL   //    200,000  (zero-init)
#define ZERO_BASE  OFF_KPART
#define ZERO_CNT   200256
#define OFF_ATTN   47800256UL   //          2 (+pad)
#define OFF_RP     47800272UL   //    200,001 (+pad)
#define OFF_BCUR   48000280UL   //        256
#define OFF_WTIL   48010000UL   //      3,072  gene wtilde [24][128]
#define OFF_BTIL   48013100UL   //         24
#define OFF_WTILD  48013200UL   //      1,024  disease wtilde [8][128]
#define OFF_BTILD  48014300UL   //          8
#define OFF_BSUM   48200280UL   //        256
#define OFF_COL    48200536UL   //  2,400,000
// end: 50,600,536 elems = 202.4 MB

typedef float  f32x4  __attribute__((ext_vector_type(4)));
typedef short  bf16x8 __attribute__((ext_vector_type(8)));
#define MFMA(a, b, c) __builtin_amdgcn_mfma_f32_16x16x32_bf16(a, b, c, 0, 0, 0)

__device__ __forceinline__ unsigned short bf16_rne(float f) {
    unsigned u = __float_as_uint(f);
    u += 0x7FFFu + ((u >> 16) & 1u);
    return (unsigned short)(u >> 16);
}
__device__ __forceinline__ float bf16f(unsigned short h) {
    return __uint_as_float(((unsigned)h) << 16);
}
__device__ __forceinline__ unsigned short f16_bits(float f) {
    __half h = __float2half(f);
    return *(unsigned short*)&h;
}
__device__ __forceinline__ float fast_tanh(float x) {
    x = fminf(fmaxf(x, -15.f), 15.f);
    float t = __expf(2.f * x);
    return (t - 1.f) / (t + 1.f);
}
__device__ __forceinline__ bf16x8 cvt_relu(f32x4 v0, f32x4 v1) {
    bf16x8 f;
    f[0] = (short)bf16_rne(fmaxf(v0.x, 0.f));
    f[1] = (short)bf16_rne(fmaxf(v0.y, 0.f));
    f[2] = (short)bf16_rne(fmaxf(v0.z, 0.f));
    f[3] = (short)bf16_rne(fmaxf(v0.w, 0.f));
    f[4] = (short)bf16_rne(fmaxf(v1.x, 0.f));
    f[5] = (short)bf16_rne(fmaxf(v1.y, 0.f));
    f[6] = (short)bf16_rne(fmaxf(v1.z, 0.f));
    f[7] = (short)bf16_rne(fmaxf(v1.w, 0.f));
    return f;
}
__device__ __forceinline__ bf16x8 cvt_hi8(f32x4 v0, f32x4 v1) {
    bf16x8 f;
    f[0] = (short)bf16_rne(v0.x); f[1] = (short)bf16_rne(v0.y);
    f[2] = (short)bf16_rne(v0.z); f[3] = (short)bf16_rne(v0.w);
    f[4] = (short)bf16_rne(v1.x); f[5] = (short)bf16_rne(v1.y);
    f[6] = (short)bf16_rne(v1.z); f[7] = (short)bf16_rne(v1.w);
    return f;
}
__device__ __forceinline__ bf16x8 cvt_lo8(f32x4 v0, f32x4 v1, bf16x8 h) {
    bf16x8 f;
    f[0] = (short)bf16_rne(v0.x - bf16f((unsigned short)h[0]));
    f[1] = (short)bf16_rne(v0.y - bf16f((unsigned short)h[1]));
    f[2] = (short)bf16_rne(v0.z - bf16f((unsigned short)h[2]));
    f[3] = (short)bf16_rne(v0.w - bf16f((unsigned short)h[3]));
    f[4] = (short)bf16_rne(v1.x - bf16f((unsigned short)h[4]));
    f[5] = (short)bf16_rne(v1.y - bf16f((unsigned short)h[5]));
    f[6] = (short)bf16_rne(v1.z - bf16f((unsigned short)h[6]));
    f[7] = (short)bf16_rne(v1.w - bf16f((unsigned short)h[7]));
    return f;
}

// ---------------- init ----------------
__global__ void init_zero_k(float* __restrict__ p, int n) {
    int i = blockIdx.x * 256 + threadIdx.x;
    if (i < n) p[i] = 0.f;
}

// ---------------- wtilde: w~[v*8+h][k] = sum_c att_v[h*16+c] * W[h*16+c][k] ----------------
__global__ void make_wtil(const float* __restrict__ W, const float* __restrict__ bias,
                          const float* __restrict__ a0, const float* __restrict__ a1,
                          const float* __restrict__ a2, int natt,
                          float* __restrict__ wtil, float* __restrict__ btil) {
    int tot = natt * 8 * 128;
    for (int i = blockIdx.x * 256 + threadIdx.x; i < tot; i += gridDim.x * 256) {
        int k = i & 127, cc = i >> 7;
        int v = cc >> 3, h = cc & 7;
        const float* av = (v == 0) ? a0 : (v == 1) ? a1 : a2;
        float s = 0.f;
        #pragma unroll
        for (int c = 0; c < 16; c++) s += av[h * 16 + c] * W[(h * 16 + c) * 128 + k];
        wtil[i] = s;
    }
    if (blockIdx.x == 0 && threadIdx.x < natt * 8) {
        int v = threadIdx.x >> 3, h = threadIdx.x & 7;
        const float* av = (v == 0) ? a0 : (v == 1) ? a1 : a2;
        float s = 0.f;
        #pragma unroll
        for (int c = 0; c < 16; c++) s += av[h * 16 + c] * bias[h * 16 + c];
        btil[threadIdx.x] = s;
    }
}

// ---------------- proj via split-bf16 MFMA (straight-line, scratch-free) ----------------
// table = f16(X@W^T + b); logits = X@wtil^T + btil as extra col-tiles
template<int NATT>
__launch_bounds__(256)
__global__ void proj_mfma(const float* __restrict__ x, const float* __restrict__ W,
                          const float* __restrict__ bias,
                          const float* __restrict__ wtil, const float* __restrict__ btil,
                          unsigned short* __restrict__ xbf,   // f16 [N][128]
                          float* __restrict__ o0, float* __restrict__ o1,
                          float* __restrict__ o2, int N) {
    constexpr int NTE = (NATT * 8 + 15) / 16;
    constexpr int NT = 8 + NTE;
    __shared__ bf16x8 Bhi[NT * 4 * 64];
    __shared__ bf16x8 Blo[8 * 4 * 64];
    // coalesced W staging (hi+lo), fragment layout slot=(ct*4+kc)*64 + q16*16 + c
    for (int idx = threadIdx.x; idx < 128 * 32; idx += 256) {
        int row = idx >> 5, kq = idx & 31;
        f32x4 v = *(const f32x4*)&W[row * 128 + kq * 4];
        int ct = row >> 4, c = row & 15;
        int k0 = kq * 4;
        int kc = k0 >> 5, q16 = (k0 & 31) >> 3, j2 = (k0 & 7) >> 1;
        int slot = (ct * 4 + kc) * 64 + q16 * 16 + c;
        unsigned short hx = bf16_rne(v.x), hy = bf16_rne(v.y);
        unsigned short hz = bf16_rne(v.z), hw = bf16_rne(v.w);
        unsigned* dh = (unsigned*)&Bhi[slot];
        dh[j2]     = ((unsigned)hy << 16) | hx;
        dh[j2 + 1] = ((unsigned)hw << 16) | hz;
        unsigned* dl = (unsigned*)&Blo[slot];
        dl[j2]     = ((unsigned)bf16_rne(v.y - bf16f(hy)) << 16) | bf16_rne(v.x - bf16f(hx));
        dl[j2 + 1] = ((unsigned)bf16_rne(v.w - bf16f(hw)) << 16) | bf16_rne(v.z - bf16f(hz));
    }
    // wtil staging (bf16, hi only; zero-pad unused cols)
    for (int idx = threadIdx.x; idx < NTE * 16 * 32; idx += 256) {
        int cc = idx >> 5, kq = idx & 31;
        f32x4 v = {0.f, 0.f, 0.f, 0.f};
        if (cc < NATT * 8) v = *(const f32x4*)&wtil[cc * 128 + kq * 4];
        int ct = 8 + (cc >> 4), c = cc & 15;
        int k0 = kq * 4;
        int kc = k0 >> 5, q16 = (k0 & 31) >> 3, j2 = (k0 & 7) >> 1;
        unsigned* dh = (unsigned*)&Bhi[(ct * 4 + kc) * 64 + q16 * 16 + c];
        dh[j2]     = ((unsigned)bf16_rne(v.y) << 16) | bf16_rne(v.x);
        dh[j2 + 1] = ((unsigned)bf16_rne(v.w) << 16) | bf16_rne(v.z);
    }
    __syncthreads();
    int wv = threadIdx.x >> 6, l = threadIdx.x & 63;
    int q = l >> 4, c16 = l & 15;
    int rw = blockIdx.x * 128 + wv * 32;
    // clamped input rows (x is an input buffer: no over-read); stores row-guarded
    int n0 = min(rw + c16, N - 1);
    int n1 = min(rw + 16 + c16, N - 1);
    const float* xr0 = &x[(size_t)n0 * 128 + q * 8];
    const float* xr1 = &x[(size_t)n1 * 128 + q * 8];
    #define LOADX(FH, FL, PTR, OFF) \
        bf16x8 FH, FL; \
        { f32x4 v0_ = *(const f32x4*)((PTR) + (OFF)); \
          f32x4 v1_ = *(const f32x4*)((PTR) + (OFF) + 4); \
          FH = cvt_hi8(v0_, v1_); FL = cvt_lo8(v0_, v1_, FH); }
    LOADX(xh00, xl00, xr0, 0)  LOADX(xh01, xl01, xr0, 32)
    LOADX(xh02, xl02, xr0, 64) LOADX(xh03, xl03, xr0, 96)
    LOADX(xh10, xl10, xr1, 0)  LOADX(xh11, xl11, xr1, 32)
    LOADX(xh12, xl12, xr1, 64) LOADX(xh13, xl13, xr1, 96)
    #undef LOADX
    int r0 = rw + q * 4;
    int r1 = r0 + 16;
    #define CT_MAIN(CT) { \
        bf16x8 bh0 = Bhi[((CT) * 4 + 0) * 64 + l]; \
        bf16x8 bh1 = Bhi[((CT) * 4 + 1) * 64 + l]; \
        bf16x8 bh2 = Bhi[((CT) * 4 + 2) * 64 + l]; \
        bf16x8 bh3 = Bhi[((CT) * 4 + 3) * 64 + l]; \
        bf16x8 bl0 = Blo[((CT) * 4 + 0) * 64 + l]; \
        bf16x8 bl1 = Blo[((CT) * 4 + 1) * 64 + l]; \
        bf16x8 bl2 = Blo[((CT) * 4 + 2) * 64 + l]; \
        bf16x8 bl3 = Blo[((CT) * 4 + 3) * 64 + l]; \
        f32x4 aA = {0,0,0,0}, aB = {0,0,0,0}, aC = {0,0,0,0}, aD = {0,0,0,0}; \
        aA = MFMA(xh00, bh0, aA); aB = MFMA(xh01, bh1, aB); \
        aC = MFMA(xh10, bh0, aC); aD = MFMA(xh11, bh1, aD); \
        aA = MFMA(xl00, bh0, aA); aB = MFMA(xl01, bh1, aB); \
        aC = MFMA(xl10, bh0, aC); aD = MFMA(xl11, bh1, aD); \
        aA = MFMA(xh00, bl0, aA); aB = MFMA(xh01, bl1, aB); \
        aC = MFMA(xh10, bl0, aC); aD = MFMA(xh11, bl1, aD); \
        aA = MFMA(xh02, bh2, aA); aB = MFMA(xh03, bh3, aB); \
        aC = MFMA(xh12, bh2, aC); aD = MFMA(xh13, bh3, aD); \
        aA = MFMA(xl02, bh2, aA); aB = MFMA(xl03, bh3, aB); \
        aC = MFMA(xl12, bh2, aC); aD = MFMA(xl13, bh3, aD); \
        aA = MFMA(xh02, bl2, aA); aB = MFMA(xh03, bl3, aB); \
        aC = MFMA(xh12, bl2, aC); aD = MFMA(xh13, bl3, aD); \
        f32x4 d0 = aA + aB, d1 = aC + aD; \
        float bv = bias[(CT) * 16 + c16]; \
        int col = (CT) * 16 + c16; \
        if (r0 + 0 < N) xbf[(size_t)(r0 + 0) * 128 + col] = f16_bits(d0[0] + bv); \
        if (r0 + 1 < N) xbf[(size_t)(r0 + 1) * 128 + col] = f16_bits(d0[1] + bv); \
        if (r0 + 2 < N) xbf[(size_t)(r0 + 2) * 128 + col] = f16_bits(d0[2] + bv); \
        if (r0 + 3 < N) xbf[(size_t)(r0 + 3) * 128 + col] = f16_bits(d0[3] + bv); \
        if (r1 + 0 < N) xbf[(size_t)(r1 + 0) * 128 + col] = f16_bits(d1[0] + bv); \
        if (r1 + 1 < N) xbf[(size_t)(r1 + 1) * 128 + col] = f16_bits(d1[1] + bv); \
        if (r1 + 2 < N) xbf[(size_t)(r1 + 2) * 128 + col] = f16_bits(d1[2] + bv); \
        if (r1 + 3 < N) xbf[(size_t)(r1 + 3) * 128 + col] = f16_bits(d1[3] + bv); }
    CT_MAIN(0) CT_MAIN(1) CT_MAIN(2) CT_MAIN(3)
    CT_MAIN(4) CT_MAIN(5) CT_MAIN(6) CT_MAIN(7)
    #undef CT_MAIN
    #define CT_ATT(TE) { \
        bf16x8 bh0 = Bhi[((8 + (TE)) * 4 + 0) * 64 + l]; \
        bf16x8 bh1 = Bhi[((8 + (TE)) * 4 + 1) * 64 + l]; \
        bf16x8 bh2 = Bhi[((8 + (TE)) * 4 + 2) * 64 + l]; \
        bf16x8 bh3 = Bhi[((8 + (TE)) * 4 + 3) * 64 + l]; \
        f32x4 aA = {0,0,0,0}, aB = {0,0,0,0}, aC = {0,0,0,0}, aD = {0,0,0,0}; \
        aA = MFMA(xh00, bh0, aA); aB = MFMA(xh01, bh1, aB); \
        aC = MFMA(xh10, bh0, aC); aD = MFMA(xh11, bh1, aD); \
        aA = MFMA(xh02, bh2, aA); aB = MFMA(xh03, bh3, aB); \
        aC = MFMA(xh12, bh2, aC); aD = MFMA(xh13, bh3, aD); \
        f32x4 d0 = aA + aB, d1 = aC + aD; \
        int cc = (TE) * 16 + c16; \
        if (cc < NATT * 8) { \
            float bt = btil[cc]; \
            int v = cc >> 3, h = cc & 7; \
            float* op = (v == 0) ? o0 : ((v == 1) ? o1 : o2); \
            if (r0 + 0 < N) op[(r0 + 0) * 8 + h] = d0[0] + bt; \
            if (r0 + 1 < N) op[(r0 + 1) * 8 + h] = d0[1] + bt; \
            if (r0 + 2 < N) op[(r0 + 2) * 8 + h] = d0[2] + bt; \
            if (r0 + 3 < N) op[(r0 + 3) * 8 + h] = d0[3] + bt; \
            if (r1 + 0 < N) op[(r1 + 0) * 8 + h] = d1[0] + bt; \
            if (r1 + 1 < N) op[(r1 + 1) * 8 + h] = d1[1] + bt; \
            if (r1 + 2 < N) op[(r1 + 2) * 8 + h] = d1[2] + bt; \
            if (r1 + 3 < N) op[(r1 + 3) * 8 + h] = d1[3] + bt; } }
    CT_ATT(0)
    if constexpr (NTE > 1) { CT_ATT(1) }
    #undef CT_ATT
}

// ---------------- kmean via bf16 MFMA (straight-line, merged gg/dg) ----------------
__launch_bounds__(256)
__global__ void kmean_mfma(const float* __restrict__ srcA, const float* __restrict__ srcB,
                           const float* __restrict__ W, const float* __restrict__ bias,
                           float* __restrict__ kp) {
    __shared__ bf16x8 Bs[8 * 4 * 64];
    for (int idx = threadIdx.x; idx < 128 * 32; idx += 256) {
        int row = idx >> 5, kq = idx & 31;
        f32x4 v = *(const f32x4*)&W[row * 128 + kq * 4];
        int ct = row >> 4, c = row & 15;
        int k0 = kq * 4;
        int kc = k0 >> 5, q16 = (k0 & 31) >> 3, j2 = (k0 & 7) >> 1;
        unsigned* dst = (unsigned*)&Bs[(ct * 4 + kc) * 64 + q16 * 16 + c];
        dst[j2]     = ((unsigned)bf16_rne(v.y) << 16) | bf16_rne(v.x);
        dst[j2 + 1] = ((unsigned)bf16_rne(v.w) << 16) | bf16_rne(v.z);
    }
    __syncthreads();
    int half = blockIdx.x >= KM_HALF;
    const float* src = half ? srcB : srcA;
    float* kpp = half ? (kp + 128) : kp;
    int rb = (half ? blockIdx.x - KM_HALF : blockIdx.x) * 128;
    int wv = threadIdx.x >> 6, l = threadIdx.x & 63;
    int q = l >> 4, c16 = l & 15;
    int rw = rb + wv * 32;
    const float* xr0 = &src[(size_t)(rw + c16) * 128 + q * 8];
    const float* xr1 = xr0 + 16 * 128;
    bf16x8 f00 = cvt_relu(*(const f32x4*)(xr0 +  0), *(const f32x4*)(xr0 +  4));
    bf16x8 f01 = cvt_relu(*(const f32x4*)(xr0 + 32), *(const f32x4*)(xr0 + 36));
    bf16x8 f02 = cvt_relu(*(const f32x4*)(xr0 + 64), *(const f32x4*)(xr0 + 68));
    bf16x8 f03 = cvt_relu(*(const f32x4*)(xr0 + 96), *(const f32x4*)(xr0 + 100));
    bf16x8 f10 = cvt_relu(*(const f32x4*)(xr1 +  0), *(const f32x4*)(xr1 +  4));
    bf16x8 f11 = cvt_relu(*(const f32x4*)(xr1 + 32), *(const f32x4*)(xr1 + 36));
    bf16x8 f12 = cvt_relu(*(const f32x4*)(xr1 + 64), *(const f32x4*)(xr1 + 68));
    bf16x8 f13 = cvt_relu(*(const f32x4*)(xr1 + 96), *(const f32x4*)(xr1 + 100));
    float bv0 = bias[c16],      bv1 = bias[16 + c16], bv2 = bias[32 + c16], bv3 = bias[48 + c16];
    float bv4 = bias[64 + c16], bv5 = bias[80 + c16], bv6 = bias[96 + c16], bv7 = bias[112 + c16];
    int row0 = rw + q * 4;
    int row1 = row0 + 16;
    float cs0 = 0.f, cs1 = 0.f, cs2 = 0.f, cs3 = 0.f, cs4 = 0.f, cs5 = 0.f, cs6 = 0.f, cs7 = 0.f;
    #define CT_STEP(CT, CS, BV) { \
        bf16x8 b0 = Bs[((CT) * 4 + 0) * 64 + l]; \
        bf16x8 b1 = Bs[((CT) * 4 + 1) * 64 + l]; \
        bf16x8 b2 = Bs[((CT) * 4 + 2) * 64 + l]; \
        bf16x8 b3 = Bs[((CT) * 4 + 3) * 64 + l]; \
        f32x4 aA = {0,0,0,0}, aB = {0,0,0,0}, aC = {0,0,0,0}, aD = {0,0,0,0}; \
        aA = MFMA(f00, b0, aA); aB = MFMA(f01, b1, aB); \
        aA = MFMA(f02, b2, aA); aB = MFMA(f03, b3, aB); \
        aC = MFMA(f10, b0, aC); aD = MFMA(f11, b1, aD); \
        aC = MFMA(f12, b2, aC); aD = MFMA(f13, b3, aD); \
        f32x4 d0 = aA + aB, d1 = aC + aD; \
        float s = 0.f; \
        if (row0 + 0 < NG) s += fast_tanh(d0[0] + (BV)); \
        if (row0 + 1 < NG) s += fast_tanh(d0[1] + (BV)); \
        if (row0 + 2 < NG) s += fast_tanh(d0[2] + (BV)); \
        if (row0 + 3 < NG) s += fast_tanh(d0[3] + (BV)); \
        if (row1 + 0 < NG) s += fast_tanh(d1[0] + (BV)); \
        if (row1 + 1 < NG) s += fast_tanh(d1[1] + (BV)); \
        if (row1 + 2 < NG) s += fast_tanh(d1[2] + (BV)); \
        if (row1 + 3 < NG) s += fast_tanh(d1[3] + (BV)); \
        CS += s; }
    CT_STEP(0, cs0, bv0) CT_STEP(1, cs1, bv1) CT_STEP(2, cs2, bv2) CT_STEP(3, cs3, bv3)
    CT_STEP(4, cs4, bv4) CT_STEP(5, cs5, bv5) CT_STEP(6, cs6, bv6) CT_STEP(7, cs7, bv7)
    #undef CT_STEP
    __syncthreads();
    float* red = (float*)Bs;
    #define REDUCE_CT(CT, CS) { \
        float v = (CS); \
        v += __shfl_xor(v, 16); v += __shfl_xor(v, 32); \
        if (l < 16) red[wv * 128 + (CT) * 16 + l] = v; }
    REDUCE_CT(0, cs0) REDUCE_CT(1, cs1) REDUCE_CT(2, cs2) REDUCE_CT(3, cs3)
    REDUCE_CT(4, cs4) REDUCE_CT(5, cs5) REDUCE_CT(6, cs6) REDUCE_CT(7, cs7)
    #undef REDUCE_CT
    __syncthreads();
    if (threadIdx.x < 128) {
        float s = red[threadIdx.x] + red[128 + threadIdx.x]
                + red[256 + threadIdx.x] + red[384 + threadIdx.x];
        atomicAdd(&kpp[threadIdx.x], s);
    }
}

// ---------------- CSR build ----------------
__global__ void count_all(const int* __restrict__ gg_dst, const int* __restrict__ dg_dst,
                          int* __restrict__ deg) {
    int e = blockIdx.x * 256 + threadIdx.x;
    if (e < EGG) atomicAdd(&deg[gg_dst[e]], 1);
    else if (e < EALL) atomicAdd(&deg[NG + dg_dst[e - EGG]], 1);
}

__global__ void scan1(const int* __restrict__ deg, int* __restrict__ rp,
                      int* __restrict__ bsum, int N) {
    __shared__ int tsum[256];
    int t = threadIdx.x;
    int base = blockIdx.x * 1024 + t * 4;
    int v0 = 0, v1 = 0, v2 = 0, v3 = 0;
    if (base + 0 < N) v0 = deg[base + 0];
    if (base + 1 < N) v1 = deg[base + 1];
    if (base + 2 < N) v2 = deg[base + 2];
    if (base + 3 < N) v3 = deg[base + 3];
    int tot = v0 + v1 + v2 + v3;
    tsum[t] = tot;
    __syncthreads();
    for (int off = 1; off < 256; off <<= 1) {
        int y = (t >= off) ? tsum[t - off] : 0;
        __syncthreads();
        tsum[t] += y;
        __syncthreads();
    }
    int excl = tsum[t] - tot;
    if (base + 0 < N) rp[base + 0] = excl;
    if (base + 1 < N) rp[base + 1] = excl + v0;
    if (base + 2 < N) rp[base + 2] = excl + v0 + v1;
    if (base + 3 < N) rp[base + 3] = excl + v0 + v1 + v2;
    if (t == 255) bsum[blockIdx.x] = tsum[255];
}

__global__ void scan2(int* __restrict__ bsum, int NB) {
    __shared__ int s[256];
    int t = threadIdx.x;
    int v = (t < NB) ? bsum[t] : 0;
    s[t] = v;
    __syncthreads();
    for (int off = 1; off < 256; off <<= 1) {
        int y = (t >= off) ? s[t - off] : 0;
        __syncthreads();
        s[t] += y;
        __syncthreads();
    }
    if (t < NB) bsum[t] = s[t] - v;
}

__global__ void scan3(int* __restrict__ rp, const int* __restrict__ bsum,
                      int* __restrict__ bcur, int N, int E) {
    int i = blockIdx.x * 256 + threadIdx.x;
    if (i < N) {
        int v = rp[i] + bsum[i >> 10];
        rp[i] = v;
        if ((i & (BDSTS - 1)) == 0) bcur[i >> SHIFT] = v;
    }
    if (i == 0) rp[N] = E;
}

// ---------------- S1: LDS-staged bucket scatter ----------------
__launch_bounds__(256)
__global__ void bucket_scatter(const int* __restrict__ gg_src, const int* __restrict__ gg_dst,
                               const int* __restrict__ dg_src, const int* __restrict__ dg_dst,
                               int* __restrict__ bcur, unsigned int* __restrict__ colPacked) {
    __shared__ int cnt[256], scanE[256], gbase[256], cursor[256];
    __shared__ unsigned int sorted[S1_CH];
    __shared__ unsigned char bof[S1_CH];
    int t = threadIdx.x;
    cnt[t] = 0;
    __syncthreads();
    int base = blockIdx.x * S1_CH;
    for (int k = 0; k < S1_CH; k += 256) {
        int e = base + k + t;
        if (e < EALL) {
            int dn = (e < EGG) ? gg_dst[e] : (NG + dg_dst[e - EGG]);
            atomicAdd(&cnt[dn >> SHIFT], 1);
        }
    }
    __syncthreads();
    int v = cnt[t];
    __shared__ int ss[256];
    ss[t] = v;
    __syncthreads();
    for (int off = 1; off < 256; off <<= 1) {
        int y = (t >= off) ? ss[t - off] : 0;
        __syncthreads();
        ss[t] += y;
        __syncthreads();
    }
    scanE[t] = ss[t] - v;
    cursor[t] = ss[t] - v;
    if (t < NBUK && v > 0) gbase[t] = atomicAdd(&bcur[t], v);
    __syncthreads();
    for (int k = 0; k < S1_CH; k += 256) {
        int e = base + k + t;
        if (e < EALL) {
            int s, dn;
            if (e < EGG) { s = gg_src[e]; dn = gg_dst[e]; }
            else         { s = dg_src[e - EGG]; dn = NG + dg_dst[e - EGG]; }
            int b = dn >> SHIFT;
            int slot = atomicAdd(&cursor[b], 1);
            sorted[slot] = ((unsigned int)s << SHIFT) | (unsigned int)(dn & (BDSTS - 1));
            bof[slot] = (unsigned char)b;
        }
    }
    __syncthreads();
    int total = ss[255];
    for (int f = t; f < total; f += 256) {
        int b = bof[f];
        colPacked[gbase[b] + (f - scanE[b])] = sorted[f];
    }
}

// ---------------- S2: bucket-local counting sort ----------------
__launch_bounds__(256)
__global__ void bucket_sort(const unsigned int* __restrict__ colPacked,
                            const int* __restrict__ rp, int* __restrict__ col) {
    __shared__ int lcur[BDSTS];
    int b = blockIdx.x;
    int d0 = b << SHIFT;
    int dEnd = min(d0 + BDSTS, NALL);
    int nd = dEnd - d0;
    for (int i = threadIdx.x; i < nd; i += 256) lcur[i] = rp[d0 + i];
    __syncthreads();
    int ebase = rp[d0];
    int eend  = rp[dEnd];
    for (int i = ebase + threadIdx.x; i < eend; i += 256) {
        unsigned int p = colPacked[i];
        int dlow = (int)(p & (BDSTS - 1));
        int s    = (int)(p >> SHIFT);
        int pos = atomicAdd(&lcur[dlow], 1);
        col[pos] = s;
    }
}

// ---------------- fused GAT gather v5: f16 rows + fma_mix, gg+dg merged ----------------
__launch_bounds__(256)
__global__ void gat_gather_all(const int* __restrict__ rp, const int* __restrict__ col,
                               const float* __restrict__ as_gg, const float* __restrict__ ad_gg,
                               const unsigned short* __restrict__ xg_bf,
                               const float* __restrict__ as_dg, const float* __restrict__ ad_dg,
                               const unsigned short* __restrict__ xd_bf,
                               float* __restrict__ out_gg, float* __restrict__ out_dg) {
    int wid = (blockIdx.x * 256 + threadIdx.x) >> 6;
    int l = threadIdx.x & 63;
    if (wid >= NALL) return;
    int isdg = wid >= NG;
    int d = isdg ? wid - NG : wid;
    const float* a_s = isdg ? as_dg : as_gg;
    const float* a_d = isdg ? ad_dg : ad_gg;
    const unsigned short* xbf = isdg ? xd_bf : xg_bf;
    float* outb = (isdg ? out_dg : out_gg) + (size_t)d * 128;

    int base = rp[wid];
    int deg = rp[wid + 1] - base;

    int hl = l & 7;
    int g  = l >> 3;
    float adl = a_d[d * 8 + hl];
    float m = -1e30f, ssum = 0.f;
    for (int c0 = 0; c0 < deg; c0 += 64) {
        int myi = c0 + l;
        int colreg = (myi < deg) ? col[base + myi] : 0;
        int lim = min(deg - c0, 64);
        for (int t = g; t < lim; t += 8) {
            int s = __shfl(colreg, t);
            float a = a_s[s * 8 + hl] + adl;
            a = a > 0.f ? a : 0.2f * a;
            float nm = fmaxf(m, a);
            ssum = ssum * __expf(m - nm) + __expf(a - nm);
            m = nm;
        }
    }
    for (int off = 8; off < 64; off <<= 1) {
        float m2 = __shfl_xor(m, off);
        float s2 = __shfl_xor(ssum, off);
        float nm = fmaxf(m, m2);
        ssum = ssum * __expf(m - nm) + s2 * __expf(m2 - nm);
        m = nm;
    }
    float rsc = 1.f / (ssum + 1e-16f);   // lane l holds (m, rsc) for head l&7

    // phase 2: quarter q = edge slot (4 edges/iter), cq = col block (8 f16 cols)
    int q = l >> 4;
    int cq = l & 15;
    int hq = cq >> 1;
    uint32_t colbyte = (uint32_t)cq << 4;  // 16 B per col block
    float a0 = 0.f, a1 = 0.f, a2 = 0.f, a3 = 0.f, a4 = 0.f, a5 = 0.f, a6 = 0.f, a7 = 0.f;
    for (int c0 = 0; c0 < deg; c0 += 64) {
        int myi = c0 + l;
        int colreg = (myi < deg) ? col[base + myi] : 0;
        int lim = min(deg - c0, 64);
        for (int j8 = 0; j8 < lim; j8 += 8) {
            float alpha;
            {
                int s = __shfl(colreg, j8 + g);
                float a = a_s[s * 8 + hl] + adl;
                a = a > 0.f ? a : 0.2f * a;
                alpha = __expf(a - m) * rsc;
            }
            int jlim = min(lim - j8, 8);
            #pragma unroll
            for (int sub = 0; sub < 8; sub += 4) {
                int jrel = sub + q;
                int s = __shfl(colreg, j8 + jrel);
                float al = __shfl(alpha, (jrel << 3) + hq);
                al = (jrel < jlim) ? al : 0.f;
                const uint4 rv = *(const uint4*)((const char*)xbf +
                                    (((size_t)(uint32_t)s << 8) + colbyte));
                float2 f01 = __half22float2(*(const __half2*)&rv.x);
                float2 f23 = __half22float2(*(const __half2*)&rv.y);
                float2 f45 = __half22float2(*(const __half2*)&rv.z);
                float2 f67 = __half22float2(*(const __half2*)&rv.w);
                a0 += al * f01.x; a1 += al * f01.y;
                a2 += al * f23.x; a3 += al * f23.y;
                a4 += al * f45.x; a5 += al * f45.y;
                a6 += al * f67.x; a7 += al * f67.y;
            }
        }
    }
    a0 += __shfl_xor(a0, 16); a0 += __shfl_xor(a0, 32);
    a1 += __shfl_xor(a1, 16); a1 += __shfl_xor(a1, 32);
    a2 += __shfl_xor(a2, 16); a2 += __shfl_xor(a2, 32);
    a3 += __shfl_xor(a3, 16); a3 += __shfl_xor(a3, 32);
    a4 += __shfl_xor(a4, 16); a4 += __shfl_xor(a4, 32);
    a5 += __shfl_xor(a5, 16); a5 += __shfl_xor(a5, 32);
    a6 += __shfl_xor(a6, 16); a6 += __shfl_xor(a6, 32);
    a7 += __shfl_xor(a7, 16); a7 += __shfl_xor(a7, 32);
    if (q == 0) {
        float4 o0 = {a0, a1, a2, a3};
        float4 o1 = {a4, a5, a6, a7};
        *(float4*)&outb[cq * 8] = o0;
        *(float4*)&outb[cq * 8 + 4] = o1;
    }
}

// ---------------- semantic softmax (2 scores) ----------------
__global__ void score_attn(const float* __restrict__ kpart, const float* __restrict__ q,
                           float* __restrict__ attn) {
    __shared__ float r0[128], r1[128];
    int t = threadIdx.x;
    r0[t] = q[t] * kpart[t];
    r1[t] = q[t] * kpart[128 + t];
    __syncthreads();
    for (int s = 64; s > 0; s >>= 1) {
        if (t < s) { r0[t] += r0[t + s]; r1[t] += r1[t + s]; }
        __syncthreads();
    }
    if (t == 0) {
        float s0 = r0[0] / (float)NG, s1 = r1[0] / (float)NG;
        float mx = fmaxf(s0, s1);
        float e0 = expf(s0 - mx), e1 = expf(s1 - mx);
        attn[0] = e0 / (e0 + e1);
        attn[1] = e1 / (e0 + e1);
    }
}

// ---------------- fused combine + final linear ----------------
__launch_bounds__(256)
__global__ void final_lin(const float* __restrict__ gg, const float* __restrict__ dgb,
                          const float* __restrict__ attn, const float* __restrict__ lin_w,
                          const float* __restrict__ lin_b, float* __restrict__ outp) {
    int wid = (blockIdx.x * 256 + threadIdx.x) >> 6;
    int l = threadIdx.x & 63;
    if (wid >= NG) return;
    float a0 = attn[0], a1 = attn[1];
    float2 gv = *(const float2*)&gg[(size_t)wid * 128 + l * 2];
    float2 dv = *(const float2*)&dgb[(size_t)wid * 128 + l * 2];
    float fx = a0 * fmaxf(gv.x, 0.f) + a1 * fmaxf(dv.x, 0.f);
    float fy = a0 * fmaxf(gv.y, 0.f) + a1 * fmaxf(dv.y, 0.f);
    float2 w0 = *(const float2*)&lin_w[l * 2];
    float2 w1 = *(const float2*)&lin_w[128 + l * 2];
    float p0 = fx * w0.x + fy * w0.y;
    float p1 = fx * w1.x + fy * w1.y;
    for (int off = 32; off > 0; off >>= 1) {
        p0 += __shfl_down(p0, off);
        p1 += __shfl_down(p1, off);
    }
    if (l == 0) {
        float2 o;
        o.x = p0 + lin_b[0];
        o.y = p1 + lin_b[1];
        *(float2*)&outp[wid * 2] = o;
    }
}

extern "C" void kernel_launch(void* const* d_in, const int* in_sizes, int n_in,
                              void* d_out, int out_size, void* d_ws, size_t ws_size,
                              hipStream_t stream) {
    const float* x_gene    = (const float*)d_in[0];
    const float* x_disease = (const float*)d_in[1];
    const int*   edge_gg   = (const int*)d_in[2];
    const int*   edge_dg   = (const int*)d_in[3];
    const float* pg_w      = (const float*)d_in[4];
    const float* pg_b      = (const float*)d_in[5];
    const float* pd_w      = (const float*)d_in[6];
    const float* pd_b      = (const float*)d_in[7];
    const float* att_src_gg= (const float*)d_in[8];
    const float* att_dst_gg= (const float*)d_in[9];
    const float* att_src_dg= (const float*)d_in[10];
    const float* att_dst_dg= (const float*)d_in[11];
    const float* k_lin_w   = (const float*)d_in[12];
    const float* k_lin_b   = (const float*)d_in[13];
    const float* q         = (const float*)d_in[14];
    const float* lin_w     = (const float*)d_in[15];
    const float* lin_b     = (const float*)d_in[16];
    float* out = (float*)d_out;
    float* ws  = (float*)d_ws;

    float* out_gg = ws + OFF_OUT_GG;
    float* out_dg = ws + OFF_OUT_DG;
    unsigned int* colPacked = (unsigned int*)(ws + OFF_OUT_GG);  // overlay
    unsigned short* xg_bf = (unsigned short*)(ws + OFF_XG);
    unsigned short* xd_bf = (unsigned short*)(ws + OFF_XD);
    float* a_src_gg = ws + OFF_ASG;
    float* a_dst_gg = ws + OFF_ADG;
    float* a_dst_dg = ws + OFF_ADD;
    float* a_src_dg = ws + OFF_ASD;
    float* kpart  = ws + OFF_KPART;
    float* attn   = ws + OFF_ATTN;
    float* wtilG  = ws + OFF_WTIL;
    float* btilG  = ws + OFF_BTIL;
    float* wtilD  = ws + OFF_WTILD;
    float* btilD  = ws + OFF_BTILD;
    int* deg  = (int*)(ws + OFF_DEG);
    int* rp   = (int*)(ws + OFF_RP);
    int* bcur = (int*)(ws + OFF_BCUR);
    int* bsum = (int*)(ws + OFF_BSUM);
    int* col  = (int*)(ws + OFF_COL);

    const int* gg_src = edge_gg;
    const int* gg_dst = edge_gg + EGG;
    const int* dg_src = edge_dg;
    const int* dg_dst = edge_dg + EDG;

    // 1. zero kpart + degree arrays; wtilde precompute
    hipLaunchKernelGGL(init_zero_k, dim3((ZERO_CNT + 255) / 256), dim3(256), 0, stream,
                       ws + ZERO_BASE, ZERO_CNT);
    hipLaunchKernelGGL(make_wtil, dim3(8), dim3(256), 0, stream,
                       pg_w, pg_b, att_src_gg, att_dst_gg, att_dst_dg, 3, wtilG, btilG);
    hipLaunchKernelGGL(make_wtil, dim3(4), dim3(256), 0, stream,
                       pd_w, pd_b, att_src_dg, att_src_dg, att_src_dg, 1, wtilD, btilD);
    // 2. split-bf16 MFMA projections (f16 table + fused logits)
    hipLaunchKernelGGL((proj_mfma<3>), dim3((NG + 127) / 128), dim3(256), 0, stream,
                       x_gene, pg_w, pg_b, wtilG, btilG, xg_bf,
                       a_src_gg, a_dst_gg, a_dst_dg, NG);
    hipLaunchKernelGGL((proj_mfma<1>), dim3((ND + 127) / 128), dim3(256), 0, stream,
                       x_disease, pd_w, pd_b, wtilD, btilD, xd_bf,
                       a_src_dg, (float*)nullptr, (float*)nullptr, ND);
    // 3. CSR row pointers
    hipLaunchKernelGGL(count_all, dim3((EALL + 255) / 256), dim3(256), 0, stream,
                       gg_dst, dg_dst, deg);
    hipLaunchKernelGGL(scan1, dim3((NALL + 1023) / 1024), dim3(256), 0, stream, deg, rp, bsum, NALL);
    hipLaunchKernelGGL(scan2, dim3(1), dim3(256), 0, stream, bsum, (NALL + 1023) / 1024);
    hipLaunchKernelGGL(scan3, dim3((NALL + 255) / 256), dim3(256), 0, stream, rp, bsum, bcur, NALL, EALL);
    // 4. two-level bucket sort into CSR col
    hipLaunchKernelGGL(bucket_scatter, dim3((EALL + S1_CH - 1) / S1_CH), dim3(256), 0, stream,
                       gg_src, gg_dst, dg_src, dg_dst, bcur, colPacked);
    hipLaunchKernelGGL(bucket_sort, dim3(NBUK), dim3(256), 0, stream, colPacked, rp, col);
    // 5. merged fused gather (out_gg overwrites colPacked overlay — dead by now)
    hipLaunchKernelGGL(gat_gather_all, dim3((NALL + 3) / 4), dim3(256), 0, stream,
                       rp, col, a_src_gg, a_dst_gg, xg_bf, a_src_dg, a_dst_dg, xd_bf,
                       out_gg, out_dg);
    // 6. semantic attention
    hipLaunchKernelGGL(kmean_mfma, dim3(KM_HALF * 2), dim3(256), 0, stream,
                       out_gg, out_dg, k_lin_w, k_lin_b, kpart);
    hipLaunchKernelGGL(score_attn, dim3(1), dim3(128), 0, stream, kpart, q, attn);
    // 7. fused combine + final linear
    hipLaunchKernelGGL(final_lin, dim3((NG + 3) / 4), dim3(256), 0, stream,
                       out_gg, out_dg, attn, lin_w, lin_b, out);
}

// Round 11
// 374.801 us; speedup vs baseline: 2.0570x; 1.2725x over previous
//
#include <hip/hip_runtime.h>
#include <hip/hip_fp16.h>
#include <math.h>

#define NG 100000
#define ND 50000
#define EGG 1600000
#define EDG 800000
#define EALL (EGG + EDG)
#define NALL (NG + NG)
#define HID 128
#define NH 8

// bucket sort params
#define SHIFT 11
#define BDSTS (1 << SHIFT)
#define NBUK  ((NALL + BDSTS - 1) / BDSTS)   // 98
#define BUKCAP 36864                          // mean 32768 + ~23 sigma
#define S1_CH 6144
#define KM_HALF ((NG + 127) / 128)            // 782 blocks per metapath

// ---------------- workspace layout (4-byte element offsets) ----------------
// f16 [NG][128] = 6,400,000 floats; f16 [ND][128] = 3,200,000 floats
#define OFF_OUT_GG 0UL          // 6,400,000  (colPacked overlay: 98*36864 = 3,612,672 u32)
#define OFF_OUT_DG 6400000UL    // 6,400,000
#define OFF_XG     12800000UL   // 6,400,000  -> ends 19,200,000
#define OFF_XD     19200000UL   // 3,200,000  -> ends 22,400,000
#define OFF_ASG    22400000UL   //   800,000
#define OFF_ADG    23200000UL   //   800,000
#define OFF_ADD    24000000UL   //   800,000
#define OFF_ASD    24800000UL   //   400,000  -> ends 25,200,000
#define OFF_KPART  25200000UL   //       256  (zero-init)
#define OFF_BCNT   25200256UL   //       128  (zero-init)
#define ZERO_BASE  OFF_KPART
#define ZERO_CNT   384
#define OFF_ATTN   25200384UL   //         2 (+pad)
#define OFF_BBASE  25200512UL   //       128
#define OFF_RP     25200640UL   //   200,001 -> ends 25,400,641 (+pad)
#define OFF_COL    25400704UL   // 2,400,000 -> ends 27,800,704
#define OFF_WTIL   27800704UL   //     3,072
#define OFF_BTIL   27803776UL   //        24
#define OFF_WTILD  27803904UL   //     1,024
#define OFF_BTILD  27804928UL   //         8
// end ~27,804,936 floats = 111 MB (ws proven >= 202 MB in R1-R9)

typedef float  f32x4  __attribute__((ext_vector_type(4)));
typedef short  bf16x8 __attribute__((ext_vector_type(8)));
typedef _Float16 f16x8 __attribute__((ext_vector_type(8)));
#define MFMA(a, b, c)  __builtin_amdgcn_mfma_f32_16x16x32_bf16(a, b, c, 0, 0, 0)
#define MFMAH(a, b, c) __builtin_amdgcn_mfma_f32_16x16x32_f16(a, b, c, 0, 0, 0)

// acc += f16(lo/hi half of SRC u32) * AL   (single v_fma_mix_f32)
#define FMAMIX_LO(ACC, SRC, AL) \
    asm("v_fma_mix_f32 %0, %1, %2, %0 op_sel:[0,0,0] op_sel_hi:[1,0,0]" \
        : "+v"(ACC) : "v"(SRC), "v"(AL))
#define FMAMIX_HI(ACC, SRC, AL) \
    asm("v_fma_mix_f32 %0, %1, %2, %0 op_sel:[1,0,0] op_sel_hi:[1,0,0]" \
        : "+v"(ACC) : "v"(SRC), "v"(AL))

__device__ __forceinline__ unsigned short bf16_rne(float f) {
    unsigned u = __float_as_uint(f);
    u += 0x7FFFu + ((u >> 16) & 1u);
    return (unsigned short)(u >> 16);
}
__device__ __forceinline__ float bf16f(unsigned short h) {
    return __uint_as_float(((unsigned)h) << 16);
}
__device__ __forceinline__ unsigned short f16_bits(float f) {
    __half h = __float2half(f);
    return *(unsigned short*)&h;
}
__device__ __forceinline__ float fast_tanh(float x) {
    x = fminf(fmaxf(x, -15.f), 15.f);
    float t = __expf(2.f * x);
    return (t - 1.f) / (t + 1.f);
}
__device__ __forceinline__ bf16x8 cvt_hi8(f32x4 v0, f32x4 v1) {
    bf16x8 f;
    f[0] = (short)bf16_rne(v0.x); f[1] = (short)bf16_rne(v0.y);
    f[2] = (short)bf16_rne(v0.z); f[3] = (short)bf16_rne(v0.w);
    f[4] = (short)bf16_rne(v1.x); f[5] = (short)bf16_rne(v1.y);
    f[6] = (short)bf16_rne(v1.z); f[7] = (short)bf16_rne(v1.w);
    return f;
}
__device__ __forceinline__ bf16x8 cvt_lo8(f32x4 v0, f32x4 v1, bf16x8 h) {
    bf16x8 f;
    f[0] = (short)bf16_rne(v0.x - bf16f((unsigned short)h[0]));
    f[1] = (short)bf16_rne(v0.y - bf16f((unsigned short)h[1]));
    f[2] = (short)bf16_rne(v0.z - bf16f((unsigned short)h[2]));
    f[3] = (short)bf16_rne(v0.w - bf16f((unsigned short)h[3]));
    f[4] = (short)bf16_rne(v1.x - bf16f((unsigned short)h[4]));
    f[5] = (short)bf16_rne(v1.y - bf16f((unsigned short)h[5]));
    f[6] = (short)bf16_rne(v1.z - bf16f((unsigned short)h[6]));
    f[7] = (short)bf16_rne(v1.w - bf16f((unsigned short)h[7]));
    return f;
}
// packed relu on 2x f16 in a u32: zero any half with sign bit set
__device__ __forceinline__ unsigned relu_pk(unsigned u) {
    return u & ~(((u & 0x80008000u) >> 15) * 0xFFFFu);
}
union U4F16 { uint4 u; f16x8 f; };

// ---------------- init ----------------
__global__ void init_zero_k(float* __restrict__ p, int n) {
    int i = blockIdx.x * 256 + threadIdx.x;
    if (i < n) p[i] = 0.f;
}

// ---------------- wtilde: w~[v*8+h][k] = sum_c att_v[h*16+c] * W[h*16+c][k] ----------------
__global__ void make_wtil(const float* __restrict__ W, const float* __restrict__ bias,
                          const float* __restrict__ a0, const float* __restrict__ a1,
                          const float* __restrict__ a2, int natt,
                          float* __restrict__ wtil, float* __restrict__ btil) {
    int tot = natt * 8 * 128;
    for (int i = blockIdx.x * 256 + threadIdx.x; i < tot; i += gridDim.x * 256) {
        int k = i & 127, cc = i >> 7;
        int v = cc >> 3, h = cc & 7;
        const float* av = (v == 0) ? a0 : (v == 1) ? a1 : a2;
        float s = 0.f;
        #pragma unroll
        for (int c = 0; c < 16; c++) s += av[h * 16 + c] * W[(h * 16 + c) * 128 + k];
        wtil[i] = s;
    }
    if (blockIdx.x == 0 && threadIdx.x < natt * 8) {
        int v = threadIdx.x >> 3, h = threadIdx.x & 7;
        const float* av = (v == 0) ? a0 : (v == 1) ? a1 : a2;
        float s = 0.f;
        #pragma unroll
        for (int c = 0; c < 16; c++) s += av[h * 16 + c] * bias[h * 16 + c];
        btil[threadIdx.x] = s;
    }
}

// ---------------- proj via split-bf16 MFMA (straight-line, scratch-free) ----------------
template<int NATT>
__launch_bounds__(256)
__global__ void proj_mfma(const float* __restrict__ x, const float* __restrict__ W,
                          const float* __restrict__ bias,
                          const float* __restrict__ wtil, const float* __restrict__ btil,
                          unsigned short* __restrict__ xbf,   // f16 [N][128]
                          float* __restrict__ o0, float* __restrict__ o1,
                          float* __restrict__ o2, int N) {
    constexpr int NTE = (NATT * 8 + 15) / 16;
    constexpr int NT = 8 + NTE;
    __shared__ bf16x8 Bhi[NT * 4 * 64];
    __shared__ bf16x8 Blo[8 * 4 * 64];
    for (int idx = threadIdx.x; idx < 128 * 32; idx += 256) {
        int row = idx >> 5, kq = idx & 31;
        f32x4 v = *(const f32x4*)&W[row * 128 + kq * 4];
        int ct = row >> 4, c = row & 15;
        int k0 = kq * 4;
        int kc = k0 >> 5, q16 = (k0 & 31) >> 3, j2 = (k0 & 7) >> 1;
        int slot = (ct * 4 + kc) * 64 + q16 * 16 + c;
        unsigned short hx = bf16_rne(v.x), hy = bf16_rne(v.y);
        unsigned short hz = bf16_rne(v.z), hw = bf16_rne(v.w);
        unsigned* dh = (unsigned*)&Bhi[slot];
        dh[j2]     = ((unsigned)hy << 16) | hx;
        dh[j2 + 1] = ((unsigned)hw << 16) | hz;
        unsigned* dl = (unsigned*)&Blo[slot];
        dl[j2]     = ((unsigned)bf16_rne(v.y - bf16f(hy)) << 16) | bf16_rne(v.x - bf16f(hx));
        dl[j2 + 1] = ((unsigned)bf16_rne(v.w - bf16f(hw)) << 16) | bf16_rne(v.z - bf16f(hz));
    }
    for (int idx = threadIdx.x; idx < NTE * 16 * 32; idx += 256) {
        int cc = idx >> 5, kq = idx & 31;
        f32x4 v = {0.f, 0.f, 0.f, 0.f};
        if (cc < NATT * 8) v = *(const f32x4*)&wtil[cc * 128 + kq * 4];
        int ct = 8 + (cc >> 4), c = cc & 15;
        int k0 = kq * 4;
        int kc = k0 >> 5, q16 = (k0 & 31) >> 3, j2 = (k0 & 7) >> 1;
        unsigned* dh = (unsigned*)&Bhi[(ct * 4 + kc) * 64 + q16 * 16 + c];
        dh[j2]     = ((unsigned)bf16_rne(v.y) << 16) | bf16_rne(v.x);
        dh[j2 + 1] = ((unsigned)bf16_rne(v.w) << 16) | bf16_rne(v.z);
    }
    __syncthreads();
    int wv = threadIdx.x >> 6, l = threadIdx.x & 63;
    int q = l >> 4, c16 = l & 15;
    int rw = blockIdx.x * 128 + wv * 32;
    int n0 = min(rw + c16, N - 1);
    int n1 = min(rw + 16 + c16, N - 1);
    const float* xr0 = &x[(size_t)n0 * 128 + q * 8];
    const float* xr1 = &x[(size_t)n1 * 128 + q * 8];
    #define LOADX(FH, FL, PTR, OFF) \
        bf16x8 FH, FL; \
        { f32x4 v0_ = *(const f32x4*)((PTR) + (OFF)); \
          f32x4 v1_ = *(const f32x4*)((PTR) + (OFF) + 4); \
          FH = cvt_hi8(v0_, v1_); FL = cvt_lo8(v0_, v1_, FH); }
    LOADX(xh00, xl00, xr0, 0)  LOADX(xh01, xl01, xr0, 32)
    LOADX(xh02, xl02, xr0, 64) LOADX(xh03, xl03, xr0, 96)
    LOADX(xh10, xl10, xr1, 0)  LOADX(xh11, xl11, xr1, 32)
    LOADX(xh12, xl12, xr1, 64) LOADX(xh13, xl13, xr1, 96)
    #undef LOADX
    int r0 = rw + q * 4;
    int r1 = r0 + 16;
    #define CT_MAIN(CT) { \
        bf16x8 bh0 = Bhi[((CT) * 4 + 0) * 64 + l]; \
        bf16x8 bh1 = Bhi[((CT) * 4 + 1) * 64 + l]; \
        bf16x8 bh2 = Bhi[((CT) * 4 + 2) * 64 + l]; \
        bf16x8 bh3 = Bhi[((CT) * 4 + 3) * 64 + l]; \
        bf16x8 bl0 = Blo[((CT) * 4 + 0) * 64 + l]; \
        bf16x8 bl1 = Blo[((CT) * 4 + 1) * 64 + l]; \
        bf16x8 bl2 = Blo[((CT) * 4 + 2) * 64 + l]; \
        bf16x8 bl3 = Blo[((CT) * 4 + 3) * 64 + l]; \
        f32x4 aA = {0,0,0,0}, aB = {0,0,0,0}, aC = {0,0,0,0}, aD = {0,0,0,0}; \
        aA = MFMA(xh00, bh0, aA); aB = MFMA(xh01, bh1, aB); \
        aC = MFMA(xh10, bh0, aC); aD = MFMA(xh11, bh1, aD); \
        aA = MFMA(xl00, bh0, aA); aB = MFMA(xl01, bh1, aB); \
        aC = MFMA(xl10, bh0, aC); aD = MFMA(xl11, bh1, aD); \
        aA = MFMA(xh00, bl0, aA); aB = MFMA(xh01, bl1, aB); \
        aC = MFMA(xh10, bl0, aC); aD = MFMA(xh11, bl1, aD); \
        aA = MFMA(xh02, bh2, aA); aB = MFMA(xh03, bh3, aB); \
        aC = MFMA(xh12, bh2, aC); aD = MFMA(xh13, bh3, aD); \
        aA = MFMA(xl02, bh2, aA); aB = MFMA(xl03, bh3, aB); \
        aC = MFMA(xl12, bh2, aC); aD = MFMA(xl13, bh3, aD); \
        aA = MFMA(xh02, bl2, aA); aB = MFMA(xh03, bl3, aB); \
        aC = MFMA(xh12, bl2, aC); aD = MFMA(xh13, bl3, aD); \
        f32x4 d0 = aA + aB, d1 = aC + aD; \
        float bv = bias[(CT) * 16 + c16]; \
        int col = (CT) * 16 + c16; \
        if (r0 + 0 < N) xbf[(size_t)(r0 + 0) * 128 + col] = f16_bits(d0[0] + bv); \
        if (r0 + 1 < N) xbf[(size_t)(r0 + 1) * 128 + col] = f16_bits(d0[1] + bv); \
        if (r0 + 2 < N) xbf[(size_t)(r0 + 2) * 128 + col] = f16_bits(d0[2] + bv); \
        if (r0 + 3 < N) xbf[(size_t)(r0 + 3) * 128 + col] = f16_bits(d0[3] + bv); \
        if (r1 + 0 < N) xbf[(size_t)(r1 + 0) * 128 + col] = f16_bits(d1[0] + bv); \
        if (r1 + 1 < N) xbf[(size_t)(r1 + 1) * 128 + col] = f16_bits(d1[1] + bv); \
        if (r1 + 2 < N) xbf[(size_t)(r1 + 2) * 128 + col] = f16_bits(d1[2] + bv); \
        if (r1 + 3 < N) xbf[(size_t)(r1 + 3) * 128 + col] = f16_bits(d1[3] + bv); }
    CT_MAIN(0) CT_MAIN(1) CT_MAIN(2) CT_MAIN(3)
    CT_MAIN(4) CT_MAIN(5) CT_MAIN(6) CT_MAIN(7)
    #undef CT_MAIN
    #define CT_ATT(TE) { \
        bf16x8 bh0 = Bhi[((8 + (TE)) * 4 + 0) * 64 + l]; \
        bf16x8 bh1 = Bhi[((8 + (TE)) * 4 + 1) * 64 + l]; \
        bf16x8 bh2 = Bhi[((8 + (TE)) * 4 + 2) * 64 + l]; \
        bf16x8 bh3 = Bhi[((8 + (TE)) * 4 + 3) * 64 + l]; \
        f32x4 aA = {0,0,0,0}, aB = {0,0,0,0}, aC = {0,0,0,0}, aD = {0,0,0,0}; \
        aA = MFMA(xh00, bh0, aA); aB = MFMA(xh01, bh1, aB); \
        aC = MFMA(xh10, bh0, aC); aD = MFMA(xh11, bh1, aD); \
        aA = MFMA(xh02, bh2, aA); aB = MFMA(xh03, bh3, aB); \
        aC = MFMA(xh12, bh2, aC); aD = MFMA(xh13, bh3, aD); \
        f32x4 d0 = aA + aB, d1 = aC + aD; \
        int cc = (TE) * 16 + c16; \
        if (cc < NATT * 8) { \
            float bt = btil[cc]; \
            int v = cc >> 3, h = cc & 7; \
            float* op = (v == 0) ? o0 : ((v == 1) ? o1 : o2); \
            if (r0 + 0 < N) op[(r0 + 0) * 8 + h] = d0[0] + bt; \
            if (r0 + 1 < N) op[(r0 + 1) * 8 + h] = d0[1] + bt; \
            if (r0 + 2 < N) op[(r0 + 2) * 8 + h] = d0[2] + bt; \
            if (r0 + 3 < N) op[(r0 + 3) * 8 + h] = d0[3] + bt; \
            if (r1 + 0 < N) op[(r1 + 0) * 8 + h] = d1[0] + bt; \
            if (r1 + 1 < N) op[(r1 + 1) * 8 + h] = d1[1] + bt; \
            if (r1 + 2 < N) op[(r1 + 2) * 8 + h] = d1[2] + bt; \
            if (r1 + 3 < N) op[(r1 + 3) * 8 + h] = d1[3] + bt; } }
    CT_ATT(0)
    if constexpr (NTE > 1) { CT_ATT(1) }
    #undef CT_ATT
}

// ---------------- K1: fused bucket scatter (fixed-capacity regions, no deg atomics) ----------------
__launch_bounds__(256)
__global__ void fused_scatter(const int* __restrict__ gg_src, const int* __restrict__ gg_dst,
                              const int* __restrict__ dg_src, const int* __restrict__ dg_dst,
                              int* __restrict__ bcnt, unsigned int* __restrict__ colPacked) {
    __shared__ int cnt[256], scanE[256], gbase[256], cursor[256];
    __shared__ int ss[256];
    __shared__ unsigned int sorted[S1_CH];
    __shared__ unsigned char bof[S1_CH];
    int t = threadIdx.x;
    cnt[t] = 0;
    __syncthreads();
    int base = blockIdx.x * S1_CH;
    for (int k = 0; k < S1_CH; k += 256) {
        int e = base + k + t;
        if (e < EALL) {
            int dn = (e < EGG) ? gg_dst[e] : (NG + dg_dst[e - EGG]);
            atomicAdd(&cnt[dn >> SHIFT], 1);
        }
    }
    __syncthreads();
    int v = cnt[t];
    ss[t] = v;
    __syncthreads();
    for (int off = 1; off < 256; off <<= 1) {
        int y = (t >= off) ? ss[t - off] : 0;
        __syncthreads();
        ss[t] += y;
        __syncthreads();
    }
    scanE[t] = ss[t] - v;
    cursor[t] = ss[t] - v;
    if (t < NBUK && v > 0) gbase[t] = atomicAdd(&bcnt[t], v);
    __syncthreads();
    for (int k = 0; k < S1_CH; k += 256) {
        int e = base + k + t;
        if (e < EALL) {
            int s, dn;
            if (e < EGG) { s = gg_src[e]; dn = gg_dst[e]; }
            else         { s = dg_src[e - EGG]; dn = NG + dg_dst[e - EGG]; }
            int b = dn >> SHIFT;
            int slot = atomicAdd(&cursor[b], 1);
            sorted[slot] = ((unsigned int)s << SHIFT) | (unsigned int)(dn & (BDSTS - 1));
            bof[slot] = (unsigned char)b;
        }
    }
    __syncthreads();
    int total = ss[255];
    for (int f = t; f < total; f += 256) {
        int b = bof[f];
        colPacked[(size_t)b * BUKCAP + gbase[b] + (f - scanE[b])] = sorted[f];
    }
}

// ---------------- K2: bucket-base scan (98 buckets) ----------------
__global__ void scan_buckets(const int* __restrict__ bcnt, int* __restrict__ bbase,
                             int* __restrict__ rp) {
    __shared__ int s[128];
    int t = threadIdx.x;
    int v = (t < NBUK) ? bcnt[t] : 0;
    s[t] = v;
    __syncthreads();
    for (int off = 1; off < 128; off <<= 1) {
        int y = (t >= off) ? s[t - off] : 0;
        __syncthreads();
        s[t] += y;
        __syncthreads();
    }
    if (t < NBUK) bbase[t] = s[t] - v;
    if (t == 0) rp[NALL] = EALL;
}

// ---------------- K3: per-bucket LDS histogram + scan -> rp, col ----------------
__launch_bounds__(256)
__global__ void bucket_build(const unsigned int* __restrict__ colPacked,
                             const int* __restrict__ bcnt, const int* __restrict__ bbase,
                             int* __restrict__ rp, int* __restrict__ col) {
    __shared__ int lcur[BDSTS];
    __shared__ int tsum[256];
    int b = blockIdx.x;
    int t = threadIdx.x;
    int d0 = b << SHIFT;
    int nd = min(BDSTS, NALL - d0);
    int cnt = bcnt[b];
    const unsigned int* pk = colPacked + (size_t)b * BUKCAP;
    for (int i = t; i < BDSTS; i += 256) lcur[i] = 0;
    __syncthreads();
    for (int i = t; i < cnt; i += 256)
        atomicAdd(&lcur[pk[i] & (BDSTS - 1)], 1);
    __syncthreads();
    int h0 = lcur[t * 8 + 0], h1 = lcur[t * 8 + 1], h2 = lcur[t * 8 + 2], h3 = lcur[t * 8 + 3];
    int h4 = lcur[t * 8 + 4], h5 = lcur[t * 8 + 5], h6 = lcur[t * 8 + 6], h7 = lcur[t * 8 + 7];
    int tot = h0 + h1 + h2 + h3 + h4 + h5 + h6 + h7;
    tsum[t] = tot;
    __syncthreads();
    for (int off = 1; off < 256; off <<= 1) {
        int y = (t >= off) ? tsum[t - off] : 0;
        __syncthreads();
        tsum[t] += y;
        __syncthreads();
    }
    int gb = bbase[b];
    int pp = tsum[t] - tot + gb;
    __syncthreads();
    #define EMIT(J, HJ) { int idx = t * 8 + (J); \
        if (idx < nd) rp[d0 + idx] = pp; \
        lcur[idx] = pp; pp += (HJ); }
    EMIT(0, h0) EMIT(1, h1) EMIT(2, h2) EMIT(3, h3)
    EMIT(4, h4) EMIT(5, h5) EMIT(6, h6) EMIT(7, h7)
    #undef EMIT
    __syncthreads();
    for (int i = t; i < cnt; i += 256) {
        unsigned int p = pk[i];
        int pos = atomicAdd(&lcur[p & (BDSTS - 1)], 1);
        col[pos] = (int)(p >> SHIFT);
    }
}

// ---------------- gather v6: no-max softmax, fma_mix, f16 in/out ----------------
__launch_bounds__(256)
__global__ void gat_gather_all(const int* __restrict__ rp, const int* __restrict__ col,
                               const float* __restrict__ as_gg, const float* __restrict__ ad_gg,
                               const unsigned short* __restrict__ xg_h,
                               const float* __restrict__ as_dg, const float* __restrict__ ad_dg,
                               const unsigned short* __restrict__ xd_h,
                               unsigned short* __restrict__ out_gg,
                               unsigned short* __restrict__ out_dg) {
    int wid = (blockIdx.x * 256 + threadIdx.x) >> 6;
    int l = threadIdx.x & 63;
    if (wid >= NALL) return;
    int isdg = wid >= NG;
    int d = isdg ? wid - NG : wid;
    const float* a_s = isdg ? as_dg : as_gg;
    const float* a_d = isdg ? ad_dg : ad_gg;
    const unsigned short* xbf = isdg ? xd_h : xg_h;
    unsigned short* outh = (isdg ? out_dg : out_gg);

    int base = rp[wid];
    int deg = rp[wid + 1] - base;

    int hl = l & 7;
    int g  = l >> 3;
    float adl = a_d[d * 8 + hl];
    // phase 1: ssum = sum exp(a)  (logits bounded |a| <~ 1.5 by construction: no max needed)
    float ssum = 0.f;
    for (int c0 = 0; c0 < deg; c0 += 64) {
        int myi = c0 + l;
        int colreg = (myi < deg) ? col[base + myi] : 0;
        int lim = min(deg - c0, 64);
        for (int t = g; t < lim; t += 8) {
            int s = __shfl(colreg, t);
            float a = a_s[s * 8 + hl] + adl;
            a = a > 0.f ? a : 0.2f * a;
            ssum += __expf(a);
        }
    }
    ssum += __shfl_xor(ssum, 8);
    ssum += __shfl_xor(ssum, 16);
    ssum += __shfl_xor(ssum, 32);
    float rsc = 1.f / (ssum + 1e-16f);

    // phase 2: quarter q = edge slot, cq = 8-col block (one head)
    int q = l >> 4;
    int cq = l & 15;
    int hq = cq >> 1;
    uint32_t colbyte = (uint32_t)cq << 4;
    float a0 = 0.f, a1 = 0.f, a2 = 0.f, a3 = 0.f, a4 = 0.f, a5 = 0.f, a6 = 0.f, a7 = 0.f;
    for (int c0 = 0; c0 < deg; c0 += 64) {
        int myi = c0 + l;
        int colreg = (myi < deg) ? col[base + myi] : 0;
        int lim = min(deg - c0, 64);
        for (int j8 = 0; j8 < lim; j8 += 8) {
            float alpha;
            {
                int s = __shfl(colreg, j8 + g);
                float a = a_s[s * 8 + hl] + adl;
                a = a > 0.f ? a : 0.2f * a;
                alpha = __expf(a) * rsc;
            }
            int jlim = min(lim - j8, 8);
            #pragma unroll
            for (int sub = 0; sub < 8; sub += 4) {
                int jrel = sub + q;
                int s = __shfl(colreg, j8 + jrel);
                float al = __shfl(alpha, (jrel << 3) + hq);
                al = (jrel < jlim) ? al : 0.f;
                const uint4 rv = *(const uint4*)((const char*)xbf +
                                    (((size_t)(uint32_t)s << 8) + colbyte));
                FMAMIX_LO(a0, rv.x, al); FMAMIX_HI(a1, rv.x, al);
                FMAMIX_LO(a2, rv.y, al); FMAMIX_HI(a3, rv.y, al);
                FMAMIX_LO(a4, rv.z, al); FMAMIX_HI(a5, rv.z, al);
                FMAMIX_LO(a6, rv.w, al); FMAMIX_HI(a7, rv.w, al);
            }
        }
    }
    a0 += __shfl_xor(a0, 16); a0 += __shfl_xor(a0, 32);
    a1 += __shfl_xor(a1, 16); a1 += __shfl_xor(a1, 32);
    a2 += __shfl_xor(a2, 16); a2 += __shfl_xor(a2, 32);
    a3 += __shfl_xor(a3, 16); a3 += __shfl_xor(a3, 32);
    a4 += __shfl_xor(a4, 16); a4 += __shfl_xor(a4, 32);
    a5 += __shfl_xor(a5, 16); a5 += __shfl_xor(a5, 32);
    a6 += __shfl_xor(a6, 16); a6 += __shfl_xor(a6, 32);
    a7 += __shfl_xor(a7, 16); a7 += __shfl_xor(a7, 32);
    if (q == 0) {
        __half2 h01 = __floats2half2_rn(a0, a1);
        __half2 h23 = __floats2half2_rn(a2, a3);
        __half2 h45 = __floats2half2_rn(a4, a5);
        __half2 h67 = __floats2half2_rn(a6, a7);
        uint4 o;
        o.x = *(unsigned*)&h01; o.y = *(unsigned*)&h23;
        o.z = *(unsigned*)&h45; o.w = *(unsigned*)&h67;
        *(uint4*)((char*)outh + (size_t)d * 256 + cq * 16) = o;
    }
}

// ---------------- kmean via f16 MFMA (raw f16 rows, packed relu) ----------------
__launch_bounds__(256)
__global__ void kmean_mfma(const unsigned short* __restrict__ srcA,
                           const unsigned short* __restrict__ srcB,
                           const float* __restrict__ W, const float* __restrict__ bias,
                           float* __restrict__ kp) {
    __shared__ f16x8 Bs[8 * 4 * 64];
    for (int idx = threadIdx.x; idx < 128 * 32; idx += 256) {
        int row = idx >> 5, kq = idx & 31;
        f32x4 v = *(const f32x4*)&W[row * 128 + kq * 4];
        int ct = row >> 4, c = row & 15;
        int k0 = kq * 4;
        int kc = k0 >> 5, q16 = (k0 & 31) >> 3, j2 = (k0 & 7) >> 1;
        unsigned* dst = (unsigned*)&Bs[(ct * 4 + kc) * 64 + q16 * 16 + c];
        dst[j2]     = ((unsigned)f16_bits(v.y) << 16) | f16_bits(v.x);
        dst[j2 + 1] = ((unsigned)f16_bits(v.w) << 16) | f16_bits(v.z);
    }
    __syncthreads();
    int half = blockIdx.x >= KM_HALF;
    const unsigned short* src = half ? srcB : srcA;
    float* kpp = half ? (kp + 128) : kp;
    int rb = (half ? blockIdx.x - KM_HALF : blockIdx.x) * 128;
    int wv = threadIdx.x >> 6, l = threadIdx.x & 63;
    int q = l >> 4, c16 = l & 15;
    int rw = rb + wv * 32;
    const char* xr0 = (const char*)src + (size_t)(rw + c16) * 256 + q * 16;
    const char* xr1 = xr0 + 16 * 256;
    #define LOADA(F, PTR, OFF) f16x8 F; { \
        U4F16 u_; u_.u = *(const uint4*)((PTR) + (OFF)); \
        u_.u.x = relu_pk(u_.u.x); u_.u.y = relu_pk(u_.u.y); \
        u_.u.z = relu_pk(u_.u.z); u_.u.w = relu_pk(u_.u.w); \
        F = u_.f; }
    LOADA(f00, xr0, 0) LOADA(f01, xr0, 64) LOADA(f02, xr0, 128) LOADA(f03, xr0, 192)
    LOADA(f10, xr1, 0) LOADA(f11, xr1, 64) LOADA(f12, xr1, 128) LOADA(f13, xr1, 192)
    #undef LOADA
    float bv0 = bias[c16],      bv1 = bias[16 + c16], bv2 = bias[32 + c16], bv3 = bias[48 + c16];
    float bv4 = bias[64 + c16], bv5 = bias[80 + c16], bv6 = bias[96 + c16], bv7 = bias[112 + c16];
    int row0 = rw + q * 4;
    int row1 = row0 + 16;
    float cs0 = 0.f, cs1 = 0.f, cs2 = 0.f, cs3 = 0.f, cs4 = 0.f, cs5 = 0.f, cs6 = 0.f, cs7 = 0.f;
    #define CT_STEP(CT, CS, BV) { \
        f16x8 b0 = Bs[((CT) * 4 + 0) * 64 + l]; \
        f16x8 b1 = Bs[((CT) * 4 + 1) * 64 + l]; \
        f16x8 b2 = Bs[((CT) * 4 + 2) * 64 + l]; \
        f16x8 b3 = Bs[((CT) * 4 + 3) * 64 + l]; \
        f32x4 aA = {0,0,0,0}, aB = {0,0,0,0}, aC = {0,0,0,0}, aD = {0,0,0,0}; \
        aA = MFMAH(f00, b0, aA); aB = MFMAH(f01, b1, aB); \
        aA = MFMAH(f02, b2, aA); aB = MFMAH(f03, b3, aB); \
        aC = MFMAH(f10, b0, aC); aD = MFMAH(f11, b1, aD); \
        aC = MFMAH(f12, b2, aC); aD = MFMAH(f13, b3, aD); \
        f32x4 d0 = aA + aB, d1 = aC + aD; \
        float s = 0.f; \
        if (row0 + 0 < NG) s += fast_tanh(d0[0] + (BV)); \
        if (row0 + 1 < NG) s += fast_tanh(d0[1] + (BV)); \
        if (row0 + 2 < NG) s += fast_tanh(d0[2] + (BV)); \
        if (row0 + 3 < NG) s += fast_tanh(d0[3] + (BV)); \
        if (row1 + 0 < NG) s += fast_tanh(d1[0] + (BV)); \
        if (row1 + 1 < NG) s += fast_tanh(d1[1] + (BV)); \
        if (row1 + 2 < NG) s += fast_tanh(d1[2] + (BV)); \
        if (row1 + 3 < NG) s += fast_tanh(d1[3] + (BV)); \
        CS += s; }
    CT_STEP(0, cs0, bv0) CT_STEP(1, cs1, bv1) CT_STEP(2, cs2, bv2) CT_STEP(3, cs3, bv3)
    CT_STEP(4, cs4, bv4) CT_STEP(5, cs5, bv5) CT_STEP(6, cs6, bv6) CT_STEP(7, cs7, bv7)
    #undef CT_STEP
    __syncthreads();
    float* red = (float*)Bs;
    #define REDUCE_CT(CT, CS) { \
        float v = (CS); \
        v += __shfl_xor(v, 16); v += __shfl_xor(v, 32); \
        if (l < 16) red[wv * 128 + (CT) * 16 + l] = v; }
    REDUCE_CT(0, cs0) REDUCE_CT(1, cs1) REDUCE_CT(2, cs2) REDUCE_CT(3, cs3)
    REDUCE_CT(4, cs4) REDUCE_CT(5, cs5) REDUCE_CT(6, cs6) REDUCE_CT(7, cs7)
    #undef REDUCE_CT
    __syncthreads();
    if (threadIdx.x < 128) {
        float s = red[threadIdx.x] + red[128 + threadIdx.x]
                + red[256 + threadIdx.x] + red[384 + threadIdx.x];
        atomicAdd(&kpp[threadIdx.x], s);
    }
}

// ---------------- semantic softmax (2 scores) ----------------
__global__ void score_attn(const float* __restrict__ kpart, const float* __restrict__ q,
                           float* __restrict__ attn) {
    __shared__ float r0[128], r1[128];
    int t = threadIdx.x;
    r0[t] = q[t] * kpart[t];
    r1[t] = q[t] * kpart[128 + t];
    __syncthreads();
    for (int s = 64; s > 0; s >>= 1) {
        if (t < s) { r0[t] += r0[t + s]; r1[t] += r1[t + s]; }
        __syncthreads();
    }
    if (t == 0) {
        float s0 = r0[0] / (float)NG, s1 = r1[0] / (float)NG;
        float mx = fmaxf(s0, s1);
        float e0 = expf(s0 - mx), e1 = expf(s1 - mx);
        attn[0] = e0 / (e0 + e1);
        attn[1] = e1 / (e0 + e1);
    }
}

// ---------------- fused combine + final linear (f16 inputs) ----------------
__launch_bounds__(256)
__global__ void final_lin(const unsigned short* __restrict__ gg,
                          const unsigned short* __restrict__ dgb,
                          const float* __restrict__ attn, const float* __restrict__ lin_w,
                          const float* __restrict__ lin_b, float* __restrict__ outp) {
    int wid = (blockIdx.x * 256 + threadIdx.x) >> 6;
    int l = threadIdx.x & 63;
    if (wid >= NG) return;
    float a0 = attn[0], a1 = attn[1];
    unsigned gu = *(const unsigned*)((const char*)gg + (size_t)wid * 256 + l * 4);
    unsigned du = *(const unsigned*)((const char*)dgb + (size_t)wid * 256 + l * 4);
    float2 gv = __half22float2(*(const __half2*)&gu);
    float2 dv = __half22float2(*(const __half2*)&du);
    float fx = a0 * fmaxf(gv.x, 0.f) + a1 * fmaxf(dv.x, 0.f);
    float fy = a0 * fmaxf(gv.y, 0.f) + a1 * fmaxf(dv.y, 0.f);
    float2 w0 = *(const float2*)&lin_w[l * 2];
    float2 w1 = *(const float2*)&lin_w[128 + l * 2];
    float p0 = fx * w0.x + fy * w0.y;
    float p1 = fx * w1.x + fy * w1.y;
    for (int off = 32; off > 0; off >>= 1) {
        p0 += __shfl_down(p0, off);
        p1 += __shfl_down(p1, off);
    }
    if (l == 0) {
        float2 o;
        o.x = p0 + lin_b[0];
        o.y = p1 + lin_b[1];
        *(float2*)&outp[wid * 2] = o;
    }
}

extern "C" void kernel_launch(void* const* d_in, const int* in_sizes, int n_in,
                              void* d_out, int out_size, void* d_ws, size_t ws_size,
                              hipStream_t stream) {
    const float* x_gene    = (const float*)d_in[0];
    const float* x_disease = (const float*)d_in[1];
    const int*   edge_gg   = (const int*)d_in[2];
    const int*   edge_dg   = (const int*)d_in[3];
    const float* pg_w      = (const float*)d_in[4];
    const float* pg_b      = (const float*)d_in[5];
    const float* pd_w      = (const float*)d_in[6];
    const float* pd_b      = (const float*)d_in[7];
    const float* att_src_gg= (const float*)d_in[8];
    const float* att_dst_gg= (const float*)d_in[9];
    const float* att_src_dg= (const float*)d_in[10];
    const float* att_dst_dg= (const float*)d_in[11];
    const float* k_lin_w   = (const float*)d_in[12];
    const float* k_lin_b   = (const float*)d_in[13];
    const float* q         = (const float*)d_in[14];
    const float* lin_w     = (const float*)d_in[15];
    const float* lin_b     = (const float*)d_in[16];
    float* out = (float*)d_out;
    float* ws  = (float*)d_ws;

    unsigned short* out_gg = (unsigned short*)(ws + OFF_OUT_GG);
    unsigned short* out_dg = (unsigned short*)(ws + OFF_OUT_DG);
    unsigned int* colPacked = (unsigned int*)(ws + OFF_OUT_GG);  // overlay (dead before gather)
    unsigned short* xg_h = (unsigned short*)(ws + OFF_XG);
    unsigned short* xd_h = (unsigned short*)(ws + OFF_XD);
    float* a_src_gg = ws + OFF_ASG;
    float* a_dst_gg = ws + OFF_ADG;
    float* a_dst_dg = ws + OFF_ADD;
    float* a_src_dg = ws + OFF_ASD;
    float* kpart  = ws + OFF_KPART;
    float* attn   = ws + OFF_ATTN;
    float* wtilG  = ws + OFF_WTIL;
    float* btilG  = ws + OFF_BTIL;
    float* wtilD  = ws + OFF_WTILD;
    float* btilD  = ws + OFF_BTILD;
    int* bcnt  = (int*)(ws + OFF_BCNT);
    int* bbase = (int*)(ws + OFF_BBASE);
    int* rp    = (int*)(ws + OFF_RP);
    int* col   = (int*)(ws + OFF_COL);

    const int* gg_src = edge_gg;
    const int* gg_dst = edge_gg + EGG;
    const int* dg_src = edge_dg;
    const int* dg_dst = edge_dg + EDG;

    // 1. zero kpart + bucket counters; wtilde precompute
    hipLaunchKernelGGL(init_zero_k, dim3(2), dim3(256), 0, stream, ws + ZERO_BASE, ZERO_CNT);
    hipLaunchKernelGGL(make_wtil, dim3(8), dim3(256), 0, stream,
                       pg_w, pg_b, att_src_gg, att_dst_gg, att_dst_dg, 3, wtilG, btilG);
    hipLaunchKernelGGL(make_wtil, dim3(4), dim3(256), 0, stream,
                       pd_w, pd_b, att_src_dg, att_src_dg, att_src_dg, 1, wtilD, btilD);
    // 2. split-bf16 MFMA projections (f16 table + fused logits)
    hipLaunchKernelGGL((proj_mfma<3>), dim3((NG + 127) / 128), dim3(256), 0, stream,
                       x_gene, pg_w, pg_b, wtilG, btilG, xg_h,
                       a_src_gg, a_dst_gg, a_dst_dg, NG);
    hipLaunchKernelGGL((proj_mfma<1>), dim3((ND + 127) / 128), dim3(256), 0, stream,
                       x_disease, pd_w, pd_b, wtilD, btilD, xd_h,
                       a_src_dg, (float*)nullptr, (float*)nullptr, ND);
    // 3. CSR build: fused scatter -> bucket scan -> per-bucket build
    hipLaunchKernelGGL(fused_scatter, dim3((EALL + S1_CH - 1) / S1_CH), dim3(256), 0, stream,
                       gg_src, gg_dst, dg_src, dg_dst, bcnt, colPacked);
    hipLaunchKernelGGL(scan_buckets, dim3(1), dim3(128), 0, stream, bcnt, bbase, rp);
    hipLaunchKernelGGL(bucket_build, dim3(NBUK), dim3(256), 0, stream,
                       colPacked, bcnt, bbase, rp, col);
    // 4. merged fused gather (out_gg overwrites colPacked overlay — dead by now)
    hipLaunchKernelGGL(gat_gather_all, dim3((NALL + 3) / 4), dim3(256), 0, stream,
                       rp, col, a_src_gg, a_dst_gg, xg_h, a_src_dg, a_dst_dg, xd_h,
                       out_gg, out_dg);
    // 5. semantic attention (f16 MFMA kmean)
    hipLaunchKernelGGL(kmean_mfma, dim3(KM_HALF * 2), dim3(256), 0, stream,
                       out_gg, out_dg, k_lin_w, k_lin_b, kpart);
    hipLaunchKernelGGL(score_attn, dim3(1), dim3(128), 0, stream, kpart, q, attn);
    // 6. fused combine + final linear (f16 reads)
    hipLaunchKernelGGL(final_lin, dim3((NG + 3) / 4), dim3(256), 0, stream,
                       out_gg, out_dg, attn, lin_w, lin_b, out);
}